// Round 1
// baseline (333.850 us; speedup 1.0000x reference)
//
#include <hip/hip_runtime.h>
#include <math.h>

namespace {
constexpr int N_   = 50000;
constexpr int E_   = 800000;
constexpr int EP_  = E_ + N_;   // edges + self loops = 850000
constexpr float SLOPE = 0.2f;

// workspace layout (bytes, 16B-aligned chunks)
constexpr size_t OFF_H1  = 0;                                   // [N][128] f32
constexpr size_t OFF_Y1  = OFF_H1  + (size_t)N_ * 128 * 4;      // [N][128] f32 (elu out)
constexpr size_t OFF_H2  = OFF_Y1  + (size_t)N_ * 128 * 4;      // [N][64] f32
constexpr size_t OFF_AS1 = OFF_H2  + (size_t)N_ * 64 * 4;       // [N][4]
constexpr size_t OFF_AD1 = OFF_AS1 + (size_t)N_ * 4 * 4;        // [N][4]
constexpr size_t OFF_AS2 = OFF_AD1 + (size_t)N_ * 4 * 4;        // [N]
constexpr size_t OFF_AD2 = OFF_AS2 + (size_t)N_ * 4;            // [N]
constexpr size_t OFF_DEG = OFF_AD2 + (size_t)N_ * 4;            // [N] int
constexpr size_t OFF_ROW = OFF_DEG + (size_t)N_ * 4;            // [N+1] int
constexpr size_t OFF_CUR = OFF_ROW + (((size_t)(N_ + 1) * 4 + 15) & ~(size_t)15); // [N] int
constexpr size_t OFF_BS  = OFF_CUR + (size_t)N_ * 4;            // [196] int (block sums)
constexpr size_t OFF_EB  = OFF_BS  + 1024;                      // [EP] int (src sorted by dst)
}

// ---------------- GEMM1: h1 = x @ W1 ; a_s1/a_d1 per head ----------------
__global__ __launch_bounds__(256) void k_gemm1(const float* __restrict__ x,
    const float* __restrict__ W, const float* __restrict__ av_s,
    const float* __restrict__ av_d, float* __restrict__ h,
    float* __restrict__ a_s, float* __restrict__ a_d)
{
  __shared__ float xs[16 * 128];
  const int t = threadIdx.x;
  const int rbase = blockIdx.x * 16;
  {
    const float4* xg = (const float4*)(x + (size_t)rbase * 128);
    float4* s4 = (float4*)xs;
    s4[t] = xg[t];
    s4[t + 256] = xg[t + 256];
  }
  __syncthreads();
  const int c = t & 127;
  const int rr = t >> 7;   // 0..1
  float acc[8] = {0, 0, 0, 0, 0, 0, 0, 0};
  for (int k0 = 0; k0 < 128; k0 += 4) {
    const float w0 = W[(k0 + 0) * 128 + c];
    const float w1 = W[(k0 + 1) * 128 + c];
    const float w2 = W[(k0 + 2) * 128 + c];
    const float w3 = W[(k0 + 3) * 128 + c];
#pragma unroll
    for (int j = 0; j < 8; ++j) {
      const int r = rr + 2 * j;
      const float4 xv = *(const float4*)&xs[r * 128 + k0];
      acc[j] = fmaf(xv.x, w0, acc[j]);
      acc[j] = fmaf(xv.y, w1, acc[j]);
      acc[j] = fmaf(xv.z, w2, acc[j]);
      acc[j] = fmaf(xv.w, w3, acc[j]);
    }
  }
  const float asc = av_s[c];
  const float adc = av_d[c];
#pragma unroll
  for (int j = 0; j < 8; ++j) {
    const int rg = rbase + rr + 2 * j;
    h[(size_t)rg * 128 + c] = acc[j];
    float ps = acc[j] * asc;
    float pd = acc[j] * adc;
#pragma unroll
    for (int m = 16; m >= 1; m >>= 1) {
      ps += __shfl_xor(ps, m);
      pd += __shfl_xor(pd, m);
    }
    if ((c & 31) == 0) {
      a_s[rg * 4 + (c >> 5)] = ps;
      a_d[rg * 4 + (c >> 5)] = pd;
    }
  }
}

// ---------------- GEMM2: h2 = y1 @ W2 ; a_s2/a_d2 (1 head) ----------------
__global__ __launch_bounds__(256) void k_gemm2(const float* __restrict__ y,
    const float* __restrict__ W, const float* __restrict__ av_s,
    const float* __restrict__ av_d, float* __restrict__ h,
    float* __restrict__ a_s, float* __restrict__ a_d)
{
  __shared__ float ys[16 * 128];
  const int t = threadIdx.x;
  const int rbase = blockIdx.x * 16;
  {
    const float4* yg = (const float4*)(y + (size_t)rbase * 128);
    float4* s4 = (float4*)ys;
    s4[t] = yg[t];
    s4[t + 256] = yg[t + 256];
  }
  __syncthreads();
  const int c = t & 63;
  const int rr = t >> 6;   // 0..3
  float acc[4] = {0, 0, 0, 0};
  for (int k0 = 0; k0 < 128; k0 += 4) {
    const float w0 = W[(k0 + 0) * 64 + c];
    const float w1 = W[(k0 + 1) * 64 + c];
    const float w2 = W[(k0 + 2) * 64 + c];
    const float w3 = W[(k0 + 3) * 64 + c];
#pragma unroll
    for (int j = 0; j < 4; ++j) {
      const int r = rr + 4 * j;
      const float4 yv = *(const float4*)&ys[r * 128 + k0];
      acc[j] = fmaf(yv.x, w0, acc[j]);
      acc[j] = fmaf(yv.y, w1, acc[j]);
      acc[j] = fmaf(yv.z, w2, acc[j]);
      acc[j] = fmaf(yv.w, w3, acc[j]);
    }
  }
  const float asc = av_s[c];
  const float adc = av_d[c];
#pragma unroll
  for (int j = 0; j < 4; ++j) {
    const int rg = rbase + rr + 4 * j;
    h[(size_t)rg * 64 + c] = acc[j];
    float ps = acc[j] * asc;
    float pd = acc[j] * adc;
#pragma unroll
    for (int m = 32; m >= 1; m >>= 1) {
      ps += __shfl_xor(ps, m);
      pd += __shfl_xor(pd, m);
    }
    if (c == 0) { a_s[rg] = ps; a_d[rg] = pd; }
  }
}

// ---------------- CSR build ----------------
__global__ __launch_bounds__(256) void k_deg(const int* __restrict__ ei,
                                             int* __restrict__ deg)
{
  const int i = blockIdx.x * 256 + threadIdx.x;
  if (i >= EP_) return;
  const int d = (i < E_) ? ei[E_ + i] : (i - E_);
  atomicAdd(&deg[d], 1);
}

__global__ __launch_bounds__(256) void k_scanA(const int* __restrict__ deg,
                                               int* __restrict__ bsum)
{
  __shared__ int sd[256];
  const int t = threadIdx.x;
  const int i = blockIdx.x * 256 + t;
  sd[t] = (i < N_) ? deg[i] : 0;
  __syncthreads();
  for (int off = 128; off > 0; off >>= 1) {
    if (t < off) sd[t] += sd[t + off];
    __syncthreads();
  }
  if (t == 0) bsum[blockIdx.x] = sd[0];
}

__global__ __launch_bounds__(256) void k_scanB(int* __restrict__ bsum)
{
  __shared__ int sd[256];
  const int t = threadIdx.x;
  const int v = (t < 196) ? bsum[t] : 0;
  sd[t] = v;
  __syncthreads();
  for (int off = 1; off < 256; off <<= 1) {
    const int add = (t >= off) ? sd[t - off] : 0;
    __syncthreads();
    sd[t] += add;
    __syncthreads();
  }
  if (t < 196) bsum[t] = sd[t] - v;   // exclusive
}

__global__ __launch_bounds__(256) void k_scanC(const int* __restrict__ deg,
    const int* __restrict__ bsum, int* __restrict__ rowptr)
{
  __shared__ int sd[256];
  const int t = threadIdx.x;
  const int i = blockIdx.x * 256 + t;
  const int v = (i < N_) ? deg[i] : 0;
  sd[t] = v;
  __syncthreads();
  for (int off = 1; off < 256; off <<= 1) {
    const int add = (t >= off) ? sd[t - off] : 0;
    __syncthreads();
    sd[t] += add;
    __syncthreads();
  }
  if (i <= N_) rowptr[i] = sd[t] - v + bsum[blockIdx.x];
}

__global__ __launch_bounds__(256) void k_fill(const int* __restrict__ ei,
    const int* __restrict__ rowptr, int* __restrict__ cursor,
    int* __restrict__ ebuf)
{
  const int i = blockIdx.x * 256 + threadIdx.x;
  if (i >= EP_) return;
  int s, d;
  if (i < E_) { s = ei[i]; d = ei[E_ + i]; }
  else        { s = i - E_; d = s; }
  const int pos = rowptr[d] + atomicAdd(&cursor[d], 1);
  ebuf[pos] = s;
}

// ---------------- Layer-1 aggregation (4 heads x 32 ch), + b1, ELU -------
__global__ __launch_bounds__(256) void k_agg1(const int* __restrict__ rowptr,
    const int* __restrict__ ebuf, const float* __restrict__ a_s,
    const float* __restrict__ a_d, const float* __restrict__ h,
    const float* __restrict__ b1, float* __restrict__ y)
{
  __shared__ float plds[4][128][4];
  __shared__ int   slds[4][128];
  const int w = threadIdx.x >> 6;
  const int l = threadIdx.x & 63;
  const int d = blockIdx.x * 4 + w;
  const int base = rowptr[d];
  const int deg  = rowptr[d + 1] - base;
  const float4 ad = *(const float4*)&a_d[(size_t)d * 4];
  float mx0 = -1e30f, mx1 = -1e30f, mx2 = -1e30f, mx3 = -1e30f;
  for (int i = l; i < deg; i += 64) {
    const int s = ebuf[base + i];
    const float4 as = *(const float4*)&a_s[(size_t)s * 4];
    float e0 = as.x + ad.x; e0 = e0 > 0.f ? e0 : SLOPE * e0;
    float e1 = as.y + ad.y; e1 = e1 > 0.f ? e1 : SLOPE * e1;
    float e2 = as.z + ad.z; e2 = e2 > 0.f ? e2 : SLOPE * e2;
    float e3 = as.w + ad.w; e3 = e3 > 0.f ? e3 : SLOPE * e3;
    if (i < 128) {
      slds[w][i] = s;
      plds[w][i][0] = e0; plds[w][i][1] = e1;
      plds[w][i][2] = e2; plds[w][i][3] = e3;
    }
    mx0 = fmaxf(mx0, e0); mx1 = fmaxf(mx1, e1);
    mx2 = fmaxf(mx2, e2); mx3 = fmaxf(mx3, e3);
  }
#pragma unroll
  for (int m = 32; m >= 1; m >>= 1) {
    mx0 = fmaxf(mx0, __shfl_xor(mx0, m));
    mx1 = fmaxf(mx1, __shfl_xor(mx1, m));
    mx2 = fmaxf(mx2, __shfl_xor(mx2, m));
    mx3 = fmaxf(mx3, __shfl_xor(mx3, m));
  }
  float sm0 = 0.f, sm1 = 0.f, sm2 = 0.f, sm3 = 0.f;
  for (int i = l; i < deg; i += 64) {
    float e0, e1, e2, e3;
    if (i < 128) {
      e0 = plds[w][i][0]; e1 = plds[w][i][1];
      e2 = plds[w][i][2]; e3 = plds[w][i][3];
    } else {
      const int s = ebuf[base + i];
      const float4 as = *(const float4*)&a_s[(size_t)s * 4];
      e0 = as.x + ad.x; e0 = e0 > 0.f ? e0 : SLOPE * e0;
      e1 = as.y + ad.y; e1 = e1 > 0.f ? e1 : SLOPE * e1;
      e2 = as.z + ad.z; e2 = e2 > 0.f ? e2 : SLOPE * e2;
      e3 = as.w + ad.w; e3 = e3 > 0.f ? e3 : SLOPE * e3;
    }
    const float p0 = __expf(e0 - mx0);
    const float p1 = __expf(e1 - mx1);
    const float p2 = __expf(e2 - mx2);
    const float p3 = __expf(e3 - mx3);
    if (i < 128) {
      plds[w][i][0] = p0; plds[w][i][1] = p1;
      plds[w][i][2] = p2; plds[w][i][3] = p3;
    }
    sm0 += p0; sm1 += p1; sm2 += p2; sm3 += p3;
  }
#pragma unroll
  for (int m = 32; m >= 1; m >>= 1) {
    sm0 += __shfl_xor(sm0, m);
    sm1 += __shfl_xor(sm1, m);
    sm2 += __shfl_xor(sm2, m);
    sm3 += __shfl_xor(sm3, m);
  }
  const float r0 = 1.f / (sm0 + 1e-16f);
  const float r1 = 1.f / (sm1 + 1e-16f);
  const float r2 = 1.f / (sm2 + 1e-16f);
  const float r3 = 1.f / (sm3 + 1e-16f);
  const bool hi = (l >= 32);
  const float mxA = hi ? mx1 : mx0;
  const float mxB = hi ? mx3 : mx2;
  const float rA  = hi ? r1 : r0;
  const float rB  = hi ? r3 : r2;
  const int hA = hi ? 1 : 0;
  const int hB = hA + 2;
  float accA = 0.f, accB = 0.f;
  for (int i = 0; i < deg; ++i) {
    int s; float pA, pB;
    if (i < 128) {
      s = slds[w][i];
      pA = plds[w][i][hA];
      pB = plds[w][i][hB];
    } else {
      s = ebuf[base + i];
      const float4 as = *(const float4*)&a_s[(size_t)s * 4];
      float eA = hi ? (as.y + ad.y) : (as.x + ad.x);
      eA = eA > 0.f ? eA : SLOPE * eA;
      float eB = hi ? (as.w + ad.w) : (as.z + ad.z);
      eB = eB > 0.f ? eB : SLOPE * eB;
      pA = __expf(eA - mxA);
      pB = __expf(eB - mxB);
    }
    const float* hr = h + (size_t)s * 128;
    accA = fmaf(pA, hr[l], accA);
    accB = fmaf(pB, hr[l + 64], accB);
  }
  const float oA = accA * rA + b1[l];
  const float oB = accB * rB + b1[l + 64];
  y[(size_t)d * 128 + l]      = oA > 0.f ? oA : expm1f(oA);
  y[(size_t)d * 128 + l + 64] = oB > 0.f ? oB : expm1f(oB);
}

// ---------------- Layer-2 aggregation (1 head x 64 ch), + b2 -------------
__global__ __launch_bounds__(256) void k_agg2(const int* __restrict__ rowptr,
    const int* __restrict__ ebuf, const float* __restrict__ a_s,
    const float* __restrict__ a_d, const float* __restrict__ h,
    const float* __restrict__ b2, float* __restrict__ out)
{
  __shared__ float plds[4][128];
  __shared__ int   slds[4][128];
  const int w = threadIdx.x >> 6;
  const int l = threadIdx.x & 63;
  const int d = blockIdx.x * 4 + w;
  const int base = rowptr[d];
  const int deg  = rowptr[d + 1] - base;
  const float ad = a_d[d];
  float mx = -1e30f;
  for (int i = l; i < deg; i += 64) {
    const int s = ebuf[base + i];
    float e = a_s[s] + ad; e = e > 0.f ? e : SLOPE * e;
    if (i < 128) { slds[w][i] = s; plds[w][i] = e; }
    mx = fmaxf(mx, e);
  }
#pragma unroll
  for (int m = 32; m >= 1; m >>= 1) mx = fmaxf(mx, __shfl_xor(mx, m));
  float sm = 0.f;
  for (int i = l; i < deg; i += 64) {
    float e;
    if (i < 128) e = plds[w][i];
    else { const int s = ebuf[base + i]; e = a_s[s] + ad; e = e > 0.f ? e : SLOPE * e; }
    const float p = __expf(e - mx);
    if (i < 128) plds[w][i] = p;
    sm += p;
  }
#pragma unroll
  for (int m = 32; m >= 1; m >>= 1) sm += __shfl_xor(sm, m);
  const float rv = 1.f / (sm + 1e-16f);
  float acc = 0.f;
  for (int i = 0; i < deg; ++i) {
    int s; float p;
    if (i < 128) { s = slds[w][i]; p = plds[w][i]; }
    else {
      s = ebuf[base + i];
      float e = a_s[s] + ad; e = e > 0.f ? e : SLOPE * e;
      p = __expf(e - mx);
    }
    acc = fmaf(p, h[(size_t)s * 64 + l], acc);
  }
  out[(size_t)d * 64 + l] = acc * rv + b2[l];
}

extern "C" void kernel_launch(void* const* d_in, const int* in_sizes, int n_in,
                              void* d_out, int out_size, void* d_ws, size_t ws_size,
                              hipStream_t stream) {
  const float* x     = (const float*)d_in[0];
  const int*   ei    = (const int*)d_in[1];
  const float* W1    = (const float*)d_in[2];
  const float* as1v  = (const float*)d_in[3];
  const float* ad1v  = (const float*)d_in[4];
  const float* b1    = (const float*)d_in[5];
  const float* W2    = (const float*)d_in[6];
  const float* as2v  = (const float*)d_in[7];
  const float* ad2v  = (const float*)d_in[8];
  const float* b2    = (const float*)d_in[9];
  float* out = (float*)d_out;

  char* ws = (char*)d_ws;
  float* h1   = (float*)(ws + OFF_H1);
  float* y1   = (float*)(ws + OFF_Y1);
  float* h2   = (float*)(ws + OFF_H2);
  float* a_s1 = (float*)(ws + OFF_AS1);
  float* a_d1 = (float*)(ws + OFF_AD1);
  float* a_s2 = (float*)(ws + OFF_AS2);
  float* a_d2 = (float*)(ws + OFF_AD2);
  int* deg    = (int*)(ws + OFF_DEG);
  int* rowptr = (int*)(ws + OFF_ROW);
  int* cursor = (int*)(ws + OFF_CUR);
  int* bsum   = (int*)(ws + OFF_BS);
  int* ebuf   = (int*)(ws + OFF_EB);

  hipMemsetAsync(deg, 0, (size_t)N_ * 4, stream);
  hipMemsetAsync(cursor, 0, (size_t)N_ * 4, stream);

  k_gemm1<<<N_ / 16, 256, 0, stream>>>(x, W1, as1v, ad1v, h1, a_s1, a_d1);
  k_deg<<<(EP_ + 255) / 256, 256, 0, stream>>>(ei, deg);
  k_scanA<<<196, 256, 0, stream>>>(deg, bsum);
  k_scanB<<<1, 256, 0, stream>>>(bsum);
  k_scanC<<<196, 256, 0, stream>>>(deg, bsum, rowptr);
  k_fill<<<(EP_ + 255) / 256, 256, 0, stream>>>(ei, rowptr, cursor, ebuf);
  k_agg1<<<N_ / 4, 256, 0, stream>>>(rowptr, ebuf, a_s1, a_d1, h1, b1, y1);
  k_gemm2<<<N_ / 16, 256, 0, stream>>>(y1, W2, as2v, ad2v, h2, a_s2, a_d2);
  k_agg2<<<N_ / 4, 256, 0, stream>>>(rowptr, ebuf, a_s2, a_d2, h2, b2, out);
}

// Round 2
// 284.092 us; speedup vs baseline: 1.1751x; 1.1751x over previous
//
#include <hip/hip_runtime.h>
#include <math.h>

namespace {
constexpr int N_   = 50000;
constexpr int E_   = 800000;
constexpr int EP_  = E_ + N_;   // edges + self loops = 850000
constexpr float SLOPE = 0.2f;

// workspace layout (bytes, 16B-aligned chunks)
constexpr size_t OFF_H1  = 0;                                   // [N][128] f32
constexpr size_t OFF_Y1  = OFF_H1  + (size_t)N_ * 128 * 4;      // [N][128] f32 (elu out)
constexpr size_t OFF_H2  = OFF_Y1  + (size_t)N_ * 128 * 4;      // [N][64] f32
constexpr size_t OFF_AS1 = OFF_H2  + (size_t)N_ * 64 * 4;       // [N][4]
constexpr size_t OFF_AD1 = OFF_AS1 + (size_t)N_ * 4 * 4;        // [N][4]
constexpr size_t OFF_AS2 = OFF_AD1 + (size_t)N_ * 4 * 4;        // [N]
constexpr size_t OFF_AD2 = OFF_AS2 + (size_t)N_ * 4;            // [N]
constexpr size_t OFF_DEG = OFF_AD2 + (size_t)N_ * 4;            // [N] int
constexpr size_t OFF_ROW = OFF_DEG + (size_t)N_ * 4;            // [N+1] int
constexpr size_t OFF_CUR = OFF_ROW + (((size_t)(N_ + 1) * 4 + 15) & ~(size_t)15); // [N] int
constexpr size_t OFF_BS  = OFF_CUR + (size_t)N_ * 4;            // [196] int (block sums)
constexpr size_t OFF_EB  = OFF_BS  + 1024;                      // [EP] int (src sorted by dst)
}

// ---------------- GEMM1: h1 = x @ W1 ; a_s1/a_d1 per head ----------------
// k-loop strip-mined (unroll 1, W chunk of 8 in regs) to keep VGPR low and
// occupancy high; previous version fully unrolled -> 256 VGPR, 10% occupancy.
__global__ __launch_bounds__(256, 4) void k_gemm1(const float* __restrict__ x,
    const float* __restrict__ W, const float* __restrict__ av_s,
    const float* __restrict__ av_d, float* __restrict__ h,
    float* __restrict__ a_s, float* __restrict__ a_d)
{
  __shared__ float xs[16 * 128];
  const int t = threadIdx.x;
  const int rbase = blockIdx.x * 16;
  {
    const float4* xg = (const float4*)(x + (size_t)rbase * 128);
    float4* s4 = (float4*)xs;
    s4[t] = xg[t];
    s4[t + 256] = xg[t + 256];
  }
  __syncthreads();
  const int c = t & 127;
  const int rr = t >> 7;   // 0..1
  float acc[8] = {0, 0, 0, 0, 0, 0, 0, 0};
#pragma unroll 1
  for (int k0 = 0; k0 < 128; k0 += 8) {
    float w[8];
#pragma unroll
    for (int u = 0; u < 8; ++u) w[u] = W[(k0 + u) * 128 + c];
#pragma unroll
    for (int j = 0; j < 8; ++j) {
      const int r = rr + 2 * j;
      const float4 xa = *(const float4*)&xs[r * 128 + k0];
      const float4 xb = *(const float4*)&xs[r * 128 + k0 + 4];
      acc[j] = fmaf(xa.x, w[0], acc[j]);
      acc[j] = fmaf(xa.y, w[1], acc[j]);
      acc[j] = fmaf(xa.z, w[2], acc[j]);
      acc[j] = fmaf(xa.w, w[3], acc[j]);
      acc[j] = fmaf(xb.x, w[4], acc[j]);
      acc[j] = fmaf(xb.y, w[5], acc[j]);
      acc[j] = fmaf(xb.z, w[6], acc[j]);
      acc[j] = fmaf(xb.w, w[7], acc[j]);
    }
  }
  const float asc = av_s[c];
  const float adc = av_d[c];
#pragma unroll
  for (int j = 0; j < 8; ++j) {
    const int rg = rbase + rr + 2 * j;
    h[(size_t)rg * 128 + c] = acc[j];
    float ps = acc[j] * asc;
    float pd = acc[j] * adc;
#pragma unroll
    for (int m = 16; m >= 1; m >>= 1) {
      ps += __shfl_xor(ps, m);
      pd += __shfl_xor(pd, m);
    }
    if ((c & 31) == 0) {
      a_s[rg * 4 + (c >> 5)] = ps;
      a_d[rg * 4 + (c >> 5)] = pd;
    }
  }
}

// ---------------- GEMM2: h2 = y1 @ W2 ; a_s2/a_d2 (1 head) ----------------
__global__ __launch_bounds__(256, 4) void k_gemm2(const float* __restrict__ y,
    const float* __restrict__ W, const float* __restrict__ av_s,
    const float* __restrict__ av_d, float* __restrict__ h,
    float* __restrict__ a_s, float* __restrict__ a_d)
{
  __shared__ float ys[16 * 128];
  const int t = threadIdx.x;
  const int rbase = blockIdx.x * 16;
  {
    const float4* yg = (const float4*)(y + (size_t)rbase * 128);
    float4* s4 = (float4*)ys;
    s4[t] = yg[t];
    s4[t + 256] = yg[t + 256];
  }
  __syncthreads();
  const int c = t & 63;
  const int rr = t >> 6;   // 0..3
  float acc[4] = {0, 0, 0, 0};
#pragma unroll 1
  for (int k0 = 0; k0 < 128; k0 += 8) {
    float w[8];
#pragma unroll
    for (int u = 0; u < 8; ++u) w[u] = W[(k0 + u) * 64 + c];
#pragma unroll
    for (int j = 0; j < 4; ++j) {
      const int r = rr + 4 * j;
      const float4 ya = *(const float4*)&ys[r * 128 + k0];
      const float4 yb = *(const float4*)&ys[r * 128 + k0 + 4];
      acc[j] = fmaf(ya.x, w[0], acc[j]);
      acc[j] = fmaf(ya.y, w[1], acc[j]);
      acc[j] = fmaf(ya.z, w[2], acc[j]);
      acc[j] = fmaf(ya.w, w[3], acc[j]);
      acc[j] = fmaf(yb.x, w[4], acc[j]);
      acc[j] = fmaf(yb.y, w[5], acc[j]);
      acc[j] = fmaf(yb.z, w[6], acc[j]);
      acc[j] = fmaf(yb.w, w[7], acc[j]);
    }
  }
  const float asc = av_s[c];
  const float adc = av_d[c];
#pragma unroll
  for (int j = 0; j < 4; ++j) {
    const int rg = rbase + rr + 4 * j;
    h[(size_t)rg * 64 + c] = acc[j];
    float ps = acc[j] * asc;
    float pd = acc[j] * adc;
#pragma unroll
    for (int m = 32; m >= 1; m >>= 1) {
      ps += __shfl_xor(ps, m);
      pd += __shfl_xor(pd, m);
    }
    if (c == 0) { a_s[rg] = ps; a_d[rg] = pd; }
  }
}

// ---------------- CSR build ----------------
__global__ __launch_bounds__(256) void k_deg(const int* __restrict__ ei,
                                             int* __restrict__ deg)
{
  const int i = blockIdx.x * 256 + threadIdx.x;
  if (i >= EP_) return;
  const int d = (i < E_) ? ei[E_ + i] : (i - E_);
  atomicAdd(&deg[d], 1);
}

__global__ __launch_bounds__(256) void k_scanA(const int* __restrict__ deg,
                                               int* __restrict__ bsum)
{
  __shared__ int sd[256];
  const int t = threadIdx.x;
  const int i = blockIdx.x * 256 + t;
  sd[t] = (i < N_) ? deg[i] : 0;
  __syncthreads();
  for (int off = 128; off > 0; off >>= 1) {
    if (t < off) sd[t] += sd[t + off];
    __syncthreads();
  }
  if (t == 0) bsum[blockIdx.x] = sd[0];
}

__global__ __launch_bounds__(256) void k_scanB(int* __restrict__ bsum)
{
  __shared__ int sd[256];
  const int t = threadIdx.x;
  const int v = (t < 196) ? bsum[t] : 0;
  sd[t] = v;
  __syncthreads();
  for (int off = 1; off < 256; off <<= 1) {
    const int add = (t >= off) ? sd[t - off] : 0;
    __syncthreads();
    sd[t] += add;
    __syncthreads();
  }
  if (t < 196) bsum[t] = sd[t] - v;   // exclusive
}

__global__ __launch_bounds__(256) void k_scanC(const int* __restrict__ deg,
    const int* __restrict__ bsum, int* __restrict__ rowptr)
{
  __shared__ int sd[256];
  const int t = threadIdx.x;
  const int i = blockIdx.x * 256 + t;
  const int v = (i < N_) ? deg[i] : 0;
  sd[t] = v;
  __syncthreads();
  for (int off = 1; off < 256; off <<= 1) {
    const int add = (t >= off) ? sd[t - off] : 0;
    __syncthreads();
    sd[t] += add;
    __syncthreads();
  }
  if (i <= N_) rowptr[i] = sd[t] - v + bsum[blockIdx.x];
}

__global__ __launch_bounds__(256) void k_fill(const int* __restrict__ ei,
    const int* __restrict__ rowptr, int* __restrict__ cursor,
    int* __restrict__ ebuf)
{
  const int i = blockIdx.x * 256 + threadIdx.x;
  if (i >= EP_) return;
  int s, d;
  if (i < E_) { s = ei[i]; d = ei[E_ + i]; }
  else        { s = i - E_; d = s; }
  const int pos = rowptr[d] + atomicAdd(&cursor[d], 1);
  ebuf[pos] = s;
}

// ---------------- Layer-1 aggregation (4 heads x 32 ch), + b1, ELU -------
__global__ __launch_bounds__(256) void k_agg1(const int* __restrict__ rowptr,
    const int* __restrict__ ebuf, const float* __restrict__ a_s,
    const float* __restrict__ a_d, const float* __restrict__ h,
    const float* __restrict__ b1, float* __restrict__ y)
{
  __shared__ float plds[4][128][4];
  __shared__ int   slds[4][128];
  const int w = threadIdx.x >> 6;
  const int l = threadIdx.x & 63;
  const int d = blockIdx.x * 4 + w;
  const int base = rowptr[d];
  const int deg  = rowptr[d + 1] - base;
  const float4 ad = *(const float4*)&a_d[(size_t)d * 4];
  float mx0 = -1e30f, mx1 = -1e30f, mx2 = -1e30f, mx3 = -1e30f;
  for (int i = l; i < deg; i += 64) {
    const int s = ebuf[base + i];
    const float4 as = *(const float4*)&a_s[(size_t)s * 4];
    float e0 = as.x + ad.x; e0 = e0 > 0.f ? e0 : SLOPE * e0;
    float e1 = as.y + ad.y; e1 = e1 > 0.f ? e1 : SLOPE * e1;
    float e2 = as.z + ad.z; e2 = e2 > 0.f ? e2 : SLOPE * e2;
    float e3 = as.w + ad.w; e3 = e3 > 0.f ? e3 : SLOPE * e3;
    if (i < 128) {
      slds[w][i] = s;
      plds[w][i][0] = e0; plds[w][i][1] = e1;
      plds[w][i][2] = e2; plds[w][i][3] = e3;
    }
    mx0 = fmaxf(mx0, e0); mx1 = fmaxf(mx1, e1);
    mx2 = fmaxf(mx2, e2); mx3 = fmaxf(mx3, e3);
  }
#pragma unroll
  for (int m = 32; m >= 1; m >>= 1) {
    mx0 = fmaxf(mx0, __shfl_xor(mx0, m));
    mx1 = fmaxf(mx1, __shfl_xor(mx1, m));
    mx2 = fmaxf(mx2, __shfl_xor(mx2, m));
    mx3 = fmaxf(mx3, __shfl_xor(mx3, m));
  }
  float sm0 = 0.f, sm1 = 0.f, sm2 = 0.f, sm3 = 0.f;
  for (int i = l; i < deg; i += 64) {
    float e0, e1, e2, e3;
    if (i < 128) {
      e0 = plds[w][i][0]; e1 = plds[w][i][1];
      e2 = plds[w][i][2]; e3 = plds[w][i][3];
    } else {
      const int s = ebuf[base + i];
      const float4 as = *(const float4*)&a_s[(size_t)s * 4];
      e0 = as.x + ad.x; e0 = e0 > 0.f ? e0 : SLOPE * e0;
      e1 = as.y + ad.y; e1 = e1 > 0.f ? e1 : SLOPE * e1;
      e2 = as.z + ad.z; e2 = e2 > 0.f ? e2 : SLOPE * e2;
      e3 = as.w + ad.w; e3 = e3 > 0.f ? e3 : SLOPE * e3;
    }
    const float p0 = __expf(e0 - mx0);
    const float p1 = __expf(e1 - mx1);
    const float p2 = __expf(e2 - mx2);
    const float p3 = __expf(e3 - mx3);
    if (i < 128) {
      plds[w][i][0] = p0; plds[w][i][1] = p1;
      plds[w][i][2] = p2; plds[w][i][3] = p3;
    }
    sm0 += p0; sm1 += p1; sm2 += p2; sm3 += p3;
  }
#pragma unroll
  for (int m = 32; m >= 1; m >>= 1) {
    sm0 += __shfl_xor(sm0, m);
    sm1 += __shfl_xor(sm1, m);
    sm2 += __shfl_xor(sm2, m);
    sm3 += __shfl_xor(sm3, m);
  }
  const float r0 = 1.f / (sm0 + 1e-16f);
  const float r1 = 1.f / (sm1 + 1e-16f);
  const float r2 = 1.f / (sm2 + 1e-16f);
  const float r3 = 1.f / (sm3 + 1e-16f);
  const bool hi = (l >= 32);
  const float mxA = hi ? mx1 : mx0;
  const float mxB = hi ? mx3 : mx2;
  const float rA  = hi ? r1 : r0;
  const float rB  = hi ? r3 : r2;
  const int hA = hi ? 1 : 0;
  const int hB = hA + 2;
  float accA = 0.f, accB = 0.f;
  for (int i = 0; i < deg; ++i) {
    int s; float pA, pB;
    if (i < 128) {
      s = slds[w][i];
      pA = plds[w][i][hA];
      pB = plds[w][i][hB];
    } else {
      s = ebuf[base + i];
      const float4 as = *(const float4*)&a_s[(size_t)s * 4];
      float eA = hi ? (as.y + ad.y) : (as.x + ad.x);
      eA = eA > 0.f ? eA : SLOPE * eA;
      float eB = hi ? (as.w + ad.w) : (as.z + ad.z);
      eB = eB > 0.f ? eB : SLOPE * eB;
      pA = __expf(eA - mxA);
      pB = __expf(eB - mxB);
    }
    const float* hr = h + (size_t)s * 128;
    accA = fmaf(pA, hr[l], accA);
    accB = fmaf(pB, hr[l + 64], accB);
  }
  const float oA = accA * rA + b1[l];
  const float oB = accB * rB + b1[l + 64];
  y[(size_t)d * 128 + l]      = oA > 0.f ? oA : expm1f(oA);
  y[(size_t)d * 128 + l + 64] = oB > 0.f ? oB : expm1f(oB);
}

// ---------------- Layer-2 aggregation (1 head x 64 ch), + b2 -------------
__global__ __launch_bounds__(256) void k_agg2(const int* __restrict__ rowptr,
    const int* __restrict__ ebuf, const float* __restrict__ a_s,
    const float* __restrict__ a_d, const float* __restrict__ h,
    const float* __restrict__ b2, float* __restrict__ out)
{
  __shared__ float plds[4][128];
  __shared__ int   slds[4][128];
  const int w = threadIdx.x >> 6;
  const int l = threadIdx.x & 63;
  const int d = blockIdx.x * 4 + w;
  const int base = rowptr[d];
  const int deg  = rowptr[d + 1] - base;
  const float ad = a_d[d];
  float mx = -1e30f;
  for (int i = l; i < deg; i += 64) {
    const int s = ebuf[base + i];
    float e = a_s[s] + ad; e = e > 0.f ? e : SLOPE * e;
    if (i < 128) { slds[w][i] = s; plds[w][i] = e; }
    mx = fmaxf(mx, e);
  }
#pragma unroll
  for (int m = 32; m >= 1; m >>= 1) mx = fmaxf(mx, __shfl_xor(mx, m));
  float sm = 0.f;
  for (int i = l; i < deg; i += 64) {
    float e;
    if (i < 128) e = plds[w][i];
    else { const int s = ebuf[base + i]; e = a_s[s] + ad; e = e > 0.f ? e : SLOPE * e; }
    const float p = __expf(e - mx);
    if (i < 128) plds[w][i] = p;
    sm += p;
  }
#pragma unroll
  for (int m = 32; m >= 1; m >>= 1) sm += __shfl_xor(sm, m);
  const float rv = 1.f / (sm + 1e-16f);
  float acc = 0.f;
  for (int i = 0; i < deg; ++i) {
    int s; float p;
    if (i < 128) { s = slds[w][i]; p = plds[w][i]; }
    else {
      s = ebuf[base + i];
      float e = a_s[s] + ad; e = e > 0.f ? e : SLOPE * e;
      p = __expf(e - mx);
    }
    acc = fmaf(p, h[(size_t)s * 64 + l], acc);
  }
  out[(size_t)d * 64 + l] = acc * rv + b2[l];
}

extern "C" void kernel_launch(void* const* d_in, const int* in_sizes, int n_in,
                              void* d_out, int out_size, void* d_ws, size_t ws_size,
                              hipStream_t stream) {
  const float* x     = (const float*)d_in[0];
  const int*   ei    = (const int*)d_in[1];
  const float* W1    = (const float*)d_in[2];
  const float* as1v  = (const float*)d_in[3];
  const float* ad1v  = (const float*)d_in[4];
  const float* b1    = (const float*)d_in[5];
  const float* W2    = (const float*)d_in[6];
  const float* as2v  = (const float*)d_in[7];
  const float* ad2v  = (const float*)d_in[8];
  const float* b2    = (const float*)d_in[9];
  float* out = (float*)d_out;

  char* ws = (char*)d_ws;
  float* h1   = (float*)(ws + OFF_H1);
  float* y1   = (float*)(ws + OFF_Y1);
  float* h2   = (float*)(ws + OFF_H2);
  float* a_s1 = (float*)(ws + OFF_AS1);
  float* a_d1 = (float*)(ws + OFF_AD1);
  float* a_s2 = (float*)(ws + OFF_AS2);
  float* a_d2 = (float*)(ws + OFF_AD2);
  int* deg    = (int*)(ws + OFF_DEG);
  int* rowptr = (int*)(ws + OFF_ROW);
  int* cursor = (int*)(ws + OFF_CUR);
  int* bsum   = (int*)(ws + OFF_BS);
  int* ebuf   = (int*)(ws + OFF_EB);

  hipMemsetAsync(deg, 0, (size_t)N_ * 4, stream);
  hipMemsetAsync(cursor, 0, (size_t)N_ * 4, stream);

  k_gemm1<<<N_ / 16, 256, 0, stream>>>(x, W1, as1v, ad1v, h1, a_s1, a_d1);
  k_deg<<<(EP_ + 255) / 256, 256, 0, stream>>>(ei, deg);
  k_scanA<<<196, 256, 0, stream>>>(deg, bsum);
  k_scanB<<<1, 256, 0, stream>>>(bsum);
  k_scanC<<<196, 256, 0, stream>>>(deg, bsum, rowptr);
  k_fill<<<(EP_ + 255) / 256, 256, 0, stream>>>(ei, rowptr, cursor, ebuf);
  k_agg1<<<N_ / 4, 256, 0, stream>>>(rowptr, ebuf, a_s1, a_d1, h1, b1, y1);
  k_gemm2<<<N_ / 16, 256, 0, stream>>>(y1, W2, as2v, ad2v, h2, a_s2, a_d2);
  k_agg2<<<N_ / 4, 256, 0, stream>>>(rowptr, ebuf, a_s2, a_d2, h2, b2, out);
}

// Round 3
// 281.745 us; speedup vs baseline: 1.1849x; 1.0083x over previous
//
#include <hip/hip_runtime.h>
#include <math.h>

namespace {
constexpr int N_   = 50000;
constexpr int E_   = 800000;
constexpr int EP_  = E_ + N_;   // edges + self loops = 850000
constexpr float SLOPE = 0.2f;

// workspace layout (bytes, 16B-aligned chunks)
constexpr size_t OFF_H1  = 0;                                   // [N][128] f32
constexpr size_t OFF_Y1  = OFF_H1  + (size_t)N_ * 128 * 4;      // [N][128] f32 (elu out)
constexpr size_t OFF_H2  = OFF_Y1  + (size_t)N_ * 128 * 4;      // [N][64] f32
constexpr size_t OFF_AS1 = OFF_H2  + (size_t)N_ * 64 * 4;       // [N][4]
constexpr size_t OFF_AD1 = OFF_AS1 + (size_t)N_ * 4 * 4;        // [N][4]
constexpr size_t OFF_AS2 = OFF_AD1 + (size_t)N_ * 4 * 4;        // [N]
constexpr size_t OFF_AD2 = OFF_AS2 + (size_t)N_ * 4;            // [N]
constexpr size_t OFF_DEG = OFF_AD2 + (size_t)N_ * 4;            // [N] int
constexpr size_t OFF_ROW = OFF_DEG + (size_t)N_ * 4;            // [N+1] int
constexpr size_t OFF_CUR = OFF_ROW + (((size_t)(N_ + 1) * 4 + 15) & ~(size_t)15); // [N] int
constexpr size_t OFF_BS  = OFF_CUR + (size_t)N_ * 4;            // [196] int (block sums)
constexpr size_t OFF_EB  = OFF_BS  + 1024;                      // [EP] int (src sorted by dst)
}

__device__ __forceinline__ float bcast_f(float v, int lane) {
  return __uint_as_float(__builtin_amdgcn_readlane(__float_as_uint(v), lane));
}
__device__ __forceinline__ int bcast_i(int v, int lane) {
  return __builtin_amdgcn_readlane(v, lane);
}

// ---------------- GEMM1: h1 = x @ W1 ; a_s1/a_d1 per head ----------------
// k-loop strip-mined (unroll 1, W chunk of 8 in regs) to keep VGPR low.
__global__ __launch_bounds__(256, 4) void k_gemm1(const float* __restrict__ x,
    const float* __restrict__ W, const float* __restrict__ av_s,
    const float* __restrict__ av_d, float* __restrict__ h,
    float* __restrict__ a_s, float* __restrict__ a_d)
{
  __shared__ float xs[16 * 128];
  const int t = threadIdx.x;
  const int rbase = blockIdx.x * 16;
  {
    const float4* xg = (const float4*)(x + (size_t)rbase * 128);
    float4* s4 = (float4*)xs;
    s4[t] = xg[t];
    s4[t + 256] = xg[t + 256];
  }
  __syncthreads();
  const int c = t & 127;
  const int rr = t >> 7;   // 0..1
  float acc[8] = {0, 0, 0, 0, 0, 0, 0, 0};
#pragma unroll 1
  for (int k0 = 0; k0 < 128; k0 += 8) {
    float w[8];
#pragma unroll
    for (int u = 0; u < 8; ++u) w[u] = W[(k0 + u) * 128 + c];
#pragma unroll
    for (int j = 0; j < 8; ++j) {
      const int r = rr + 2 * j;
      const float4 xa = *(const float4*)&xs[r * 128 + k0];
      const float4 xb = *(const float4*)&xs[r * 128 + k0 + 4];
      acc[j] = fmaf(xa.x, w[0], acc[j]);
      acc[j] = fmaf(xa.y, w[1], acc[j]);
      acc[j] = fmaf(xa.z, w[2], acc[j]);
      acc[j] = fmaf(xa.w, w[3], acc[j]);
      acc[j] = fmaf(xb.x, w[4], acc[j]);
      acc[j] = fmaf(xb.y, w[5], acc[j]);
      acc[j] = fmaf(xb.z, w[6], acc[j]);
      acc[j] = fmaf(xb.w, w[7], acc[j]);
    }
  }
  const float asc = av_s[c];
  const float adc = av_d[c];
#pragma unroll
  for (int j = 0; j < 8; ++j) {
    const int rg = rbase + rr + 2 * j;
    h[(size_t)rg * 128 + c] = acc[j];
    float ps = acc[j] * asc;
    float pd = acc[j] * adc;
#pragma unroll
    for (int m = 16; m >= 1; m >>= 1) {
      ps += __shfl_xor(ps, m);
      pd += __shfl_xor(pd, m);
    }
    if ((c & 31) == 0) {
      a_s[rg * 4 + (c >> 5)] = ps;
      a_d[rg * 4 + (c >> 5)] = pd;
    }
  }
}

// ---------------- GEMM2: h2 = y1 @ W2 ; a_s2/a_d2 (1 head) ----------------
__global__ __launch_bounds__(256, 4) void k_gemm2(const float* __restrict__ y,
    const float* __restrict__ W, const float* __restrict__ av_s,
    const float* __restrict__ av_d, float* __restrict__ h,
    float* __restrict__ a_s, float* __restrict__ a_d)
{
  __shared__ float ys[16 * 128];
  const int t = threadIdx.x;
  const int rbase = blockIdx.x * 16;
  {
    const float4* yg = (const float4*)(y + (size_t)rbase * 128);
    float4* s4 = (float4*)ys;
    s4[t] = yg[t];
    s4[t + 256] = yg[t + 256];
  }
  __syncthreads();
  const int c = t & 63;
  const int rr = t >> 6;   // 0..3
  float acc[4] = {0, 0, 0, 0};
#pragma unroll 1
  for (int k0 = 0; k0 < 128; k0 += 8) {
    float w[8];
#pragma unroll
    for (int u = 0; u < 8; ++u) w[u] = W[(k0 + u) * 64 + c];
#pragma unroll
    for (int j = 0; j < 4; ++j) {
      const int r = rr + 4 * j;
      const float4 ya = *(const float4*)&ys[r * 128 + k0];
      const float4 yb = *(const float4*)&ys[r * 128 + k0 + 4];
      acc[j] = fmaf(ya.x, w[0], acc[j]);
      acc[j] = fmaf(ya.y, w[1], acc[j]);
      acc[j] = fmaf(ya.z, w[2], acc[j]);
      acc[j] = fmaf(ya.w, w[3], acc[j]);
      acc[j] = fmaf(yb.x, w[4], acc[j]);
      acc[j] = fmaf(yb.y, w[5], acc[j]);
      acc[j] = fmaf(yb.z, w[6], acc[j]);
      acc[j] = fmaf(yb.w, w[7], acc[j]);
    }
  }
  const float asc = av_s[c];
  const float adc = av_d[c];
#pragma unroll
  for (int j = 0; j < 4; ++j) {
    const int rg = rbase + rr + 4 * j;
    h[(size_t)rg * 64 + c] = acc[j];
    float ps = acc[j] * asc;
    float pd = acc[j] * adc;
#pragma unroll
    for (int m = 32; m >= 1; m >>= 1) {
      ps += __shfl_xor(ps, m);
      pd += __shfl_xor(pd, m);
    }
    if (c == 0) { a_s[rg] = ps; a_d[rg] = pd; }
  }
}

// ---------------- CSR build ----------------
__global__ __launch_bounds__(256) void k_deg(const int* __restrict__ ei,
                                             int* __restrict__ deg)
{
  const int i = blockIdx.x * 256 + threadIdx.x;
  if (i >= EP_) return;
  const int d = (i < E_) ? ei[E_ + i] : (i - E_);
  atomicAdd(&deg[d], 1);
}

__global__ __launch_bounds__(256) void k_scanA(const int* __restrict__ deg,
                                               int* __restrict__ bsum)
{
  __shared__ int sd[256];
  const int t = threadIdx.x;
  const int i = blockIdx.x * 256 + t;
  sd[t] = (i < N_) ? deg[i] : 0;
  __syncthreads();
  for (int off = 128; off > 0; off >>= 1) {
    if (t < off) sd[t] += sd[t + off];
    __syncthreads();
  }
  if (t == 0) bsum[blockIdx.x] = sd[0];
}

__global__ __launch_bounds__(256) void k_scanB(int* __restrict__ bsum)
{
  __shared__ int sd[256];
  const int t = threadIdx.x;
  const int v = (t < 196) ? bsum[t] : 0;
  sd[t] = v;
  __syncthreads();
  for (int off = 1; off < 256; off <<= 1) {
    const int add = (t >= off) ? sd[t - off] : 0;
    __syncthreads();
    sd[t] += add;
    __syncthreads();
  }
  if (t < 196) bsum[t] = sd[t] - v;   // exclusive
}

__global__ __launch_bounds__(256) void k_scanC(const int* __restrict__ deg,
    const int* __restrict__ bsum, int* __restrict__ rowptr)
{
  __shared__ int sd[256];
  const int t = threadIdx.x;
  const int i = blockIdx.x * 256 + t;
  const int v = (i < N_) ? deg[i] : 0;
  sd[t] = v;
  __syncthreads();
  for (int off = 1; off < 256; off <<= 1) {
    const int add = (t >= off) ? sd[t - off] : 0;
    __syncthreads();
    sd[t] += add;
    __syncthreads();
  }
  if (i <= N_) rowptr[i] = sd[t] - v + bsum[blockIdx.x];
}

__global__ __launch_bounds__(256) void k_fill(const int* __restrict__ ei,
    const int* __restrict__ rowptr, int* __restrict__ cursor,
    int* __restrict__ ebuf)
{
  const int i = blockIdx.x * 256 + threadIdx.x;
  if (i >= EP_) return;
  int s, d;
  if (i < E_) { s = ei[i]; d = ei[E_ + i]; }
  else        { s = i - E_; d = s; }
  const int pos = rowptr[d] + atomicAdd(&cursor[d], 1);
  ebuf[pos] = s;
}

// ---------------- Layer-1 aggregation: 2 waves per dst (64 ch each) -----
// Softmax state held in registers (lane i <-> edge i, valid while deg<=64;
// any-deg fallback branch below). Phase-3 gather unrolled x4 with readlane
// broadcast (uniform lane index -> SGPR base) for ILP.
__global__ __launch_bounds__(256, 8) void k_agg1(const int* __restrict__ rowptr,
    const int* __restrict__ ebuf, const float* __restrict__ a_s,
    const float* __restrict__ a_d, const float* __restrict__ h,
    const float* __restrict__ b1, float* __restrict__ y)
{
  const int w = threadIdx.x >> 6;
  const int l = threadIdx.x & 63;
  const int d = blockIdx.x * 2 + (w >> 1);
  const int half = w & 1;              // which 64-channel half (heads 2h,2h+1)
  const int base = rowptr[d];
  const int deg  = rowptr[d + 1] - base;
  const float2 ad = *(const float2*)&a_d[(size_t)d * 4 + half * 2];
  const bool hi = (l >= 32);
  const float* __restrict__ hh = h + half * 64;
  float acc = 0.f;
  float rsel;

  if (deg <= 64) {
    // ---- fast path: edge i lives in lane i ----
    int   sreg = 0;
    float e0 = -1e30f, e1 = -1e30f;
    if (l < deg) {
      sreg = ebuf[base + l];
      const float2 as = *(const float2*)&a_s[(size_t)sreg * 4 + half * 2];
      e0 = as.x + ad.x; e0 = e0 > 0.f ? e0 : SLOPE * e0;
      e1 = as.y + ad.y; e1 = e1 > 0.f ? e1 : SLOPE * e1;
    }
    float mx0 = e0, mx1 = e1;
#pragma unroll
    for (int m = 32; m >= 1; m >>= 1) {
      mx0 = fmaxf(mx0, __shfl_xor(mx0, m));
      mx1 = fmaxf(mx1, __shfl_xor(mx1, m));
    }
    const float p0 = (l < deg) ? __expf(e0 - mx0) : 0.f;
    const float p1 = (l < deg) ? __expf(e1 - mx1) : 0.f;
    float sm0 = p0, sm1 = p1;
#pragma unroll
    for (int m = 32; m >= 1; m >>= 1) {
      sm0 += __shfl_xor(sm0, m);
      sm1 += __shfl_xor(sm1, m);
    }
    const float r0 = 1.f / (sm0 + 1e-16f);
    const float r1 = 1.f / (sm1 + 1e-16f);
    rsel = hi ? r1 : r0;
    int i = 0;
    for (; i + 4 <= deg; i += 4) {
      const int s0 = bcast_i(sreg, i);
      const int s1 = bcast_i(sreg, i + 1);
      const int s2 = bcast_i(sreg, i + 2);
      const int s3 = bcast_i(sreg, i + 3);
      const float pa0 = hi ? bcast_f(p1, i)     : bcast_f(p0, i);
      const float pa1 = hi ? bcast_f(p1, i + 1) : bcast_f(p0, i + 1);
      const float pa2 = hi ? bcast_f(p1, i + 2) : bcast_f(p0, i + 2);
      const float pa3 = hi ? bcast_f(p1, i + 3) : bcast_f(p0, i + 3);
      const float v0 = hh[(size_t)s0 * 128 + l];
      const float v1 = hh[(size_t)s1 * 128 + l];
      const float v2 = hh[(size_t)s2 * 128 + l];
      const float v3 = hh[(size_t)s3 * 128 + l];
      acc = fmaf(pa0, v0, acc);
      acc = fmaf(pa1, v1, acc);
      acc = fmaf(pa2, v2, acc);
      acc = fmaf(pa3, v3, acc);
    }
    for (; i < deg; ++i) {
      const int s = bcast_i(sreg, i);
      const float pa = hi ? bcast_f(p1, i) : bcast_f(p0, i);
      acc = fmaf(pa, hh[(size_t)s * 128 + l], acc);
    }
  } else {
    // ---- any-deg fallback (never taken for this graph, kept for safety) --
    float mx0 = -1e30f, mx1 = -1e30f;
    for (int i = l; i < deg; i += 64) {
      const int s = ebuf[base + i];
      const float2 as = *(const float2*)&a_s[(size_t)s * 4 + half * 2];
      float e0 = as.x + ad.x; e0 = e0 > 0.f ? e0 : SLOPE * e0;
      float e1 = as.y + ad.y; e1 = e1 > 0.f ? e1 : SLOPE * e1;
      mx0 = fmaxf(mx0, e0); mx1 = fmaxf(mx1, e1);
    }
#pragma unroll
    for (int m = 32; m >= 1; m >>= 1) {
      mx0 = fmaxf(mx0, __shfl_xor(mx0, m));
      mx1 = fmaxf(mx1, __shfl_xor(mx1, m));
    }
    float sm0 = 0.f, sm1 = 0.f;
    for (int i = l; i < deg; i += 64) {
      const int s = ebuf[base + i];
      const float2 as = *(const float2*)&a_s[(size_t)s * 4 + half * 2];
      float e0 = as.x + ad.x; e0 = e0 > 0.f ? e0 : SLOPE * e0;
      float e1 = as.y + ad.y; e1 = e1 > 0.f ? e1 : SLOPE * e1;
      sm0 += __expf(e0 - mx0); sm1 += __expf(e1 - mx1);
    }
#pragma unroll
    for (int m = 32; m >= 1; m >>= 1) {
      sm0 += __shfl_xor(sm0, m);
      sm1 += __shfl_xor(sm1, m);
    }
    const float r0 = 1.f / (sm0 + 1e-16f);
    const float r1 = 1.f / (sm1 + 1e-16f);
    rsel = hi ? r1 : r0;
    const float mxs = hi ? mx1 : mx0;
    for (int i = 0; i < deg; ++i) {
      const int s = ebuf[base + i];   // uniform broadcast load
      const float2 as = *(const float2*)&a_s[(size_t)s * 4 + half * 2];
      float e0 = as.x + ad.x; e0 = e0 > 0.f ? e0 : SLOPE * e0;
      float e1 = as.y + ad.y; e1 = e1 > 0.f ? e1 : SLOPE * e1;
      const float pa = __expf((hi ? e1 : e0) - mxs);
      acc = fmaf(pa, hh[(size_t)s * 128 + l], acc);
    }
  }
  const int cg = half * 64 + l;
  const float o = acc * rsel + b1[cg];
  y[(size_t)d * 128 + cg] = o > 0.f ? o : expm1f(o);
}

// ---------------- Layer-2 aggregation: 1 wave per dst (64 ch) -----------
__global__ __launch_bounds__(256, 8) void k_agg2(const int* __restrict__ rowptr,
    const int* __restrict__ ebuf, const float* __restrict__ a_s,
    const float* __restrict__ a_d, const float* __restrict__ h,
    const float* __restrict__ b2, float* __restrict__ out)
{
  const int w = threadIdx.x >> 6;
  const int l = threadIdx.x & 63;
  const int d = blockIdx.x * 4 + w;
  const int base = rowptr[d];
  const int deg  = rowptr[d + 1] - base;
  const float ad = a_d[d];
  float acc = 0.f;
  float rv;

  if (deg <= 64) {
    int   sreg = 0;
    float e = -1e30f;
    if (l < deg) {
      sreg = ebuf[base + l];
      e = a_s[sreg] + ad; e = e > 0.f ? e : SLOPE * e;
    }
    float mx = e;
#pragma unroll
    for (int m = 32; m >= 1; m >>= 1) mx = fmaxf(mx, __shfl_xor(mx, m));
    const float p = (l < deg) ? __expf(e - mx) : 0.f;
    float sm = p;
#pragma unroll
    for (int m = 32; m >= 1; m >>= 1) sm += __shfl_xor(sm, m);
    rv = 1.f / (sm + 1e-16f);
    int i = 0;
    for (; i + 4 <= deg; i += 4) {
      const int s0 = bcast_i(sreg, i);
      const int s1 = bcast_i(sreg, i + 1);
      const int s2 = bcast_i(sreg, i + 2);
      const int s3 = bcast_i(sreg, i + 3);
      const float pa0 = bcast_f(p, i);
      const float pa1 = bcast_f(p, i + 1);
      const float pa2 = bcast_f(p, i + 2);
      const float pa3 = bcast_f(p, i + 3);
      const float v0 = h[(size_t)s0 * 64 + l];
      const float v1 = h[(size_t)s1 * 64 + l];
      const float v2 = h[(size_t)s2 * 64 + l];
      const float v3 = h[(size_t)s3 * 64 + l];
      acc = fmaf(pa0, v0, acc);
      acc = fmaf(pa1, v1, acc);
      acc = fmaf(pa2, v2, acc);
      acc = fmaf(pa3, v3, acc);
    }
    for (; i < deg; ++i) {
      const int s = bcast_i(sreg, i);
      acc = fmaf(bcast_f(p, i), h[(size_t)s * 64 + l], acc);
    }
  } else {
    float mx = -1e30f;
    for (int i = l; i < deg; i += 64) {
      const int s = ebuf[base + i];
      float e = a_s[s] + ad; e = e > 0.f ? e : SLOPE * e;
      mx = fmaxf(mx, e);
    }
#pragma unroll
    for (int m = 32; m >= 1; m >>= 1) mx = fmaxf(mx, __shfl_xor(mx, m));
    float sm = 0.f;
    for (int i = l; i < deg; i += 64) {
      const int s = ebuf[base + i];
      float e = a_s[s] + ad; e = e > 0.f ? e : SLOPE * e;
      sm += __expf(e - mx);
    }
#pragma unroll
    for (int m = 32; m >= 1; m >>= 1) sm += __shfl_xor(sm, m);
    rv = 1.f / (sm + 1e-16f);
    for (int i = 0; i < deg; ++i) {
      const int s = ebuf[base + i];
      float e = a_s[s] + ad; e = e > 0.f ? e : SLOPE * e;
      acc = fmaf(__expf(e - mx), h[(size_t)s * 64 + l], acc);
    }
  }
  out[(size_t)d * 64 + l] = acc * rv + b2[l];
}

extern "C" void kernel_launch(void* const* d_in, const int* in_sizes, int n_in,
                              void* d_out, int out_size, void* d_ws, size_t ws_size,
                              hipStream_t stream) {
  const float* x     = (const float*)d_in[0];
  const int*   ei    = (const int*)d_in[1];
  const float* W1    = (const float*)d_in[2];
  const float* as1v  = (const float*)d_in[3];
  const float* ad1v  = (const float*)d_in[4];
  const float* b1    = (const float*)d_in[5];
  const float* W2    = (const float*)d_in[6];
  const float* as2v  = (const float*)d_in[7];
  const float* ad2v  = (const float*)d_in[8];
  const float* b2    = (const float*)d_in[9];
  float* out = (float*)d_out;

  char* ws = (char*)d_ws;
  float* h1   = (float*)(ws + OFF_H1);
  float* y1   = (float*)(ws + OFF_Y1);
  float* h2   = (float*)(ws + OFF_H2);
  float* a_s1 = (float*)(ws + OFF_AS1);
  float* a_d1 = (float*)(ws + OFF_AD1);
  float* a_s2 = (float*)(ws + OFF_AS2);
  float* a_d2 = (float*)(ws + OFF_AD2);
  int* deg    = (int*)(ws + OFF_DEG);
  int* rowptr = (int*)(ws + OFF_ROW);
  int* cursor = (int*)(ws + OFF_CUR);
  int* bsum   = (int*)(ws + OFF_BS);
  int* ebuf   = (int*)(ws + OFF_EB);

  hipMemsetAsync(deg, 0, (size_t)N_ * 4, stream);
  hipMemsetAsync(cursor, 0, (size_t)N_ * 4, stream);

  k_gemm1<<<N_ / 16, 256, 0, stream>>>(x, W1, as1v, ad1v, h1, a_s1, a_d1);
  k_deg<<<(EP_ + 255) / 256, 256, 0, stream>>>(ei, deg);
  k_scanA<<<196, 256, 0, stream>>>(deg, bsum);
  k_scanB<<<1, 256, 0, stream>>>(bsum);
  k_scanC<<<196, 256, 0, stream>>>(deg, bsum, rowptr);
  k_fill<<<(EP_ + 255) / 256, 256, 0, stream>>>(ei, rowptr, cursor, ebuf);
  k_agg1<<<N_ / 2, 256, 0, stream>>>(rowptr, ebuf, a_s1, a_d1, h1, b1, y1);
  k_gemm2<<<N_ / 16, 256, 0, stream>>>(y1, W2, as2v, ad2v, h2, a_s2, a_d2);
  k_agg2<<<N_ / 4, 256, 0, stream>>>(rowptr, ebuf, a_s2, a_d2, h2, b2, out);
}

// Round 4
// 253.644 us; speedup vs baseline: 1.3162x; 1.1108x over previous
//
#include <hip/hip_runtime.h>
#include <math.h>

namespace {
constexpr int N_   = 50000;
constexpr int E_   = 800000;
constexpr int EP_  = E_ + N_;   // edges + self loops = 850000
constexpr float SLOPE = 0.2f;

// workspace layout (bytes, 16B-aligned chunks)
constexpr size_t OFF_H1  = 0;                                    // [N][128] bf16
constexpr size_t OFF_Y1  = OFF_H1  + (size_t)N_ * 128 * 2;       // [N][128] f32 (elu out)
constexpr size_t OFF_H2  = OFF_Y1  + (size_t)N_ * 128 * 4;       // [N][64] bf16
constexpr size_t OFF_AS1 = OFF_H2  + (size_t)N_ * 64 * 2;        // [N][4]
constexpr size_t OFF_AD1 = OFF_AS1 + (size_t)N_ * 4 * 4;         // [N][4]
constexpr size_t OFF_AS2 = OFF_AD1 + (size_t)N_ * 4 * 4;         // [N]
constexpr size_t OFF_AD2 = OFF_AS2 + (size_t)N_ * 4;             // [N]
constexpr size_t OFF_DEG = OFF_AD2 + (size_t)N_ * 4;             // [N] int
constexpr size_t OFF_ROW = OFF_DEG + (size_t)N_ * 4;             // [N+1] int
constexpr size_t OFF_CUR = OFF_ROW + (((size_t)(N_ + 1) * 4 + 15) & ~(size_t)15); // [N] int
constexpr size_t OFF_BS  = OFF_CUR + (size_t)N_ * 4;             // [196] int (block sums)
constexpr size_t OFF_EB  = OFF_BS  + 1024;                       // [EP] int (src sorted by dst)
}

__device__ __forceinline__ float bcast_f(float v, int lane) {
  return __uint_as_float(__builtin_amdgcn_readlane(__float_as_uint(v), lane));
}
__device__ __forceinline__ int bcast_i(int v, int lane) {
  return __builtin_amdgcn_readlane(v, lane);
}
__device__ __forceinline__ unsigned short f2bf(float x) {   // RNE
  unsigned u = __float_as_uint(x);
  return (unsigned short)((u + 0x7FFFu + ((u >> 16) & 1u)) >> 16);
}
__device__ __forceinline__ float bf_lo(unsigned u) { return __uint_as_float(u << 16); }
__device__ __forceinline__ float bf_hi(unsigned u) { return __uint_as_float(u & 0xFFFF0000u); }

// ---------------- GEMM1: h1 = x @ W1 (bf16 out) ; a_s1/a_d1 per head -----
__global__ __launch_bounds__(256, 4) void k_gemm1(const float* __restrict__ x,
    const float* __restrict__ W, const float* __restrict__ av_s,
    const float* __restrict__ av_d, unsigned short* __restrict__ hbf,
    float* __restrict__ a_s, float* __restrict__ a_d)
{
  __shared__ float xs[16 * 128];
  const int t = threadIdx.x;
  const int rbase = blockIdx.x * 16;
  {
    const float4* xg = (const float4*)(x + (size_t)rbase * 128);
    float4* s4 = (float4*)xs;
    s4[t] = xg[t];
    s4[t + 256] = xg[t + 256];
  }
  __syncthreads();
  const int c = t & 127;
  const int rr = t >> 7;   // 0..1
  float acc[8] = {0, 0, 0, 0, 0, 0, 0, 0};
#pragma unroll 1
  for (int k0 = 0; k0 < 128; k0 += 8) {
    float w[8];
#pragma unroll
    for (int u = 0; u < 8; ++u) w[u] = W[(k0 + u) * 128 + c];
#pragma unroll
    for (int j = 0; j < 8; ++j) {
      const int r = rr + 2 * j;
      const float4 xa = *(const float4*)&xs[r * 128 + k0];
      const float4 xb = *(const float4*)&xs[r * 128 + k0 + 4];
      acc[j] = fmaf(xa.x, w[0], acc[j]);
      acc[j] = fmaf(xa.y, w[1], acc[j]);
      acc[j] = fmaf(xa.z, w[2], acc[j]);
      acc[j] = fmaf(xa.w, w[3], acc[j]);
      acc[j] = fmaf(xb.x, w[4], acc[j]);
      acc[j] = fmaf(xb.y, w[5], acc[j]);
      acc[j] = fmaf(xb.z, w[6], acc[j]);
      acc[j] = fmaf(xb.w, w[7], acc[j]);
    }
  }
  const float asc = av_s[c];
  const float adc = av_d[c];
#pragma unroll
  for (int j = 0; j < 8; ++j) {
    const int rg = rbase + rr + 2 * j;
    hbf[(size_t)rg * 128 + c] = f2bf(acc[j]);
    float ps = acc[j] * asc;
    float pd = acc[j] * adc;
#pragma unroll
    for (int m = 16; m >= 1; m >>= 1) {
      ps += __shfl_xor(ps, m);
      pd += __shfl_xor(pd, m);
    }
    if ((c & 31) == 0) {
      a_s[rg * 4 + (c >> 5)] = ps;
      a_d[rg * 4 + (c >> 5)] = pd;
    }
  }
}

// ---------------- GEMM2: h2 = y1 @ W2 (bf16 out) ; a_s2/a_d2 (1 head) ----
__global__ __launch_bounds__(256, 4) void k_gemm2(const float* __restrict__ y,
    const float* __restrict__ W, const float* __restrict__ av_s,
    const float* __restrict__ av_d, unsigned short* __restrict__ hbf,
    float* __restrict__ a_s, float* __restrict__ a_d)
{
  __shared__ float ys[16 * 128];
  const int t = threadIdx.x;
  const int rbase = blockIdx.x * 16;
  {
    const float4* yg = (const float4*)(y + (size_t)rbase * 128);
    float4* s4 = (float4*)ys;
    s4[t] = yg[t];
    s4[t + 256] = yg[t + 256];
  }
  __syncthreads();
  const int c = t & 63;
  const int rr = t >> 6;   // 0..3
  float acc[4] = {0, 0, 0, 0};
#pragma unroll 1
  for (int k0 = 0; k0 < 128; k0 += 8) {
    float w[8];
#pragma unroll
    for (int u = 0; u < 8; ++u) w[u] = W[(k0 + u) * 64 + c];
#pragma unroll
    for (int j = 0; j < 4; ++j) {
      const int r = rr + 4 * j;
      const float4 ya = *(const float4*)&ys[r * 128 + k0];
      const float4 yb = *(const float4*)&ys[r * 128 + k0 + 4];
      acc[j] = fmaf(ya.x, w[0], acc[j]);
      acc[j] = fmaf(ya.y, w[1], acc[j]);
      acc[j] = fmaf(ya.z, w[2], acc[j]);
      acc[j] = fmaf(ya.w, w[3], acc[j]);
      acc[j] = fmaf(yb.x, w[4], acc[j]);
      acc[j] = fmaf(yb.y, w[5], acc[j]);
      acc[j] = fmaf(yb.z, w[6], acc[j]);
      acc[j] = fmaf(yb.w, w[7], acc[j]);
    }
  }
  const float asc = av_s[c];
  const float adc = av_d[c];
#pragma unroll
  for (int j = 0; j < 4; ++j) {
    const int rg = rbase + rr + 4 * j;
    hbf[(size_t)rg * 64 + c] = f2bf(acc[j]);
    float ps = acc[j] * asc;
    float pd = acc[j] * adc;
#pragma unroll
    for (int m = 32; m >= 1; m >>= 1) {
      ps += __shfl_xor(ps, m);
      pd += __shfl_xor(pd, m);
    }
    if (c == 0) { a_s[rg] = ps; a_d[rg] = pd; }
  }
}

// ---------------- CSR build ----------------
__global__ __launch_bounds__(256) void k_deg(const int* __restrict__ ei,
                                             int* __restrict__ deg)
{
  const int i = blockIdx.x * 256 + threadIdx.x;
  if (i >= EP_) return;
  const int d = (i < E_) ? ei[E_ + i] : (i - E_);
  atomicAdd(&deg[d], 1);
}

__global__ __launch_bounds__(256) void k_scanA(const int* __restrict__ deg,
                                               int* __restrict__ bsum)
{
  __shared__ int sd[256];
  const int t = threadIdx.x;
  const int i = blockIdx.x * 256 + t;
  sd[t] = (i < N_) ? deg[i] : 0;
  __syncthreads();
  for (int off = 128; off > 0; off >>= 1) {
    if (t < off) sd[t] += sd[t + off];
    __syncthreads();
  }
  if (t == 0) bsum[blockIdx.x] = sd[0];
}

__global__ __launch_bounds__(256) void k_scanB(int* __restrict__ bsum)
{
  __shared__ int sd[256];
  const int t = threadIdx.x;
  const int v = (t < 196) ? bsum[t] : 0;
  sd[t] = v;
  __syncthreads();
  for (int off = 1; off < 256; off <<= 1) {
    const int add = (t >= off) ? sd[t - off] : 0;
    __syncthreads();
    sd[t] += add;
    __syncthreads();
  }
  if (t < 196) bsum[t] = sd[t] - v;   // exclusive
}

__global__ __launch_bounds__(256) void k_scanC(const int* __restrict__ deg,
    const int* __restrict__ bsum, int* __restrict__ rowptr)
{
  __shared__ int sd[256];
  const int t = threadIdx.x;
  const int i = blockIdx.x * 256 + t;
  const int v = (i < N_) ? deg[i] : 0;
  sd[t] = v;
  __syncthreads();
  for (int off = 1; off < 256; off <<= 1) {
    const int add = (t >= off) ? sd[t - off] : 0;
    __syncthreads();
    sd[t] += add;
    __syncthreads();
  }
  if (i <= N_) rowptr[i] = sd[t] - v + bsum[blockIdx.x];
}

__global__ __launch_bounds__(256) void k_fill(const int* __restrict__ ei,
    const int* __restrict__ rowptr, int* __restrict__ cursor,
    int* __restrict__ ebuf)
{
  const int i = blockIdx.x * 256 + threadIdx.x;
  if (i >= EP_) return;
  int s, d;
  if (i < E_) { s = ei[i]; d = ei[E_ + i]; }
  else        { s = i - E_; d = s; }
  const int pos = rowptr[d] + atomicAdd(&cursor[d], 1);
  ebuf[pos] = s;
}

// ---------------- Layer-1 aggregation: 1 wave/dst, bf16 h, 128 ch -------
// Lane l owns channel pair (2l, 2l+1); head = l>>4. Softmax state in regs
// (lane i <-> edge i while deg<=64; fallback below). Gather unrolled x4.
__global__ __launch_bounds__(256, 8) void k_agg1(const int* __restrict__ rowptr,
    const int* __restrict__ ebuf, const float* __restrict__ a_s,
    const float* __restrict__ a_d, const unsigned short* __restrict__ hbf,
    const float* __restrict__ b1, float* __restrict__ y)
{
  const int w = threadIdx.x >> 6;
  const int l = threadIdx.x & 63;
  const int d = blockIdx.x * 4 + w;
  const int base = rowptr[d];
  const int deg  = rowptr[d + 1] - base;
  const float4 ad = *(const float4*)&a_d[(size_t)d * 4];
  const bool hi = (l >= 32);
  const bool b4 = ((l >> 4) & 1) != 0;
  float acc0 = 0.f, acc1 = 0.f;
  float r0, r1, r2, r3;

  if (deg <= 64) {
    int   sreg = 0;
    float e0 = -1e30f, e1 = -1e30f, e2 = -1e30f, e3 = -1e30f;
    if (l < deg) {
      sreg = ebuf[base + l];
      const float4 as = *(const float4*)&a_s[(size_t)sreg * 4];
      e0 = as.x + ad.x; e0 = e0 > 0.f ? e0 : SLOPE * e0;
      e1 = as.y + ad.y; e1 = e1 > 0.f ? e1 : SLOPE * e1;
      e2 = as.z + ad.z; e2 = e2 > 0.f ? e2 : SLOPE * e2;
      e3 = as.w + ad.w; e3 = e3 > 0.f ? e3 : SLOPE * e3;
    }
    float mx0 = e0, mx1 = e1, mx2 = e2, mx3 = e3;
#pragma unroll
    for (int m = 32; m >= 1; m >>= 1) {
      mx0 = fmaxf(mx0, __shfl_xor(mx0, m));
      mx1 = fmaxf(mx1, __shfl_xor(mx1, m));
      mx2 = fmaxf(mx2, __shfl_xor(mx2, m));
      mx3 = fmaxf(mx3, __shfl_xor(mx3, m));
    }
    const float p0 = (l < deg) ? __expf(e0 - mx0) : 0.f;
    const float p1 = (l < deg) ? __expf(e1 - mx1) : 0.f;
    const float p2 = (l < deg) ? __expf(e2 - mx2) : 0.f;
    const float p3 = (l < deg) ? __expf(e3 - mx3) : 0.f;
    float sm0 = p0, sm1 = p1, sm2 = p2, sm3 = p3;
#pragma unroll
    for (int m = 32; m >= 1; m >>= 1) {
      sm0 += __shfl_xor(sm0, m);
      sm1 += __shfl_xor(sm1, m);
      sm2 += __shfl_xor(sm2, m);
      sm3 += __shfl_xor(sm3, m);
    }
    r0 = 1.f / (sm0 + 1e-16f);
    r1 = 1.f / (sm1 + 1e-16f);
    r2 = 1.f / (sm2 + 1e-16f);
    r3 = 1.f / (sm3 + 1e-16f);
    int i = 0;
    for (; i + 4 <= deg; i += 4) {
#pragma unroll
      for (int u = 0; u < 4; ++u) {
        const int   s  = bcast_i(sreg, i + u);
        const float q0 = bcast_f(p0, i + u);
        const float q1 = bcast_f(p1, i + u);
        const float q2 = bcast_f(p2, i + u);
        const float q3 = bcast_f(p3, i + u);
        const float pa = hi ? (b4 ? q3 : q2) : (b4 ? q1 : q0);
        const unsigned uu = ((const unsigned*)(hbf + (size_t)s * 128))[l];
        acc0 = fmaf(pa, bf_lo(uu), acc0);
        acc1 = fmaf(pa, bf_hi(uu), acc1);
      }
    }
    for (; i < deg; ++i) {
      const int   s  = bcast_i(sreg, i);
      const float q0 = bcast_f(p0, i);
      const float q1 = bcast_f(p1, i);
      const float q2 = bcast_f(p2, i);
      const float q3 = bcast_f(p3, i);
      const float pa = hi ? (b4 ? q3 : q2) : (b4 ? q1 : q0);
      const unsigned uu = ((const unsigned*)(hbf + (size_t)s * 128))[l];
      acc0 = fmaf(pa, bf_lo(uu), acc0);
      acc1 = fmaf(pa, bf_hi(uu), acc1);
    }
  } else {
    // ---- any-deg fallback (never taken for this graph, kept for safety) --
    float mx0 = -1e30f, mx1 = -1e30f, mx2 = -1e30f, mx3 = -1e30f;
    for (int i = l; i < deg; i += 64) {
      const int s = ebuf[base + i];
      const float4 as = *(const float4*)&a_s[(size_t)s * 4];
      float e0 = as.x + ad.x; e0 = e0 > 0.f ? e0 : SLOPE * e0;
      float e1 = as.y + ad.y; e1 = e1 > 0.f ? e1 : SLOPE * e1;
      float e2 = as.z + ad.z; e2 = e2 > 0.f ? e2 : SLOPE * e2;
      float e3 = as.w + ad.w; e3 = e3 > 0.f ? e3 : SLOPE * e3;
      mx0 = fmaxf(mx0, e0); mx1 = fmaxf(mx1, e1);
      mx2 = fmaxf(mx2, e2); mx3 = fmaxf(mx3, e3);
    }
#pragma unroll
    for (int m = 32; m >= 1; m >>= 1) {
      mx0 = fmaxf(mx0, __shfl_xor(mx0, m));
      mx1 = fmaxf(mx1, __shfl_xor(mx1, m));
      mx2 = fmaxf(mx2, __shfl_xor(mx2, m));
      mx3 = fmaxf(mx3, __shfl_xor(mx3, m));
    }
    float sm0 = 0.f, sm1 = 0.f, sm2 = 0.f, sm3 = 0.f;
    for (int i = l; i < deg; i += 64) {
      const int s = ebuf[base + i];
      const float4 as = *(const float4*)&a_s[(size_t)s * 4];
      float e0 = as.x + ad.x; e0 = e0 > 0.f ? e0 : SLOPE * e0;
      float e1 = as.y + ad.y; e1 = e1 > 0.f ? e1 : SLOPE * e1;
      float e2 = as.z + ad.z; e2 = e2 > 0.f ? e2 : SLOPE * e2;
      float e3 = as.w + ad.w; e3 = e3 > 0.f ? e3 : SLOPE * e3;
      sm0 += __expf(e0 - mx0); sm1 += __expf(e1 - mx1);
      sm2 += __expf(e2 - mx2); sm3 += __expf(e3 - mx3);
    }
#pragma unroll
    for (int m = 32; m >= 1; m >>= 1) {
      sm0 += __shfl_xor(sm0, m);
      sm1 += __shfl_xor(sm1, m);
      sm2 += __shfl_xor(sm2, m);
      sm3 += __shfl_xor(sm3, m);
    }
    r0 = 1.f / (sm0 + 1e-16f);
    r1 = 1.f / (sm1 + 1e-16f);
    r2 = 1.f / (sm2 + 1e-16f);
    r3 = 1.f / (sm3 + 1e-16f);
    const float mxs = hi ? (b4 ? mx3 : mx2) : (b4 ? mx1 : mx0);
    for (int i = 0; i < deg; ++i) {
      const int s = ebuf[base + i];
      const float4 as = *(const float4*)&a_s[(size_t)s * 4];
      float e0 = as.x + ad.x; e0 = e0 > 0.f ? e0 : SLOPE * e0;
      float e1 = as.y + ad.y; e1 = e1 > 0.f ? e1 : SLOPE * e1;
      float e2 = as.z + ad.z; e2 = e2 > 0.f ? e2 : SLOPE * e2;
      float e3 = as.w + ad.w; e3 = e3 > 0.f ? e3 : SLOPE * e3;
      const float es = hi ? (b4 ? e3 : e2) : (b4 ? e1 : e0);
      const float pa = __expf(es - mxs);
      const unsigned uu = ((const unsigned*)(hbf + (size_t)s * 128))[l];
      acc0 = fmaf(pa, bf_lo(uu), acc0);
      acc1 = fmaf(pa, bf_hi(uu), acc1);
    }
  }
  const float rsel = hi ? (b4 ? r3 : r2) : (b4 ? r1 : r0);
  const int c0 = 2 * l;
  const float2 bb = *(const float2*)&b1[c0];
  float o0 = acc0 * rsel + bb.x;
  float o1 = acc1 * rsel + bb.y;
  o0 = o0 > 0.f ? o0 : expm1f(o0);
  o1 = o1 > 0.f ? o1 : expm1f(o1);
  *(float2*)&y[(size_t)d * 128 + c0] = make_float2(o0, o1);
}

// ---------------- Layer-2 aggregation: 1 wave/dst, bf16 h, 64 ch --------
// Lanes 0-31 process even edges, 32-63 odd edges (ch pair index l&31);
// halves merged with one shfl_xor(32) at the end.
__global__ __launch_bounds__(256, 8) void k_agg2(const int* __restrict__ rowptr,
    const int* __restrict__ ebuf, const float* __restrict__ a_s,
    const float* __restrict__ a_d, const unsigned short* __restrict__ hbf,
    const float* __restrict__ b2, float* __restrict__ out)
{
  const int w = threadIdx.x >> 6;
  const int l = threadIdx.x & 63;
  const int lh = l & 31;
  const bool hi = (l >= 32);
  const int d = blockIdx.x * 4 + w;
  const int base = rowptr[d];
  const int deg  = rowptr[d + 1] - base;
  const float ad = a_d[d];
  float acc0 = 0.f, acc1 = 0.f;
  float rv;

  if (deg <= 64) {
    int   sreg = 0;
    float e = -1e30f;
    if (l < deg) {
      sreg = ebuf[base + l];
      e = a_s[sreg] + ad; e = e > 0.f ? e : SLOPE * e;
    }
    float mx = e;
#pragma unroll
    for (int m = 32; m >= 1; m >>= 1) mx = fmaxf(mx, __shfl_xor(mx, m));
    const float p = (l < deg) ? __expf(e - mx) : 0.f;
    float sm = p;
#pragma unroll
    for (int m = 32; m >= 1; m >>= 1) sm += __shfl_xor(sm, m);
    rv = 1.f / (sm + 1e-16f);
    int i = 0;
    for (; i + 4 <= deg; i += 4) {
#pragma unroll
      for (int u = 0; u < 4; u += 2) {
        const int   sA = bcast_i(sreg, i + u);
        const int   sB = bcast_i(sreg, i + u + 1);
        const float pA = bcast_f(p, i + u);
        const float pB = bcast_f(p, i + u + 1);
        const int   s  = hi ? sB : sA;
        const float pp = hi ? pB : pA;
        const unsigned uu = ((const unsigned*)(hbf + (size_t)s * 64))[lh];
        acc0 = fmaf(pp, bf_lo(uu), acc0);
        acc1 = fmaf(pp, bf_hi(uu), acc1);
      }
    }
    for (; i < deg; ++i) {
      const int   s  = bcast_i(sreg, i);
      const float pp = hi ? 0.f : bcast_f(p, i);
      const unsigned uu = ((const unsigned*)(hbf + (size_t)s * 64))[lh];
      acc0 = fmaf(pp, bf_lo(uu), acc0);
      acc1 = fmaf(pp, bf_hi(uu), acc1);
    }
  } else {
    float mx = -1e30f;
    for (int i = l; i < deg; i += 64) {
      const int s = ebuf[base + i];
      float e = a_s[s] + ad; e = e > 0.f ? e : SLOPE * e;
      mx = fmaxf(mx, e);
    }
#pragma unroll
    for (int m = 32; m >= 1; m >>= 1) mx = fmaxf(mx, __shfl_xor(mx, m));
    float sm = 0.f;
    for (int i = l; i < deg; i += 64) {
      const int s = ebuf[base + i];
      float e = a_s[s] + ad; e = e > 0.f ? e : SLOPE * e;
      sm += __expf(e - mx);
    }
#pragma unroll
    for (int m = 32; m >= 1; m >>= 1) sm += __shfl_xor(sm, m);
    rv = 1.f / (sm + 1e-16f);
    for (int i = 0; i < deg; ++i) {
      const int s = ebuf[base + i];
      float e = a_s[s] + ad; e = e > 0.f ? e : SLOPE * e;
      const float pp = hi ? 0.f : __expf(e - mx);
      const unsigned uu = ((const unsigned*)(hbf + (size_t)s * 64))[lh];
      acc0 = fmaf(pp, bf_lo(uu), acc0);
      acc1 = fmaf(pp, bf_hi(uu), acc1);
    }
  }
  acc0 += __shfl_xor(acc0, 32);
  acc1 += __shfl_xor(acc1, 32);
  if (!hi) {
    const int c0 = 2 * lh;
    const float2 bb = *(const float2*)&b2[c0];
    *(float2*)&out[(size_t)d * 64 + c0] =
        make_float2(acc0 * rv + bb.x, acc1 * rv + bb.y);
  }
}

extern "C" void kernel_launch(void* const* d_in, const int* in_sizes, int n_in,
                              void* d_out, int out_size, void* d_ws, size_t ws_size,
                              hipStream_t stream) {
  const float* x     = (const float*)d_in[0];
  const int*   ei    = (const int*)d_in[1];
  const float* W1    = (const float*)d_in[2];
  const float* as1v  = (const float*)d_in[3];
  const float* ad1v  = (const float*)d_in[4];
  const float* b1    = (const float*)d_in[5];
  const float* W2    = (const float*)d_in[6];
  const float* as2v  = (const float*)d_in[7];
  const float* ad2v  = (const float*)d_in[8];
  const float* b2    = (const float*)d_in[9];
  float* out = (float*)d_out;

  char* ws = (char*)d_ws;
  unsigned short* h1 = (unsigned short*)(ws + OFF_H1);
  float* y1   = (float*)(ws + OFF_Y1);
  unsigned short* h2 = (unsigned short*)(ws + OFF_H2);
  float* a_s1 = (float*)(ws + OFF_AS1);
  float* a_d1 = (float*)(ws + OFF_AD1);
  float* a_s2 = (float*)(ws + OFF_AS2);
  float* a_d2 = (float*)(ws + OFF_AD2);
  int* deg    = (int*)(ws + OFF_DEG);
  int* rowptr = (int*)(ws + OFF_ROW);
  int* cursor = (int*)(ws + OFF_CUR);
  int* bsum   = (int*)(ws + OFF_BS);
  int* ebuf   = (int*)(ws + OFF_EB);

  hipMemsetAsync(deg, 0, (size_t)N_ * 4, stream);
  hipMemsetAsync(cursor, 0, (size_t)N_ * 4, stream);

  k_gemm1<<<N_ / 16, 256, 0, stream>>>(x, W1, as1v, ad1v, h1, a_s1, a_d1);
  k_deg<<<(EP_ + 255) / 256, 256, 0, stream>>>(ei, deg);
  k_scanA<<<196, 256, 0, stream>>>(deg, bsum);
  k_scanB<<<1, 256, 0, stream>>>(bsum);
  k_scanC<<<196, 256, 0, stream>>>(deg, bsum, rowptr);
  k_fill<<<(EP_ + 255) / 256, 256, 0, stream>>>(ei, rowptr, cursor, ebuf);
  k_agg1<<<N_ / 4, 256, 0, stream>>>(rowptr, ebuf, a_s1, a_d1, h1, b1, y1);
  k_gemm2<<<N_ / 16, 256, 0, stream>>>(y1, W2, as2v, ad2v, h2, a_s2, a_d2);
  k_agg2<<<N_ / 4, 256, 0, stream>>>(rowptr, ebuf, a_s2, a_d2, h2, b2, out);
}

// Round 5
// 208.342 us; speedup vs baseline: 1.6024x; 1.2174x over previous
//
#include <hip/hip_runtime.h>
#include <math.h>

namespace {
constexpr int N_   = 50000;
constexpr int E_   = 800000;
constexpr int EP_  = E_ + N_;   // edges + self loops = 850000
constexpr float SLOPE = 0.2f;

constexpr int NB_    = (N_ + 127) / 128;          // 391 coarse buckets (dst>>7)
constexpr int CHUNK_ = 8192;                      // edges per scatter block
constexpr int NBLKA_ = (EP_ + CHUNK_ - 1) / CHUNK_; // 104
constexpr int CAPB_  = 4096;                      // LDS capacity per bucket (mean 2176)

// workspace layout (bytes)
constexpr size_t OFF_H1  = 0;                                    // [N][128] bf16
constexpr size_t OFF_Y1  = OFF_H1  + (size_t)N_ * 128 * 2;       // [N][128] f32
constexpr size_t OFF_H2  = OFF_Y1  + (size_t)N_ * 128 * 4;       // [N][64] bf16
constexpr size_t OFF_AS1 = OFF_H2  + (size_t)N_ * 64 * 2;        // [N][4]
constexpr size_t OFF_AD1 = OFF_AS1 + (size_t)N_ * 4 * 4;         // [N][4]
constexpr size_t OFF_AS2 = OFF_AD1 + (size_t)N_ * 4 * 4;         // [N]
constexpr size_t OFF_AD2 = OFF_AS2 + (size_t)N_ * 4;             // [N]
constexpr size_t OFF_ROW = OFF_AD2 + (size_t)N_ * 4;             // [N+1] int
constexpr size_t OFF_GC  = OFF_ROW + (((size_t)(N_ + 1) * 4 + 15) & ~(size_t)15); // [NB] int
constexpr size_t OFF_GO  = OFF_GC  + (((size_t)NB_ * 4 + 15) & ~(size_t)15);      // [NB+1] int
constexpr size_t OFF_GU  = OFF_GO  + (((size_t)(NB_ + 1) * 4 + 15) & ~(size_t)15);// [NB] int
constexpr size_t OFF_EB1 = OFF_GU  + (((size_t)NB_ * 4 + 15) & ~(size_t)15);      // [EP] u32 (src<<16|dst)
constexpr size_t OFF_EB  = OFF_EB1 + (size_t)EP_ * 4;            // [EP] int (src, dst-sorted)
}

__device__ __forceinline__ float bcast_f(float v, int lane) {
  return __uint_as_float(__builtin_amdgcn_readlane(__float_as_uint(v), lane));
}
__device__ __forceinline__ int bcast_i(int v, int lane) {
  return __builtin_amdgcn_readlane(v, lane);
}
__device__ __forceinline__ unsigned short f2bf(float x) {   // RNE
  unsigned u = __float_as_uint(x);
  return (unsigned short)((u + 0x7FFFu + ((u >> 16) & 1u)) >> 16);
}
__device__ __forceinline__ float bf_lo(unsigned u) { return __uint_as_float(u << 16); }
__device__ __forceinline__ float bf_hi(unsigned u) { return __uint_as_float(u & 0xFFFF0000u); }

// ---------------- GEMM1: h1 = x @ W1 (bf16 out) ; a_s1/a_d1 per head -----
__global__ __launch_bounds__(256, 4) void k_gemm1(const float* __restrict__ x,
    const float* __restrict__ W, const float* __restrict__ av_s,
    const float* __restrict__ av_d, unsigned short* __restrict__ hbf,
    float* __restrict__ a_s, float* __restrict__ a_d)
{
  __shared__ float xs[16 * 128];
  const int t = threadIdx.x;
  const int rbase = blockIdx.x * 16;
  {
    const float4* xg = (const float4*)(x + (size_t)rbase * 128);
    float4* s4 = (float4*)xs;
    s4[t] = xg[t];
    s4[t + 256] = xg[t + 256];
  }
  __syncthreads();
  const int c = t & 127;
  const int rr = t >> 7;   // 0..1
  float acc[8] = {0, 0, 0, 0, 0, 0, 0, 0};
#pragma unroll 1
  for (int k0 = 0; k0 < 128; k0 += 8) {
    float w[8];
#pragma unroll
    for (int u = 0; u < 8; ++u) w[u] = W[(k0 + u) * 128 + c];
#pragma unroll
    for (int j = 0; j < 8; ++j) {
      const int r = rr + 2 * j;
      const float4 xa = *(const float4*)&xs[r * 128 + k0];
      const float4 xb = *(const float4*)&xs[r * 128 + k0 + 4];
      acc[j] = fmaf(xa.x, w[0], acc[j]);
      acc[j] = fmaf(xa.y, w[1], acc[j]);
      acc[j] = fmaf(xa.z, w[2], acc[j]);
      acc[j] = fmaf(xa.w, w[3], acc[j]);
      acc[j] = fmaf(xb.x, w[4], acc[j]);
      acc[j] = fmaf(xb.y, w[5], acc[j]);
      acc[j] = fmaf(xb.z, w[6], acc[j]);
      acc[j] = fmaf(xb.w, w[7], acc[j]);
    }
  }
  const float asc = av_s[c];
  const float adc = av_d[c];
#pragma unroll
  for (int j = 0; j < 8; ++j) {
    const int rg = rbase + rr + 2 * j;
    hbf[(size_t)rg * 128 + c] = f2bf(acc[j]);
    float ps = acc[j] * asc;
    float pd = acc[j] * adc;
#pragma unroll
    for (int m = 16; m >= 1; m >>= 1) {
      ps += __shfl_xor(ps, m);
      pd += __shfl_xor(pd, m);
    }
    if ((c & 31) == 0) {
      a_s[rg * 4 + (c >> 5)] = ps;
      a_d[rg * 4 + (c >> 5)] = pd;
    }
  }
}

// ---------------- GEMM2: h2 = y1 @ W2 (bf16 out) ; a_s2/a_d2 (1 head) ----
__global__ __launch_bounds__(256, 4) void k_gemm2(const float* __restrict__ y,
    const float* __restrict__ W, const float* __restrict__ av_s,
    const float* __restrict__ av_d, unsigned short* __restrict__ hbf,
    float* __restrict__ a_s, float* __restrict__ a_d)
{
  __shared__ float ys[16 * 128];
  const int t = threadIdx.x;
  const int rbase = blockIdx.x * 16;
  {
    const float4* yg = (const float4*)(y + (size_t)rbase * 128);
    float4* s4 = (float4*)ys;
    s4[t] = yg[t];
    s4[t + 256] = yg[t + 256];
  }
  __syncthreads();
  const int c = t & 63;
  const int rr = t >> 6;   // 0..3
  float acc[4] = {0, 0, 0, 0};
#pragma unroll 1
  for (int k0 = 0; k0 < 128; k0 += 8) {
    float w[8];
#pragma unroll
    for (int u = 0; u < 8; ++u) w[u] = W[(k0 + u) * 64 + c];
#pragma unroll
    for (int j = 0; j < 4; ++j) {
      const int r = rr + 4 * j;
      const float4 ya = *(const float4*)&ys[r * 128 + k0];
      const float4 yb = *(const float4*)&ys[r * 128 + k0 + 4];
      acc[j] = fmaf(ya.x, w[0], acc[j]);
      acc[j] = fmaf(ya.y, w[1], acc[j]);
      acc[j] = fmaf(ya.z, w[2], acc[j]);
      acc[j] = fmaf(ya.w, w[3], acc[j]);
      acc[j] = fmaf(yb.x, w[4], acc[j]);
      acc[j] = fmaf(yb.y, w[5], acc[j]);
      acc[j] = fmaf(yb.z, w[6], acc[j]);
      acc[j] = fmaf(yb.w, w[7], acc[j]);
    }
  }
  const float asc = av_s[c];
  const float adc = av_d[c];
#pragma unroll
  for (int j = 0; j < 4; ++j) {
    const int rg = rbase + rr + 4 * j;
    hbf[(size_t)rg * 64 + c] = f2bf(acc[j]);
    float ps = acc[j] * asc;
    float pd = acc[j] * adc;
#pragma unroll
    for (int m = 32; m >= 1; m >>= 1) {
      ps += __shfl_xor(ps, m);
      pd += __shfl_xor(pd, m);
    }
    if (c == 0) { a_s[rg] = ps; a_d[rg] = pd; }
  }
}

// ---------------- CSR build: two-level counting sort ----------------
// Coarse histogram over 391 buckets (dst>>7), per-block LDS first.
__global__ __launch_bounds__(256) void k_hist(const int* __restrict__ ei,
                                              int* __restrict__ gcount)
{
  __shared__ int nh[NB_];
  const int t = threadIdx.x;
  for (int j = t; j < NB_; j += 256) nh[j] = 0;
  __syncthreads();
  const int beg = blockIdx.x * CHUNK_;
  const int end = min(beg + CHUNK_, EP_);
  for (int i = beg + t; i < end; i += 256) {
    const int d = (i < E_) ? ei[E_ + i] : (i - E_);
    atomicAdd(&nh[d >> 7], 1);
  }
  __syncthreads();
  for (int j = t; j < NB_; j += 256)
    if (nh[j]) atomicAdd(&gcount[j], nh[j]);
}

// Exclusive scan of 391 bucket counts; init cursors.
__global__ __launch_bounds__(512) void k_scan(const int* __restrict__ gcount,
    int* __restrict__ goff, int* __restrict__ gcursor)
{
  __shared__ int sd[512];
  const int t = threadIdx.x;
  const int v = (t < NB_) ? gcount[t] : 0;
  sd[t] = v;
  __syncthreads();
  for (int off = 1; off < 512; off <<= 1) {
    const int add = (t >= off) ? sd[t - off] : 0;
    __syncthreads();
    sd[t] += add;
    __syncthreads();
  }
  if (t < NB_) { goff[t] = sd[t] - v; gcursor[t] = sd[t] - v; }
  if (t == 0) goff[NB_] = EP_;
}

// Scatter edges into coarse buckets; per-(block,bucket) writes are
// contiguous runs (~21 entries) -> ~10x less write amplification than
// per-edge random scatter.
__global__ __launch_bounds__(256) void k_scatter(const int* __restrict__ ei,
    int* __restrict__ gcursor, unsigned* __restrict__ eb1)
{
  __shared__ int nh[NB_];
  __shared__ int gb[NB_];
  const int t = threadIdx.x;
  for (int j = t; j < NB_; j += 256) nh[j] = 0;
  __syncthreads();
  const int beg = blockIdx.x * CHUNK_;
  const int end = min(beg + CHUNK_, EP_);
  for (int i = beg + t; i < end; i += 256) {
    const int d = (i < E_) ? ei[E_ + i] : (i - E_);
    atomicAdd(&nh[d >> 7], 1);
  }
  __syncthreads();
  for (int j = t; j < NB_; j += 256) {
    const int c = nh[j];
    gb[j] = c ? atomicAdd(&gcursor[j], c) : 0;
    nh[j] = 0;
  }
  __syncthreads();
  for (int i = beg + t; i < end; i += 256) {
    int s, d;
    if (i < E_) { s = ei[i]; d = ei[E_ + i]; } else { s = d = i - E_; }
    const int b = d >> 7;
    const int r = atomicAdd(&nh[b], 1);
    eb1[gb[b] + r] = ((unsigned)s << 16) | (unsigned)d;   // both < 65536
  }
}

// Fine sort within each bucket (128 dsts, ~2176 edges) entirely in LDS;
// writes rowptr + final ebuf with full locality (8.7 KB region per block).
__global__ __launch_bounds__(256) void k_bucket(const unsigned* __restrict__ eb1,
    const int* __restrict__ goff, int* __restrict__ rowptr,
    int* __restrict__ ebuf)
{
  __shared__ int h[128];
  __shared__ int off[129];
  __shared__ unsigned arrv[CAPB_];
  const int b = blockIdx.x;
  const int t = threadIdx.x;
  const int base = goff[b];
  const int cnt  = goff[b + 1] - base;
  if (t < 128) h[t] = 0;
  __syncthreads();
  const bool fits = (cnt <= CAPB_);
  for (int i = t; i < cnt; i += 256) {
    const unsigned v = eb1[base + i];
    if (fits) arrv[i] = v;
    atomicAdd(&h[(int)(v & 0xFFFFu) - (b << 7)], 1);
  }
  __syncthreads();
  if (t < 64) {
    const int a0 = h[2 * t], a1 = h[2 * t + 1];
    int s = a0 + a1;
#pragma unroll
    for (int m = 1; m < 64; m <<= 1) {
      const int u = __shfl_up(s, m);
      if (t >= m) s += u;
    }
    off[2 * t + 1] = s - a1;
    off[2 * t]     = s - a1 - a0;
    if (t == 63) off[128] = s;
  }
  __syncthreads();
  if (t < 128) {
    const int dst = (b << 7) + t;
    if (dst < N_) rowptr[dst] = base + off[t];
  }
  if (b == NB_ - 1 && t == 0) rowptr[N_] = EP_;
  if (t < 128) h[t] = 0;   // reuse as rank counters
  __syncthreads();
  for (int i = t; i < cnt; i += 256) {
    const unsigned v = fits ? arrv[i] : eb1[base + i];
    const int dlow = (int)(v & 0xFFFFu) - (b << 7);
    const int r = atomicAdd(&h[dlow], 1);
    ebuf[base + off[dlow] + r] = (int)(v >> 16);
  }
}

// ---------------- Layer-1 aggregation: 1 wave/dst, bf16 h, 128 ch -------
__global__ __launch_bounds__(256, 8) void k_agg1(const int* __restrict__ rowptr,
    const int* __restrict__ ebuf, const float* __restrict__ a_s,
    const float* __restrict__ a_d, const unsigned short* __restrict__ hbf,
    const float* __restrict__ b1, float* __restrict__ y)
{
  const int w = threadIdx.x >> 6;
  const int l = threadIdx.x & 63;
  const int d = blockIdx.x * 4 + w;
  const int base = rowptr[d];
  const int deg  = rowptr[d + 1] - base;
  const float4 ad = *(const float4*)&a_d[(size_t)d * 4];
  const bool hi = (l >= 32);
  const bool b4 = ((l >> 4) & 1) != 0;
  float acc0 = 0.f, acc1 = 0.f;
  float r0, r1, r2, r3;

  if (deg <= 64) {
    int   sreg = 0;
    float e0 = -1e30f, e1 = -1e30f, e2 = -1e30f, e3 = -1e30f;
    if (l < deg) {
      sreg = ebuf[base + l];
      const float4 as = *(const float4*)&a_s[(size_t)sreg * 4];
      e0 = as.x + ad.x; e0 = e0 > 0.f ? e0 : SLOPE * e0;
      e1 = as.y + ad.y; e1 = e1 > 0.f ? e1 : SLOPE * e1;
      e2 = as.z + ad.z; e2 = e2 > 0.f ? e2 : SLOPE * e2;
      e3 = as.w + ad.w; e3 = e3 > 0.f ? e3 : SLOPE * e3;
    }
    float mx0 = e0, mx1 = e1, mx2 = e2, mx3 = e3;
#pragma unroll
    for (int m = 32; m >= 1; m >>= 1) {
      mx0 = fmaxf(mx0, __shfl_xor(mx0, m));
      mx1 = fmaxf(mx1, __shfl_xor(mx1, m));
      mx2 = fmaxf(mx2, __shfl_xor(mx2, m));
      mx3 = fmaxf(mx3, __shfl_xor(mx3, m));
    }
    const float p0 = (l < deg) ? __expf(e0 - mx0) : 0.f;
    const float p1 = (l < deg) ? __expf(e1 - mx1) : 0.f;
    const float p2 = (l < deg) ? __expf(e2 - mx2) : 0.f;
    const float p3 = (l < deg) ? __expf(e3 - mx3) : 0.f;
    float sm0 = p0, sm1 = p1, sm2 = p2, sm3 = p3;
#pragma unroll
    for (int m = 32; m >= 1; m >>= 1) {
      sm0 += __shfl_xor(sm0, m);
      sm1 += __shfl_xor(sm1, m);
      sm2 += __shfl_xor(sm2, m);
      sm3 += __shfl_xor(sm3, m);
    }
    r0 = 1.f / (sm0 + 1e-16f);
    r1 = 1.f / (sm1 + 1e-16f);
    r2 = 1.f / (sm2 + 1e-16f);
    r3 = 1.f / (sm3 + 1e-16f);
    int i = 0;
    for (; i + 4 <= deg; i += 4) {
#pragma unroll
      for (int u = 0; u < 4; ++u) {
        const int   s  = bcast_i(sreg, i + u);
        const float q0 = bcast_f(p0, i + u);
        const float q1 = bcast_f(p1, i + u);
        const float q2 = bcast_f(p2, i + u);
        const float q3 = bcast_f(p3, i + u);
        const float pa = hi ? (b4 ? q3 : q2) : (b4 ? q1 : q0);
        const unsigned uu = ((const unsigned*)(hbf + (size_t)s * 128))[l];
        acc0 = fmaf(pa, bf_lo(uu), acc0);
        acc1 = fmaf(pa, bf_hi(uu), acc1);
      }
    }
    for (; i < deg; ++i) {
      const int   s  = bcast_i(sreg, i);
      const float q0 = bcast_f(p0, i);
      const float q1 = bcast_f(p1, i);
      const float q2 = bcast_f(p2, i);
      const float q3 = bcast_f(p3, i);
      const float pa = hi ? (b4 ? q3 : q2) : (b4 ? q1 : q0);
      const unsigned uu = ((const unsigned*)(hbf + (size_t)s * 128))[l];
      acc0 = fmaf(pa, bf_lo(uu), acc0);
      acc1 = fmaf(pa, bf_hi(uu), acc1);
    }
  } else {
    // ---- any-deg fallback (never taken for this graph, kept for safety) --
    float mx0 = -1e30f, mx1 = -1e30f, mx2 = -1e30f, mx3 = -1e30f;
    for (int i = l; i < deg; i += 64) {
      const int s = ebuf[base + i];
      const float4 as = *(const float4*)&a_s[(size_t)s * 4];
      float e0 = as.x + ad.x; e0 = e0 > 0.f ? e0 : SLOPE * e0;
      float e1 = as.y + ad.y; e1 = e1 > 0.f ? e1 : SLOPE * e1;
      float e2 = as.z + ad.z; e2 = e2 > 0.f ? e2 : SLOPE * e2;
      float e3 = as.w + ad.w; e3 = e3 > 0.f ? e3 : SLOPE * e3;
      mx0 = fmaxf(mx0, e0); mx1 = fmaxf(mx1, e1);
      mx2 = fmaxf(mx2, e2); mx3 = fmaxf(mx3, e3);
    }
#pragma unroll
    for (int m = 32; m >= 1; m >>= 1) {
      mx0 = fmaxf(mx0, __shfl_xor(mx0, m));
      mx1 = fmaxf(mx1, __shfl_xor(mx1, m));
      mx2 = fmaxf(mx2, __shfl_xor(mx2, m));
      mx3 = fmaxf(mx3, __shfl_xor(mx3, m));
    }
    float sm0 = 0.f, sm1 = 0.f, sm2 = 0.f, sm3 = 0.f;
    for (int i = l; i < deg; i += 64) {
      const int s = ebuf[base + i];
      const float4 as = *(const float4*)&a_s[(size_t)s * 4];
      float e0 = as.x + ad.x; e0 = e0 > 0.f ? e0 : SLOPE * e0;
      float e1 = as.y + ad.y; e1 = e1 > 0.f ? e1 : SLOPE * e1;
      float e2 = as.z + ad.z; e2 = e2 > 0.f ? e2 : SLOPE * e2;
      float e3 = as.w + ad.w; e3 = e3 > 0.f ? e3 : SLOPE * e3;
      sm0 += __expf(e0 - mx0); sm1 += __expf(e1 - mx1);
      sm2 += __expf(e2 - mx2); sm3 += __expf(e3 - mx3);
    }
#pragma unroll
    for (int m = 32; m >= 1; m >>= 1) {
      sm0 += __shfl_xor(sm0, m);
      sm1 += __shfl_xor(sm1, m);
      sm2 += __shfl_xor(sm2, m);
      sm3 += __shfl_xor(sm3, m);
    }
    r0 = 1.f / (sm0 + 1e-16f);
    r1 = 1.f / (sm1 + 1e-16f);
    r2 = 1.f / (sm2 + 1e-16f);
    r3 = 1.f / (sm3 + 1e-16f);
    const float mxs = hi ? (b4 ? mx3 : mx2) : (b4 ? mx1 : mx0);
    for (int i = 0; i < deg; ++i) {
      const int s = ebuf[base + i];
      const float4 as = *(const float4*)&a_s[(size_t)s * 4];
      float e0 = as.x + ad.x; e0 = e0 > 0.f ? e0 : SLOPE * e0;
      float e1 = as.y + ad.y; e1 = e1 > 0.f ? e1 : SLOPE * e1;
      float e2 = as.z + ad.z; e2 = e2 > 0.f ? e2 : SLOPE * e2;
      float e3 = as.w + ad.w; e3 = e3 > 0.f ? e3 : SLOPE * e3;
      const float es = hi ? (b4 ? e3 : e2) : (b4 ? e1 : e0);
      const float pa = __expf(es - mxs);
      const unsigned uu = ((const unsigned*)(hbf + (size_t)s * 128))[l];
      acc0 = fmaf(pa, bf_lo(uu), acc0);
      acc1 = fmaf(pa, bf_hi(uu), acc1);
    }
  }
  const float rsel = hi ? (b4 ? r3 : r2) : (b4 ? r1 : r0);
  const int c0 = 2 * l;
  const float2 bb = *(const float2*)&b1[c0];
  float o0 = acc0 * rsel + bb.x;
  float o1 = acc1 * rsel + bb.y;
  o0 = o0 > 0.f ? o0 : expm1f(o0);
  o1 = o1 > 0.f ? o1 : expm1f(o1);
  *(float2*)&y[(size_t)d * 128 + c0] = make_float2(o0, o1);
}

// ---------------- Layer-2 aggregation: 1 wave/dst, bf16 h, 64 ch --------
__global__ __launch_bounds__(256, 8) void k_agg2(const int* __restrict__ rowptr,
    const int* __restrict__ ebuf, const float* __restrict__ a_s,
    const float* __restrict__ a_d, const unsigned short* __restrict__ hbf,
    const float* __restrict__ b2, float* __restrict__ out)
{
  const int w = threadIdx.x >> 6;
  const int l = threadIdx.x & 63;
  const int lh = l & 31;
  const bool hi = (l >= 32);
  const int d = blockIdx.x * 4 + w;
  const int base = rowptr[d];
  const int deg  = rowptr[d + 1] - base;
  const float ad = a_d[d];
  float acc0 = 0.f, acc1 = 0.f;
  float rv;

  if (deg <= 64) {
    int   sreg = 0;
    float e = -1e30f;
    if (l < deg) {
      sreg = ebuf[base + l];
      e = a_s[sreg] + ad; e = e > 0.f ? e : SLOPE * e;
    }
    float mx = e;
#pragma unroll
    for (int m = 32; m >= 1; m >>= 1) mx = fmaxf(mx, __shfl_xor(mx, m));
    const float p = (l < deg) ? __expf(e - mx) : 0.f;
    float sm = p;
#pragma unroll
    for (int m = 32; m >= 1; m >>= 1) sm += __shfl_xor(sm, m);
    rv = 1.f / (sm + 1e-16f);
    int i = 0;
    for (; i + 4 <= deg; i += 4) {
#pragma unroll
      for (int u = 0; u < 4; u += 2) {
        const int   sA = bcast_i(sreg, i + u);
        const int   sB = bcast_i(sreg, i + u + 1);
        const float pA = bcast_f(p, i + u);
        const float pB = bcast_f(p, i + u + 1);
        const int   s  = hi ? sB : sA;
        const float pp = hi ? pB : pA;
        const unsigned uu = ((const unsigned*)(hbf + (size_t)s * 64))[lh];
        acc0 = fmaf(pp, bf_lo(uu), acc0);
        acc1 = fmaf(pp, bf_hi(uu), acc1);
      }
    }
    for (; i < deg; ++i) {
      const int   s  = bcast_i(sreg, i);
      const float pp = hi ? 0.f : bcast_f(p, i);
      const unsigned uu = ((const unsigned*)(hbf + (size_t)s * 64))[lh];
      acc0 = fmaf(pp, bf_lo(uu), acc0);
      acc1 = fmaf(pp, bf_hi(uu), acc1);
    }
  } else {
    float mx = -1e30f;
    for (int i = l; i < deg; i += 64) {
      const int s = ebuf[base + i];
      float e = a_s[s] + ad; e = e > 0.f ? e : SLOPE * e;
      mx = fmaxf(mx, e);
    }
#pragma unroll
    for (int m = 32; m >= 1; m >>= 1) mx = fmaxf(mx, __shfl_xor(mx, m));
    float sm = 0.f;
    for (int i = l; i < deg; i += 64) {
      const int s = ebuf[base + i];
      float e = a_s[s] + ad; e = e > 0.f ? e : SLOPE * e;
      sm += __expf(e - mx);
    }
#pragma unroll
    for (int m = 32; m >= 1; m >>= 1) sm += __shfl_xor(sm, m);
    rv = 1.f / (sm + 1e-16f);
    for (int i = 0; i < deg; ++i) {
      const int s = ebuf[base + i];
      float e = a_s[s] + ad; e = e > 0.f ? e : SLOPE * e;
      const float pp = hi ? 0.f : __expf(e - mx);
      const unsigned uu = ((const unsigned*)(hbf + (size_t)s * 64))[lh];
      acc0 = fmaf(pp, bf_lo(uu), acc0);
      acc1 = fmaf(pp, bf_hi(uu), acc1);
    }
  }
  acc0 += __shfl_xor(acc0, 32);
  acc1 += __shfl_xor(acc1, 32);
  if (!hi) {
    const int c0 = 2 * lh;
    const float2 bb = *(const float2*)&b2[c0];
    *(float2*)&out[(size_t)d * 64 + c0] =
        make_float2(acc0 * rv + bb.x, acc1 * rv + bb.y);
  }
}

extern "C" void kernel_launch(void* const* d_in, const int* in_sizes, int n_in,
                              void* d_out, int out_size, void* d_ws, size_t ws_size,
                              hipStream_t stream) {
  const float* x     = (const float*)d_in[0];
  const int*   ei    = (const int*)d_in[1];
  const float* W1    = (const float*)d_in[2];
  const float* as1v  = (const float*)d_in[3];
  const float* ad1v  = (const float*)d_in[4];
  const float* b1    = (const float*)d_in[5];
  const float* W2    = (const float*)d_in[6];
  const float* as2v  = (const float*)d_in[7];
  const float* ad2v  = (const float*)d_in[8];
  const float* b2    = (const float*)d_in[9];
  float* out = (float*)d_out;

  char* ws = (char*)d_ws;
  unsigned short* h1 = (unsigned short*)(ws + OFF_H1);
  float* y1   = (float*)(ws + OFF_Y1);
  unsigned short* h2 = (unsigned short*)(ws + OFF_H2);
  float* a_s1 = (float*)(ws + OFF_AS1);
  float* a_d1 = (float*)(ws + OFF_AD1);
  float* a_s2 = (float*)(ws + OFF_AS2);
  float* a_d2 = (float*)(ws + OFF_AD2);
  int* rowptr = (int*)(ws + OFF_ROW);
  int* gcount = (int*)(ws + OFF_GC);
  int* goff   = (int*)(ws + OFF_GO);
  int* gcur   = (int*)(ws + OFF_GU);
  unsigned* eb1 = (unsigned*)(ws + OFF_EB1);
  int* ebuf   = (int*)(ws + OFF_EB);

  hipMemsetAsync(gcount, 0, (size_t)NB_ * 4, stream);

  k_gemm1<<<N_ / 16, 256, 0, stream>>>(x, W1, as1v, ad1v, h1, a_s1, a_d1);
  k_hist<<<NBLKA_, 256, 0, stream>>>(ei, gcount);
  k_scan<<<1, 512, 0, stream>>>(gcount, goff, gcur);
  k_scatter<<<NBLKA_, 256, 0, stream>>>(ei, gcur, eb1);
  k_bucket<<<NB_, 256, 0, stream>>>(eb1, goff, rowptr, ebuf);
  k_agg1<<<N_ / 4, 256, 0, stream>>>(rowptr, ebuf, a_s1, a_d1, h1, b1, y1);
  k_gemm2<<<N_ / 16, 256, 0, stream>>>(y1, W2, as2v, ad2v, h2, a_s2, a_d2);
  k_agg2<<<N_ / 4, 256, 0, stream>>>(rowptr, ebuf, a_s2, a_d2, h2, b2, out);
}

// Round 6
// 196.579 us; speedup vs baseline: 1.6983x; 1.0598x over previous
//
#include <hip/hip_runtime.h>
#include <math.h>

namespace {
constexpr int N_   = 50000;
constexpr int E_   = 800000;
constexpr int EP_  = E_ + N_;   // edges + self loops = 850000
constexpr float SLOPE = 0.2f;

constexpr int NB_    = (N_ + 127) / 128;          // 391 coarse buckets (dst>>7)
constexpr int CHUNK_ = 8192;                      // edges per scatter block
constexpr int NBLKA_ = (EP_ + CHUNK_ - 1) / CHUNK_; // 104
constexpr int CAPB_  = 4096;                      // LDS capacity per bucket (mean 2176)

// workspace layout (bytes)
constexpr size_t OFF_H1  = 0;                                    // [N][128] bf16
constexpr size_t OFF_Y1  = OFF_H1  + (size_t)N_ * 128 * 2;       // [N][128] f32
constexpr size_t OFF_H2  = OFF_Y1  + (size_t)N_ * 128 * 4;       // [N][64] bf16
constexpr size_t OFF_AS1 = OFF_H2  + (size_t)N_ * 64 * 2;        // [N][4]
constexpr size_t OFF_AD1 = OFF_AS1 + (size_t)N_ * 4 * 4;         // [N][4]
constexpr size_t OFF_AS2 = OFF_AD1 + (size_t)N_ * 4 * 4;         // [N]
constexpr size_t OFF_AD2 = OFF_AS2 + (size_t)N_ * 4;             // [N]
constexpr size_t OFF_ROW = OFF_AD2 + (size_t)N_ * 4;             // [N+1] int
constexpr size_t OFF_GC  = OFF_ROW + (((size_t)(N_ + 1) * 4 + 15) & ~(size_t)15); // [NB] int
constexpr size_t OFF_GO  = OFF_GC  + (((size_t)NB_ * 4 + 15) & ~(size_t)15);      // [NB+1] int
constexpr size_t OFF_GU  = OFF_GO  + (((size_t)(NB_ + 1) * 4 + 15) & ~(size_t)15);// [NB] int
constexpr size_t OFF_EB1 = OFF_GU  + (((size_t)NB_ * 4 + 15) & ~(size_t)15);      // [EP] u32 (src<<16|dst)
constexpr size_t OFF_EB  = OFF_EB1 + (size_t)EP_ * 4;            // [EP] int (src, dst-sorted)
}

__device__ __forceinline__ unsigned short f2bf(float x) {   // RNE
  unsigned u = __float_as_uint(x);
  return (unsigned short)((u + 0x7FFFu + ((u >> 16) & 1u)) >> 16);
}
__device__ __forceinline__ float bf_lo(unsigned u) { return __uint_as_float(u << 16); }
__device__ __forceinline__ float bf_hi(unsigned u) { return __uint_as_float(u & 0xFFFF0000u); }

// ---------------- GEMM1: h1 = x @ W1 (bf16 out) ; a_s1/a_d1 per head -----
__global__ __launch_bounds__(256, 4) void k_gemm1(const float* __restrict__ x,
    const float* __restrict__ W, const float* __restrict__ av_s,
    const float* __restrict__ av_d, unsigned short* __restrict__ hbf,
    float* __restrict__ a_s, float* __restrict__ a_d)
{
  __shared__ float xs[16 * 128];
  const int t = threadIdx.x;
  const int rbase = blockIdx.x * 16;
  {
    const float4* xg = (const float4*)(x + (size_t)rbase * 128);
    float4* s4 = (float4*)xs;
    s4[t] = xg[t];
    s4[t + 256] = xg[t + 256];
  }
  __syncthreads();
  const int c = t & 127;
  const int rr = t >> 7;   // 0..1
  float acc[8] = {0, 0, 0, 0, 0, 0, 0, 0};
#pragma unroll 1
  for (int k0 = 0; k0 < 128; k0 += 8) {
    float w[8];
#pragma unroll
    for (int u = 0; u < 8; ++u) w[u] = W[(k0 + u) * 128 + c];
#pragma unroll
    for (int j = 0; j < 8; ++j) {
      const int r = rr + 2 * j;
      const float4 xa = *(const float4*)&xs[r * 128 + k0];
      const float4 xb = *(const float4*)&xs[r * 128 + k0 + 4];
      acc[j] = fmaf(xa.x, w[0], acc[j]);
      acc[j] = fmaf(xa.y, w[1], acc[j]);
      acc[j] = fmaf(xa.z, w[2], acc[j]);
      acc[j] = fmaf(xa.w, w[3], acc[j]);
      acc[j] = fmaf(xb.x, w[4], acc[j]);
      acc[j] = fmaf(xb.y, w[5], acc[j]);
      acc[j] = fmaf(xb.z, w[6], acc[j]);
      acc[j] = fmaf(xb.w, w[7], acc[j]);
    }
  }
  const float asc = av_s[c];
  const float adc = av_d[c];
#pragma unroll
  for (int j = 0; j < 8; ++j) {
    const int rg = rbase + rr + 2 * j;
    hbf[(size_t)rg * 128 + c] = f2bf(acc[j]);
    float ps = acc[j] * asc;
    float pd = acc[j] * adc;
#pragma unroll
    for (int m = 16; m >= 1; m >>= 1) {
      ps += __shfl_xor(ps, m);
      pd += __shfl_xor(pd, m);
    }
    if ((c & 31) == 0) {
      a_s[rg * 4 + (c >> 5)] = ps;
      a_d[rg * 4 + (c >> 5)] = pd;
    }
  }
}

// ---------------- GEMM2: h2 = y1 @ W2 (bf16 out) ; a_s2/a_d2 (1 head) ----
__global__ __launch_bounds__(256, 4) void k_gemm2(const float* __restrict__ y,
    const float* __restrict__ W, const float* __restrict__ av_s,
    const float* __restrict__ av_d, unsigned short* __restrict__ hbf,
    float* __restrict__ a_s, float* __restrict__ a_d)
{
  __shared__ float ys[16 * 128];
  const int t = threadIdx.x;
  const int rbase = blockIdx.x * 16;
  {
    const float4* yg = (const float4*)(y + (size_t)rbase * 128);
    float4* s4 = (float4*)ys;
    s4[t] = yg[t];
    s4[t + 256] = yg[t + 256];
  }
  __syncthreads();
  const int c = t & 63;
  const int rr = t >> 6;   // 0..3
  float acc[4] = {0, 0, 0, 0};
#pragma unroll 1
  for (int k0 = 0; k0 < 128; k0 += 8) {
    float w[8];
#pragma unroll
    for (int u = 0; u < 8; ++u) w[u] = W[(k0 + u) * 64 + c];
#pragma unroll
    for (int j = 0; j < 4; ++j) {
      const int r = rr + 4 * j;
      const float4 ya = *(const float4*)&ys[r * 128 + k0];
      const float4 yb = *(const float4*)&ys[r * 128 + k0 + 4];
      acc[j] = fmaf(ya.x, w[0], acc[j]);
      acc[j] = fmaf(ya.y, w[1], acc[j]);
      acc[j] = fmaf(ya.z, w[2], acc[j]);
      acc[j] = fmaf(ya.w, w[3], acc[j]);
      acc[j] = fmaf(yb.x, w[4], acc[j]);
      acc[j] = fmaf(yb.y, w[5], acc[j]);
      acc[j] = fmaf(yb.z, w[6], acc[j]);
      acc[j] = fmaf(yb.w, w[7], acc[j]);
    }
  }
  const float asc = av_s[c];
  const float adc = av_d[c];
#pragma unroll
  for (int j = 0; j < 4; ++j) {
    const int rg = rbase + rr + 4 * j;
    hbf[(size_t)rg * 64 + c] = f2bf(acc[j]);
    float ps = acc[j] * asc;
    float pd = acc[j] * adc;
#pragma unroll
    for (int m = 32; m >= 1; m >>= 1) {
      ps += __shfl_xor(ps, m);
      pd += __shfl_xor(pd, m);
    }
    if (c == 0) { a_s[rg] = ps; a_d[rg] = pd; }
  }
}

// ---------------- CSR build: two-level counting sort ----------------
__global__ __launch_bounds__(256) void k_hist(const int* __restrict__ ei,
                                              int* __restrict__ gcount)
{
  __shared__ int nh[NB_];
  const int t = threadIdx.x;
  for (int j = t; j < NB_; j += 256) nh[j] = 0;
  __syncthreads();
  const int beg = blockIdx.x * CHUNK_;
  const int end = min(beg + CHUNK_, EP_);
  for (int i = beg + t; i < end; i += 256) {
    const int d = (i < E_) ? ei[E_ + i] : (i - E_);
    atomicAdd(&nh[d >> 7], 1);
  }
  __syncthreads();
  for (int j = t; j < NB_; j += 256)
    if (nh[j]) atomicAdd(&gcount[j], nh[j]);
}

__global__ __launch_bounds__(512) void k_scan(const int* __restrict__ gcount,
    int* __restrict__ goff, int* __restrict__ gcursor)
{
  __shared__ int sd[512];
  const int t = threadIdx.x;
  const int v = (t < NB_) ? gcount[t] : 0;
  sd[t] = v;
  __syncthreads();
  for (int off = 1; off < 512; off <<= 1) {
    const int add = (t >= off) ? sd[t - off] : 0;
    __syncthreads();
    sd[t] += add;
    __syncthreads();
  }
  if (t < NB_) { goff[t] = sd[t] - v; gcursor[t] = sd[t] - v; }
  if (t == 0) goff[NB_] = EP_;
}

__global__ __launch_bounds__(256) void k_scatter(const int* __restrict__ ei,
    int* __restrict__ gcursor, unsigned* __restrict__ eb1)
{
  __shared__ int nh[NB_];
  __shared__ int gb[NB_];
  const int t = threadIdx.x;
  for (int j = t; j < NB_; j += 256) nh[j] = 0;
  __syncthreads();
  const int beg = blockIdx.x * CHUNK_;
  const int end = min(beg + CHUNK_, EP_);
  for (int i = beg + t; i < end; i += 256) {
    const int d = (i < E_) ? ei[E_ + i] : (i - E_);
    atomicAdd(&nh[d >> 7], 1);
  }
  __syncthreads();
  for (int j = t; j < NB_; j += 256) {
    const int c = nh[j];
    gb[j] = c ? atomicAdd(&gcursor[j], c) : 0;
    nh[j] = 0;
  }
  __syncthreads();
  for (int i = beg + t; i < end; i += 256) {
    int s, d;
    if (i < E_) { s = ei[i]; d = ei[E_ + i]; } else { s = d = i - E_; }
    const int b = d >> 7;
    const int r = atomicAdd(&nh[b], 1);
    eb1[gb[b] + r] = ((unsigned)s << 16) | (unsigned)d;   // both < 65536
  }
}

__global__ __launch_bounds__(256) void k_bucket(const unsigned* __restrict__ eb1,
    const int* __restrict__ goff, int* __restrict__ rowptr,
    int* __restrict__ ebuf)
{
  __shared__ int h[128];
  __shared__ int off[129];
  __shared__ unsigned arrv[CAPB_];
  const int b = blockIdx.x;
  const int t = threadIdx.x;
  const int base = goff[b];
  const int cnt  = goff[b + 1] - base;
  if (t < 128) h[t] = 0;
  __syncthreads();
  const bool fits = (cnt <= CAPB_);
  for (int i = t; i < cnt; i += 256) {
    const unsigned v = eb1[base + i];
    if (fits) arrv[i] = v;
    atomicAdd(&h[(int)(v & 0xFFFFu) - (b << 7)], 1);
  }
  __syncthreads();
  if (t < 64) {
    const int a0 = h[2 * t], a1 = h[2 * t + 1];
    int s = a0 + a1;
#pragma unroll
    for (int m = 1; m < 64; m <<= 1) {
      const int u = __shfl_up(s, m);
      if (t >= m) s += u;
    }
    off[2 * t + 1] = s - a1;
    off[2 * t]     = s - a1 - a0;
    if (t == 63) off[128] = s;
  }
  __syncthreads();
  if (t < 128) {
    const int dst = (b << 7) + t;
    if (dst < N_) rowptr[dst] = base + off[t];
  }
  if (b == NB_ - 1 && t == 0) rowptr[N_] = EP_;
  if (t < 128) h[t] = 0;   // reuse as rank counters
  __syncthreads();
  for (int i = t; i < cnt; i += 256) {
    const unsigned v = fits ? arrv[i] : eb1[base + i];
    const int dlow = (int)(v & 0xFFFFu) - (b << 7);
    const int r = atomicAdd(&h[dlow], 1);
    ebuf[base + off[dlow] + r] = (int)(v >> 16);
  }
}

// ---------------- Layer-1 aggregation: 1 wave/dst, bf16 h, 128 ch -------
// Softmax in registers (lane i <-> edge i, deg<=64), then (src_off, p_head)
// pairs staged in per-wave LDS; gather loop = 1 ds_read_b64 (uniform addr,
// broadcast) + 1 global load + 2 FMA per edge. No per-edge readlanes.
__global__ __launch_bounds__(256, 8) void k_agg1(const int* __restrict__ rowptr,
    const int* __restrict__ ebuf, const float* __restrict__ a_s,
    const float* __restrict__ a_d, const unsigned short* __restrict__ hbf,
    const float* __restrict__ b1, float* __restrict__ y)
{
  // per-wave table: [head][65] pairs; head stride 65*8B -> banks 0/2/4/6
  __shared__ uint2 pl[4][4 * 65];
  const int w = threadIdx.x >> 6;
  const int l = threadIdx.x & 63;
  const int d = blockIdx.x * 4 + w;
  const int base = rowptr[d];
  const int deg  = rowptr[d + 1] - base;
  const float4 ad = *(const float4*)&a_d[(size_t)d * 4];
  const int hsel = l >> 4;             // head owning channels (2l, 2l+1)
  const unsigned l4 = (unsigned)l * 4u;
  float acc0 = 0.f, acc1 = 0.f;
  float r0, r1, r2, r3;

  if (deg <= 64) {
    int   sreg = 0;
    float e0 = -1e30f, e1 = -1e30f, e2 = -1e30f, e3 = -1e30f;
    if (l < deg) {
      sreg = ebuf[base + l];
      const float4 as = *(const float4*)&a_s[(size_t)sreg * 4];
      e0 = as.x + ad.x; e0 = e0 > 0.f ? e0 : SLOPE * e0;
      e1 = as.y + ad.y; e1 = e1 > 0.f ? e1 : SLOPE * e1;
      e2 = as.z + ad.z; e2 = e2 > 0.f ? e2 : SLOPE * e2;
      e3 = as.w + ad.w; e3 = e3 > 0.f ? e3 : SLOPE * e3;
    }
    float mx0 = e0, mx1 = e1, mx2 = e2, mx3 = e3;
#pragma unroll
    for (int m = 32; m >= 1; m >>= 1) {
      mx0 = fmaxf(mx0, __shfl_xor(mx0, m));
      mx1 = fmaxf(mx1, __shfl_xor(mx1, m));
      mx2 = fmaxf(mx2, __shfl_xor(mx2, m));
      mx3 = fmaxf(mx3, __shfl_xor(mx3, m));
    }
    const float p0 = (l < deg) ? __expf(e0 - mx0) : 0.f;
    const float p1 = (l < deg) ? __expf(e1 - mx1) : 0.f;
    const float p2 = (l < deg) ? __expf(e2 - mx2) : 0.f;
    const float p3 = (l < deg) ? __expf(e3 - mx3) : 0.f;
    float sm0 = p0, sm1 = p1, sm2 = p2, sm3 = p3;
#pragma unroll
    for (int m = 32; m >= 1; m >>= 1) {
      sm0 += __shfl_xor(sm0, m);
      sm1 += __shfl_xor(sm1, m);
      sm2 += __shfl_xor(sm2, m);
      sm3 += __shfl_xor(sm3, m);
    }
    r0 = 1.f / (sm0 + 1e-16f);
    r1 = 1.f / (sm1 + 1e-16f);
    r2 = 1.f / (sm2 + 1e-16f);
    r3 = 1.f / (sm3 + 1e-16f);
    // stage (src byte offset, p_head) pairs — same-wave, no barrier needed
    if (l < deg) {
      const unsigned soff = (unsigned)sreg << 8;   // 128 bf16 = 256 B rows
      pl[w][0 * 65 + l] = make_uint2(soff, __float_as_uint(p0));
      pl[w][1 * 65 + l] = make_uint2(soff, __float_as_uint(p1));
      pl[w][2 * 65 + l] = make_uint2(soff, __float_as_uint(p2));
      pl[w][3 * 65 + l] = make_uint2(soff, __float_as_uint(p3));
    }
    const uint2* __restrict__ rp = &pl[w][hsel * 65];
    int i = 0;
    for (; i + 8 <= deg; i += 8) {
#pragma unroll
      for (int u = 0; u < 8; ++u) {
        const uint2 sp = rp[i + u];
        const unsigned uu =
            *(const unsigned*)((const char*)hbf + (sp.x + l4));
        const float pa = __uint_as_float(sp.y);
        acc0 = fmaf(pa, bf_lo(uu), acc0);
        acc1 = fmaf(pa, bf_hi(uu), acc1);
      }
    }
    for (; i < deg; ++i) {
      const uint2 sp = rp[i];
      const unsigned uu =
          *(const unsigned*)((const char*)hbf + (sp.x + l4));
      const float pa = __uint_as_float(sp.y);
      acc0 = fmaf(pa, bf_lo(uu), acc0);
      acc1 = fmaf(pa, bf_hi(uu), acc1);
    }
  } else {
    // ---- any-deg fallback (never taken for this graph, kept for safety) --
    float mx0 = -1e30f, mx1 = -1e30f, mx2 = -1e30f, mx3 = -1e30f;
    for (int i = l; i < deg; i += 64) {
      const int s = ebuf[base + i];
      const float4 as = *(const float4*)&a_s[(size_t)s * 4];
      float e0 = as.x + ad.x; e0 = e0 > 0.f ? e0 : SLOPE * e0;
      float e1 = as.y + ad.y; e1 = e1 > 0.f ? e1 : SLOPE * e1;
      float e2 = as.z + ad.z; e2 = e2 > 0.f ? e2 : SLOPE * e2;
      float e3 = as.w + ad.w; e3 = e3 > 0.f ? e3 : SLOPE * e3;
      mx0 = fmaxf(mx0, e0); mx1 = fmaxf(mx1, e1);
      mx2 = fmaxf(mx2, e2); mx3 = fmaxf(mx3, e3);
    }
#pragma unroll
    for (int m = 32; m >= 1; m >>= 1) {
      mx0 = fmaxf(mx0, __shfl_xor(mx0, m));
      mx1 = fmaxf(mx1, __shfl_xor(mx1, m));
      mx2 = fmaxf(mx2, __shfl_xor(mx2, m));
      mx3 = fmaxf(mx3, __shfl_xor(mx3, m));
    }
    float sm0 = 0.f, sm1 = 0.f, sm2 = 0.f, sm3 = 0.f;
    for (int i = l; i < deg; i += 64) {
      const int s = ebuf[base + i];
      const float4 as = *(const float4*)&a_s[(size_t)s * 4];
      float e0 = as.x + ad.x; e0 = e0 > 0.f ? e0 : SLOPE * e0;
      float e1 = as.y + ad.y; e1 = e1 > 0.f ? e1 : SLOPE * e1;
      float e2 = as.z + ad.z; e2 = e2 > 0.f ? e2 : SLOPE * e2;
      float e3 = as.w + ad.w; e3 = e3 > 0.f ? e3 : SLOPE * e3;
      sm0 += __expf(e0 - mx0); sm1 += __expf(e1 - mx1);
      sm2 += __expf(e2 - mx2); sm3 += __expf(e3 - mx3);
    }
#pragma unroll
    for (int m = 32; m >= 1; m >>= 1) {
      sm0 += __shfl_xor(sm0, m);
      sm1 += __shfl_xor(sm1, m);
      sm2 += __shfl_xor(sm2, m);
      sm3 += __shfl_xor(sm3, m);
    }
    r0 = 1.f / (sm0 + 1e-16f);
    r1 = 1.f / (sm1 + 1e-16f);
    r2 = 1.f / (sm2 + 1e-16f);
    r3 = 1.f / (sm3 + 1e-16f);
    const float mxs = hsel == 3 ? mx3 : hsel == 2 ? mx2 : hsel == 1 ? mx1 : mx0;
    for (int i = 0; i < deg; ++i) {
      const int s = ebuf[base + i];
      const float4 as = *(const float4*)&a_s[(size_t)s * 4];
      float e0 = as.x + ad.x; e0 = e0 > 0.f ? e0 : SLOPE * e0;
      float e1 = as.y + ad.y; e1 = e1 > 0.f ? e1 : SLOPE * e1;
      float e2 = as.z + ad.z; e2 = e2 > 0.f ? e2 : SLOPE * e2;
      float e3 = as.w + ad.w; e3 = e3 > 0.f ? e3 : SLOPE * e3;
      const float es = hsel == 3 ? e3 : hsel == 2 ? e2 : hsel == 1 ? e1 : e0;
      const float pa = __expf(es - mxs);
      const unsigned uu = ((const unsigned*)(hbf + (size_t)s * 128))[l];
      acc0 = fmaf(pa, bf_lo(uu), acc0);
      acc1 = fmaf(pa, bf_hi(uu), acc1);
    }
  }
  const float rsel = hsel == 3 ? r3 : hsel == 2 ? r2 : hsel == 1 ? r1 : r0;
  const int c0 = 2 * l;
  const float2 bb = *(const float2*)&b1[c0];
  float o0 = acc0 * rsel + bb.x;
  float o1 = acc1 * rsel + bb.y;
  o0 = o0 > 0.f ? o0 : expm1f(o0);
  o1 = o1 > 0.f ? o1 : expm1f(o1);
  *(float2*)&y[(size_t)d * 128 + c0] = make_float2(o0, o1);
}

// ---------------- Layer-2 aggregation: 1 wave/dst, bf16 h, 64 ch --------
// Lanes 0-31 handle even edges, 32-63 odd edges; (src_off, p) pairs in LDS.
__global__ __launch_bounds__(256, 8) void k_agg2(const int* __restrict__ rowptr,
    const int* __restrict__ ebuf, const float* __restrict__ a_s,
    const float* __restrict__ a_d, const unsigned short* __restrict__ hbf,
    const float* __restrict__ b2, float* __restrict__ out)
{
  __shared__ uint2 pl2[4][66];
  const int w = threadIdx.x >> 6;
  const int l = threadIdx.x & 63;
  const int lh = l & 31;
  const bool hi = (l >= 32);
  const int d = blockIdx.x * 4 + w;
  const int base = rowptr[d];
  const int deg  = rowptr[d + 1] - base;
  const float ad = a_d[d];
  const unsigned lh4 = (unsigned)lh * 4u;
  float acc0 = 0.f, acc1 = 0.f;
  float rv;

  if (deg <= 64) {
    int   sreg = 0;
    float e = -1e30f;
    if (l < deg) {
      sreg = ebuf[base + l];
      e = a_s[sreg] + ad; e = e > 0.f ? e : SLOPE * e;
    }
    float mx = e;
#pragma unroll
    for (int m = 32; m >= 1; m >>= 1) mx = fmaxf(mx, __shfl_xor(mx, m));
    const float p = (l < deg) ? __expf(e - mx) : 0.f;
    float sm = p;
#pragma unroll
    for (int m = 32; m >= 1; m >>= 1) sm += __shfl_xor(sm, m);
    rv = 1.f / (sm + 1e-16f);
    if (l < deg)
      pl2[w][l] = make_uint2((unsigned)sreg << 7, __float_as_uint(p)); // 64 bf16 = 128 B
    const uint2* __restrict__ rp = &pl2[w][hi ? 1 : 0];
    int i = 0;
    for (; i + 8 <= deg; i += 8) {
#pragma unroll
      for (int u = 0; u < 8; u += 2) {
        const uint2 sp = rp[i + u];
        const unsigned uu =
            *(const unsigned*)((const char*)hbf + (sp.x + lh4));
        const float pp = __uint_as_float(sp.y);
        acc0 = fmaf(pp, bf_lo(uu), acc0);
        acc1 = fmaf(pp, bf_hi(uu), acc1);
      }
    }
    for (; i < deg; i += 2) {
      const bool act = (i + (hi ? 1 : 0)) < deg;
      const uint2 sp = act ? rp[i] : make_uint2(0u, 0u);
      const unsigned uu = act
          ? *(const unsigned*)((const char*)hbf + (sp.x + lh4)) : 0u;
      const float pp = __uint_as_float(sp.y);
      acc0 = fmaf(pp, bf_lo(uu), acc0);
      acc1 = fmaf(pp, bf_hi(uu), acc1);
    }
  } else {
    float mx = -1e30f;
    for (int i = l; i < deg; i += 64) {
      const int s = ebuf[base + i];
      float e = a_s[s] + ad; e = e > 0.f ? e : SLOPE * e;
      mx = fmaxf(mx, e);
    }
#pragma unroll
    for (int m = 32; m >= 1; m >>= 1) mx = fmaxf(mx, __shfl_xor(mx, m));
    float sm = 0.f;
    for (int i = l; i < deg; i += 64) {
      const int s = ebuf[base + i];
      float e = a_s[s] + ad; e = e > 0.f ? e : SLOPE * e;
      sm += __expf(e - mx);
    }
#pragma unroll
    for (int m = 32; m >= 1; m >>= 1) sm += __shfl_xor(sm, m);
    rv = 1.f / (sm + 1e-16f);
    for (int i = 0; i < deg; ++i) {
      const int s = ebuf[base + i];
      float e = a_s[s] + ad; e = e > 0.f ? e : SLOPE * e;
      const float pp = hi ? 0.f : __expf(e - mx);
      const unsigned uu = ((const unsigned*)(hbf + (size_t)s * 64))[lh];
      acc0 = fmaf(pp, bf_lo(uu), acc0);
      acc1 = fmaf(pp, bf_hi(uu), acc1);
    }
  }
  acc0 += __shfl_xor(acc0, 32);
  acc1 += __shfl_xor(acc1, 32);
  if (!hi) {
    const int c0 = 2 * lh;
    const float2 bb = *(const float2*)&b2[c0];
    *(float2*)&out[(size_t)d * 64 + c0] =
        make_float2(acc0 * rv + bb.x, acc1 * rv + bb.y);
  }
}

extern "C" void kernel_launch(void* const* d_in, const int* in_sizes, int n_in,
                              void* d_out, int out_size, void* d_ws, size_t ws_size,
                              hipStream_t stream) {
  const float* x     = (const float*)d_in[0];
  const int*   ei    = (const int*)d_in[1];
  const float* W1    = (const float*)d_in[2];
  const float* as1v  = (const float*)d_in[3];
  const float* ad1v  = (const float*)d_in[4];
  const float* b1    = (const float*)d_in[5];
  const float* W2    = (const float*)d_in[6];
  const float* as2v  = (const float*)d_in[7];
  const float* ad2v  = (const float*)d_in[8];
  const float* b2    = (const float*)d_in[9];
  float* out = (float*)d_out;

  char* ws = (char*)d_ws;
  unsigned short* h1 = (unsigned short*)(ws + OFF_H1);
  float* y1   = (float*)(ws + OFF_Y1);
  unsigned short* h2 = (unsigned short*)(ws + OFF_H2);
  float* a_s1 = (float*)(ws + OFF_AS1);
  float* a_d1 = (float*)(ws + OFF_AD1);
  float* a_s2 = (float*)(ws + OFF_AS2);
  float* a_d2 = (float*)(ws + OFF_AD2);
  int* rowptr = (int*)(ws + OFF_ROW);
  int* gcount = (int*)(ws + OFF_GC);
  int* goff   = (int*)(ws + OFF_GO);
  int* gcur   = (int*)(ws + OFF_GU);
  unsigned* eb1 = (unsigned*)(ws + OFF_EB1);
  int* ebuf   = (int*)(ws + OFF_EB);

  hipMemsetAsync(gcount, 0, (size_t)NB_ * 4, stream);

  k_gemm1<<<N_ / 16, 256, 0, stream>>>(x, W1, as1v, ad1v, h1, a_s1, a_d1);
  k_hist<<<NBLKA_, 256, 0, stream>>>(ei, gcount);
  k_scan<<<1, 512, 0, stream>>>(gcount, goff, gcur);
  k_scatter<<<NBLKA_, 256, 0, stream>>>(ei, gcur, eb1);
  k_bucket<<<NB_, 256, 0, stream>>>(eb1, goff, rowptr, ebuf);
  k_agg1<<<N_ / 4, 256, 0, stream>>>(rowptr, ebuf, a_s1, a_d1, h1, b1, y1);
  k_gemm2<<<N_ / 16, 256, 0, stream>>>(y1, W2, as2v, ad2v, h2, a_s2, a_d2);
  k_agg2<<<N_ / 4, 256, 0, stream>>>(rowptr, ebuf, a_s2, a_d2, h2, b2, out);
}

// Round 8
// 157.879 us; speedup vs baseline: 2.1146x; 1.2451x over previous
//
#include <hip/hip_runtime.h>
#include <math.h>

namespace {
constexpr int N_   = 50000;
constexpr int E_   = 800000;
constexpr int EP_  = E_ + N_;   // edges + self loops = 850000
constexpr float SLOPE = 0.2f;

constexpr int NB_    = (N_ + 127) / 128;          // 391 coarse buckets (dst>>7)
constexpr int CHUNK_ = 8192;                      // edges per scatter block
constexpr int NBLKA_ = (EP_ + CHUNK_ - 1) / CHUNK_; // 104
constexpr int CAPB_  = 4096;                      // LDS capacity per bucket
constexpr int NBLKG_ = (N_ + 63) / 64;            // 782 gemm blocks (64 rows)

// workspace layout (bytes)
constexpr size_t OFF_H1  = 0;                                    // [N][128] bf16
constexpr size_t OFF_Y1  = OFF_H1  + (size_t)N_ * 128 * 2;       // [N][128] bf16
constexpr size_t OFF_H2  = OFF_Y1  + (size_t)N_ * 128 * 2;       // [N][64] bf16
constexpr size_t OFF_AS1 = OFF_H2  + (size_t)N_ * 64 * 2;        // [N][4]
constexpr size_t OFF_AD1 = OFF_AS1 + (size_t)N_ * 4 * 4;         // [N][4]
constexpr size_t OFF_AS2 = OFF_AD1 + (size_t)N_ * 4 * 4;         // [N]
constexpr size_t OFF_AD2 = OFF_AS2 + (size_t)N_ * 4;             // [N]
constexpr size_t OFF_ROW = OFF_AD2 + (size_t)N_ * 4;             // [N+1] int
constexpr size_t OFF_GC  = OFF_ROW + (((size_t)(N_ + 1) * 4 + 15) & ~(size_t)15); // [NB] int
constexpr size_t OFF_GO  = OFF_GC  + (((size_t)NB_ * 4 + 15) & ~(size_t)15);      // [NB+1] int
constexpr size_t OFF_GU  = OFF_GO  + (((size_t)(NB_ + 1) * 4 + 15) & ~(size_t)15);// [NB] int
constexpr size_t OFF_EB1 = OFF_GU  + (((size_t)NB_ * 4 + 15) & ~(size_t)15);      // [EP] u32 (src<<16|dst)
constexpr size_t OFF_EB  = OFF_EB1 + (size_t)EP_ * 4;            // [EP] int (src, dst-sorted)
}

typedef __attribute__((ext_vector_type(8))) short short8;
typedef __attribute__((ext_vector_type(4))) float f32x4;

__device__ __forceinline__ unsigned short f2bf(float x) {   // RNE
  unsigned u = __float_as_uint(x);
  return (unsigned short)((u + 0x7FFFu + ((u >> 16) & 1u)) >> 16);
}
__device__ __forceinline__ unsigned pack2bf(float a, float b) {
  return (unsigned)f2bf(a) | ((unsigned)f2bf(b) << 16);
}
__device__ __forceinline__ float bf_lo(unsigned u) { return __uint_as_float(u << 16); }
__device__ __forceinline__ float bf_hi(unsigned u) { return __uint_as_float(u & 0xFFFF0000u); }

// ---------------- GEMM1 (MFMA bf16): h1 = x @ W1 ; a_s1/a_d1 -------------
// 64-row block, 4 waves x 16 rows. x staged bf16 [64][136] (pad->2-way bank).
// W staged k-pair-packed transposed: wt[n][68] u32, wt[n][kk]=(W[2kk][n],W[2kk+1][n]).
// C/D: col=lane&15, row=(lane>>4)*4+reg (HW-verified layout).
__global__ __launch_bounds__(256, 3) void k_gemm1(const float* __restrict__ x,
    const float* __restrict__ W, const float* __restrict__ av_s,
    const float* __restrict__ av_d, unsigned short* __restrict__ hbf,
    float* __restrict__ a_s, float* __restrict__ a_d)
{
  __shared__ __align__(16) char smem[52224];
  unsigned short* xs = (unsigned short*)smem;          // [64][136] bf16
  unsigned*       wt = (unsigned*)(smem + 17408);      // [128][68] u32
  float*         wtf = (float*)(smem + 17408);         // [64][132] f32 (epilogue)
  const int t = threadIdx.x;
  const int rbase = blockIdx.x * 64;
  // stage x -> bf16 LDS (2048 float4)
#pragma unroll
  for (int it = 0; it < 8; ++it) {
    const int fidx = t + it * 256;
    const int row = fidx >> 5;
    const int c4  = fidx & 31;
    const int rg  = rbase + row;
    float4 v = (rg < N_) ? ((const float4*)x)[(size_t)rg * 32 + c4]
                         : make_float4(0.f, 0.f, 0.f, 0.f);
    *(uint2*)&xs[row * 136 + c4 * 4] =
        make_uint2(pack2bf(v.x, v.y), pack2bf(v.z, v.w));
  }
  // stage W -> packed-transposed LDS (8192)
#pragma unroll
  for (int it = 0; it < 32; ++it) {
    const int idx = t + it * 256;
    const int n  = idx & 127;
    const int kk = idx >> 7;                // 0..63
    wt[n * 68 + kk] = pack2bf(W[(2 * kk) * 128 + n], W[(2 * kk + 1) * 128 + n]);
  }
  __syncthreads();
  const int wv = t >> 6;
  const int l  = t & 63;
  const int lr = l & 15;
  const int lg = l >> 4;
  f32x4 acc[8];
#pragma unroll
  for (int j = 0; j < 8; ++j) acc[j] = (f32x4){0.f, 0.f, 0.f, 0.f};
#pragma unroll
  for (int ks = 0; ks < 4; ++ks) {
    const short8 a = *(const short8*)&xs[(wv * 16 + lr) * 136 + ks * 32 + lg * 8];
#pragma unroll
    for (int j = 0; j < 8; ++j) {
      const short8 b = *(const short8*)&wt[(j * 16 + lr) * 68 + ks * 16 + lg * 4];
      acc[j] = __builtin_amdgcn_mfma_f32_16x16x32_bf16(a, b, acc[j], 0, 0, 0);
    }
  }
  __syncthreads();
  // acc -> f32 LDS [64][132]
#pragma unroll
  for (int j = 0; j < 8; ++j)
#pragma unroll
    for (int r = 0; r < 4; ++r)
      wtf[(wv * 16 + lg * 4 + r) * 132 + j * 16 + lr] = acc[j][r];
  __syncthreads();
  // h1 store (bf16, coalesced u32) — 4096 u32 = 64 rows x 64 u32 -> 16 iters
#pragma unroll
  for (int it = 0; it < 16; ++it) {
    const int idx = t + it * 256;
    const int row = idx >> 6;
    const int c2  = idx & 63;
    const int rg  = rbase + row;
    if (rg < N_) {
      const float2 hv = *(const float2*)&wtf[row * 132 + c2 * 2];
      ((unsigned*)hbf)[(size_t)rg * 64 + c2] = pack2bf(hv.x, hv.y);
    }
  }
  // a_s/a_d from f32 copy: thread row=t&63, head q=t>>6
  {
    const int row = t & 63;
    const int q   = t >> 6;
    const int rg  = rbase + row;
    float ss = 0.f, sd = 0.f;
#pragma unroll
    for (int i = 0; i < 8; ++i) {
      const float4 hv = *(const float4*)&wtf[row * 132 + q * 32 + 4 * i];
      const float4 s4 = *(const float4*)&av_s[q * 32 + 4 * i];
      const float4 d4 = *(const float4*)&av_d[q * 32 + 4 * i];
      ss += hv.x * s4.x + hv.y * s4.y + hv.z * s4.z + hv.w * s4.w;
      sd += hv.x * d4.x + hv.y * d4.y + hv.z * d4.z + hv.w * d4.w;
    }
    if (rg < N_) { a_s[rg * 4 + q] = ss; a_d[rg * 4 + q] = sd; }
  }
}

// ---------------- GEMM2 (MFMA bf16): h2 = y1 @ W2 ; a_s2/a_d2 ------------
__global__ __launch_bounds__(256, 4) void k_gemm2(const unsigned* __restrict__ ybf,
    const float* __restrict__ W, const float* __restrict__ av_s,
    const float* __restrict__ av_d, unsigned short* __restrict__ hbf,
    float* __restrict__ a_s, float* __restrict__ a_d)
{
  __shared__ __align__(16) char smem[36864];
  unsigned short* xs = (unsigned short*)smem;          // [64][136] bf16 (y)
  unsigned*       wt = (unsigned*)(smem + 17408);      // [64][68] u32
  float*         wtf = (float*)(smem + 17408);         // [64][68] f32 (epilogue)
  float*          ps = (float*)(smem + 34816);         // [2][4][64] partials
  const int t = threadIdx.x;
  const int rbase = blockIdx.x * 64;
  // stage y (already bf16) -> LDS (4096 u32)
#pragma unroll
  for (int it = 0; it < 16; ++it) {
    const int idx = t + it * 256;
    const int row = idx >> 6;
    const int c2  = idx & 63;
    const int rg  = rbase + row;
    const unsigned u = (rg < N_) ? ybf[(size_t)rg * 64 + c2] : 0u;
    *(unsigned*)&xs[row * 136 + c2 * 2] = u;
  }
  // stage W2 [128][64] -> packed-transposed (4096)
#pragma unroll
  for (int it = 0; it < 16; ++it) {
    const int idx = t + it * 256;
    const int n  = idx & 63;
    const int kk = idx >> 6;                // 0..63
    wt[n * 68 + kk] = pack2bf(W[(2 * kk) * 64 + n], W[(2 * kk + 1) * 64 + n]);
  }
  __syncthreads();
  const int wv = t >> 6;
  const int l  = t & 63;
  const int lr = l & 15;
  const int lg = l >> 4;
  f32x4 acc[4];
#pragma unroll
  for (int j = 0; j < 4; ++j) acc[j] = (f32x4){0.f, 0.f, 0.f, 0.f};
#pragma unroll
  for (int ks = 0; ks < 4; ++ks) {
    const short8 a = *(const short8*)&xs[(wv * 16 + lr) * 136 + ks * 32 + lg * 8];
#pragma unroll
    for (int j = 0; j < 4; ++j) {
      const short8 b = *(const short8*)&wt[(j * 16 + lr) * 68 + ks * 16 + lg * 4];
      acc[j] = __builtin_amdgcn_mfma_f32_16x16x32_bf16(a, b, acc[j], 0, 0, 0);
    }
  }
  __syncthreads();
#pragma unroll
  for (int j = 0; j < 4; ++j)
#pragma unroll
    for (int r = 0; r < 4; ++r)
      wtf[(wv * 16 + lg * 4 + r) * 68 + j * 16 + lr] = acc[j][r];
  __syncthreads();
  // h2 store (bf16, coalesced u32) — 2048 u32 = 64 rows x 32 u32
#pragma unroll
  for (int it = 0; it < 8; ++it) {
    const int idx = t + it * 256;
    const int row = idx >> 5;
    const int c2  = idx & 31;
    const int rg  = rbase + row;
    if (rg < N_) {
      const float2 hv = *(const float2*)&wtf[row * 68 + c2 * 2];
      ((unsigned*)hbf)[(size_t)rg * 32 + c2] = pack2bf(hv.x, hv.y);
    }
  }
  // a_s2/a_d2 (1 head, 64 ch): per-thread 16-ch partials, combine via LDS
  {
    const int row = t & 63;
    const int g   = t >> 6;
    float ss = 0.f, sd = 0.f;
#pragma unroll
    for (int i = 0; i < 4; ++i) {
      const float4 hv = *(const float4*)&wtf[row * 68 + g * 16 + 4 * i];
      const float4 s4 = *(const float4*)&av_s[g * 16 + 4 * i];
      const float4 d4 = *(const float4*)&av_d[g * 16 + 4 * i];
      ss += hv.x * s4.x + hv.y * s4.y + hv.z * s4.z + hv.w * s4.w;
      sd += hv.x * d4.x + hv.y * d4.y + hv.z * d4.z + hv.w * d4.w;
    }
    ps[g * 64 + row] = ss;
    ps[256 + g * 64 + row] = sd;
  }
  __syncthreads();
  if (t < 64) {
    const int rg = rbase + t;
    if (rg < N_) {
      a_s[rg] = ps[t] + ps[64 + t] + ps[128 + t] + ps[192 + t];
      a_d[rg] = ps[256 + t] + ps[320 + t] + ps[384 + t] + ps[448 + t];
    }
  }
}

// ---------------- CSR build: two-level counting sort ----------------
__global__ __launch_bounds__(256) void k_hist(const int* __restrict__ ei,
                                              int* __restrict__ gcount)
{
  __shared__ int nh[NB_];
  const int t = threadIdx.x;
  for (int j = t; j < NB_; j += 256) nh[j] = 0;
  __syncthreads();
  const int beg = blockIdx.x * CHUNK_;
  const int end = min(beg + CHUNK_, EP_);
  for (int i = beg + t; i < end; i += 256) {
    const int d = (i < E_) ? ei[E_ + i] : (i - E_);
    atomicAdd(&nh[d >> 7], 1);
  }
  __syncthreads();
  for (int j = t; j < NB_; j += 256)
    if (nh[j]) atomicAdd(&gcount[j], nh[j]);
}

__global__ __launch_bounds__(512) void k_scan(const int* __restrict__ gcount,
    int* __restrict__ goff, int* __restrict__ gcursor)
{
  __shared__ int sd[512];
  const int t = threadIdx.x;
  const int v = (t < NB_) ? gcount[t] : 0;
  sd[t] = v;
  __syncthreads();
  for (int off = 1; off < 512; off <<= 1) {
    const int add = (t >= off) ? sd[t - off] : 0;
    __syncthreads();
    sd[t] += add;
    __syncthreads();
  }
  if (t < NB_) { goff[t] = sd[t] - v; gcursor[t] = sd[t] - v; }
  if (t == 0) goff[NB_] = EP_;
}

__global__ __launch_bounds__(256) void k_scatter(const int* __restrict__ ei,
    int* __restrict__ gcursor, unsigned* __restrict__ eb1)
{
  __shared__ int nh[NB_];
  __shared__ int gb[NB_];
  const int t = threadIdx.x;
  for (int j = t; j < NB_; j += 256) nh[j] = 0;
  __syncthreads();
  const int beg = blockIdx.x * CHUNK_;
  const int end = min(beg + CHUNK_, EP_);
  for (int i = beg + t; i < end; i += 256) {
    const int d = (i < E_) ? ei[E_ + i] : (i - E_);
    atomicAdd(&nh[d >> 7], 1);
  }
  __syncthreads();
  for (int j = t; j < NB_; j += 256) {
    const int c = nh[j];
    gb[j] = c ? atomicAdd(&gcursor[j], c) : 0;
    nh[j] = 0;
  }
  __syncthreads();
  for (int i = beg + t; i < end; i += 256) {
    int s, d;
    if (i < E_) { s = ei[i]; d = ei[E_ + i]; } else { s = d = i - E_; }
    const int b = d >> 7;
    const int r = atomicAdd(&nh[b], 1);
    eb1[gb[b] + r] = ((unsigned)s << 16) | (unsigned)d;   // both < 65536
  }
}

__global__ __launch_bounds__(256) void k_bucket(const unsigned* __restrict__ eb1,
    const int* __restrict__ goff, int* __restrict__ rowptr,
    int* __restrict__ ebuf)
{
  __shared__ int h[128];
  __shared__ int off[129];
  __shared__ unsigned arrv[CAPB_];
  const int b = blockIdx.x;
  const int t = threadIdx.x;
  const int base = goff[b];
  const int cnt  = goff[b + 1] - base;
  if (t < 128) h[t] = 0;
  __syncthreads();
  const bool fits = (cnt <= CAPB_);
  for (int i = t; i < cnt; i += 256) {
    const unsigned v = eb1[base + i];
    if (fits) arrv[i] = v;
    atomicAdd(&h[(int)(v & 0xFFFFu) - (b << 7)], 1);
  }
  __syncthreads();
  if (t < 64) {
    const int a0 = h[2 * t], a1 = h[2 * t + 1];
    int s = a0 + a1;
#pragma unroll
    for (int m = 1; m < 64; m <<= 1) {
      const int u = __shfl_up(s, m);
      if (t >= m) s += u;
    }
    off[2 * t + 1] = s - a1;
    off[2 * t]     = s - a1 - a0;
    if (t == 63) off[128] = s;
  }
  __syncthreads();
  if (t < 128) {
    const int dst = (b << 7) + t;
    if (dst < N_) rowptr[dst] = base + off[t];
  }
  if (b == NB_ - 1 && t == 0) rowptr[N_] = EP_;
  if (t < 128) h[t] = 0;   // reuse as rank counters
  __syncthreads();
  for (int i = t; i < cnt; i += 256) {
    const unsigned v = fits ? arrv[i] : eb1[base + i];
    const int dlow = (int)(v & 0xFFFFu) - (b << 7);
    const int r = atomicAdd(&h[dlow], 1);
    ebuf[base + off[dlow] + r] = (int)(v >> 16);
  }
}

// ---------------- Layer-1 aggregation: 1 wave/dst, bf16 h, 128 ch -------
__global__ __launch_bounds__(256, 8) void k_agg1(const int* __restrict__ rowptr,
    const int* __restrict__ ebuf, const float* __restrict__ a_s,
    const float* __restrict__ a_d, const unsigned short* __restrict__ hbf,
    const float* __restrict__ b1, unsigned* __restrict__ y)
{
  __shared__ uint2 pl[4][4 * 65];
  const int w = threadIdx.x >> 6;
  const int l = threadIdx.x & 63;
  const int d = blockIdx.x * 4 + w;
  const int base = rowptr[d];
  const int deg  = rowptr[d + 1] - base;
  const float4 ad = *(const float4*)&a_d[(size_t)d * 4];
  const int hsel = l >> 4;
  const unsigned l4 = (unsigned)l * 4u;
  float acc0 = 0.f, acc1 = 0.f;
  float r0, r1, r2, r3;

  if (deg <= 64) {
    int   sreg = 0;
    float e0 = -1e30f, e1 = -1e30f, e2 = -1e30f, e3 = -1e30f;
    if (l < deg) {
      sreg = ebuf[base + l];
      const float4 as = *(const float4*)&a_s[(size_t)sreg * 4];
      e0 = as.x + ad.x; e0 = e0 > 0.f ? e0 : SLOPE * e0;
      e1 = as.y + ad.y; e1 = e1 > 0.f ? e1 : SLOPE * e1;
      e2 = as.z + ad.z; e2 = e2 > 0.f ? e2 : SLOPE * e2;
      e3 = as.w + ad.w; e3 = e3 > 0.f ? e3 : SLOPE * e3;
    }
    float mx0 = e0, mx1 = e1, mx2 = e2, mx3 = e3;
#pragma unroll
    for (int m = 32; m >= 1; m >>= 1) {
      mx0 = fmaxf(mx0, __shfl_xor(mx0, m));
      mx1 = fmaxf(mx1, __shfl_xor(mx1, m));
      mx2 = fmaxf(mx2, __shfl_xor(mx2, m));
      mx3 = fmaxf(mx3, __shfl_xor(mx3, m));
    }
    const float p0 = (l < deg) ? __expf(e0 - mx0) : 0.f;
    const float p1 = (l < deg) ? __expf(e1 - mx1) : 0.f;
    const float p2 = (l < deg) ? __expf(e2 - mx2) : 0.f;
    const float p3 = (l < deg) ? __expf(e3 - mx3) : 0.f;
    float sm0 = p0, sm1 = p1, sm2 = p2, sm3 = p3;
#pragma unroll
    for (int m = 32; m >= 1; m >>= 1) {
      sm0 += __shfl_xor(sm0, m);
      sm1 += __shfl_xor(sm1, m);
      sm2 += __shfl_xor(sm2, m);
      sm3 += __shfl_xor(sm3, m);
    }
    r0 = 1.f / (sm0 + 1e-16f);
    r1 = 1.f / (sm1 + 1e-16f);
    r2 = 1.f / (sm2 + 1e-16f);
    r3 = 1.f / (sm3 + 1e-16f);
    if (l < deg) {
      const unsigned soff = (unsigned)sreg << 8;
      pl[w][0 * 65 + l] = make_uint2(soff, __float_as_uint(p0));
      pl[w][1 * 65 + l] = make_uint2(soff, __float_as_uint(p1));
      pl[w][2 * 65 + l] = make_uint2(soff, __float_as_uint(p2));
      pl[w][3 * 65 + l] = make_uint2(soff, __float_as_uint(p3));
    }
    const uint2* __restrict__ rp = &pl[w][hsel * 65];
    int i = 0;
    for (; i + 8 <= deg; i += 8) {
#pragma unroll
      for (int u = 0; u < 8; ++u) {
        const uint2 sp = rp[i + u];
        const unsigned uu =
            *(const unsigned*)((const char*)hbf + (sp.x + l4));
        const float pa = __uint_as_float(sp.y);
        acc0 = fmaf(pa, bf_lo(uu), acc0);
        acc1 = fmaf(pa, bf_hi(uu), acc1);
      }
    }
    for (; i < deg; ++i) {
      const uint2 sp = rp[i];
      const unsigned uu =
          *(const unsigned*)((const char*)hbf + (sp.x + l4));
      const float pa = __uint_as_float(sp.y);
      acc0 = fmaf(pa, bf_lo(uu), acc0);
      acc1 = fmaf(pa, bf_hi(uu), acc1);
    }
  } else {
    float mx0 = -1e30f, mx1 = -1e30f, mx2 = -1e30f, mx3 = -1e30f;
    for (int i = l; i < deg; i += 64) {
      const int s = ebuf[base + i];
      const float4 as = *(const float4*)&a_s[(size_t)s * 4];
      float e0 = as.x + ad.x; e0 = e0 > 0.f ? e0 : SLOPE * e0;
      float e1 = as.y + ad.y; e1 = e1 > 0.f ? e1 : SLOPE * e1;
      float e2 = as.z + ad.z; e2 = e2 > 0.f ? e2 : SLOPE * e2;
      float e3 = as.w + ad.w; e3 = e3 > 0.f ? e3 : SLOPE * e3;
      mx0 = fmaxf(mx0, e0); mx1 = fmaxf(mx1, e1);
      mx2 = fmaxf(mx2, e2); mx3 = fmaxf(mx3, e3);
    }
#pragma unroll
    for (int m = 32; m >= 1; m >>= 1) {
      mx0 = fmaxf(mx0, __shfl_xor(mx0, m));
      mx1 = fmaxf(mx1, __shfl_xor(mx1, m));
      mx2 = fmaxf(mx2, __shfl_xor(mx2, m));
      mx3 = fmaxf(mx3, __shfl_xor(mx3, m));
    }
    float sm0 = 0.f, sm1 = 0.f, sm2 = 0.f, sm3 = 0.f;
    for (int i = l; i < deg; i += 64) {
      const int s = ebuf[base + i];
      const float4 as = *(const float4*)&a_s[(size_t)s * 4];
      float e0 = as.x + ad.x; e0 = e0 > 0.f ? e0 : SLOPE * e0;
      float e1 = as.y + ad.y; e1 = e1 > 0.f ? e1 : SLOPE * e1;
      float e2 = as.z + ad.z; e2 = e2 > 0.f ? e2 : SLOPE * e2;
      float e3 = as.w + ad.w; e3 = e3 > 0.f ? e3 : SLOPE * e3;
      sm0 += __expf(e0 - mx0); sm1 += __expf(e1 - mx1);
      sm2 += __expf(e2 - mx2); sm3 += __expf(e3 - mx3);
    }
#pragma unroll
    for (int m = 32; m >= 1; m >>= 1) {
      sm0 += __shfl_xor(sm0, m);
      sm1 += __shfl_xor(sm1, m);
      sm2 += __shfl_xor(sm2, m);
      sm3 += __shfl_xor(sm3, m);
    }
    r0 = 1.f / (sm0 + 1e-16f);
    r1 = 1.f / (sm1 + 1e-16f);
    r2 = 1.f / (sm2 + 1e-16f);
    r3 = 1.f / (sm3 + 1e-16f);
    const float mxs = hsel == 3 ? mx3 : hsel == 2 ? mx2 : hsel == 1 ? mx1 : mx0;
    for (int i = 0; i < deg; ++i) {
      const int s = ebuf[base + i];
      const float4 as = *(const float4*)&a_s[(size_t)s * 4];
      float e0 = as.x + ad.x; e0 = e0 > 0.f ? e0 : SLOPE * e0;
      float e1 = as.y + ad.y; e1 = e1 > 0.f ? e1 : SLOPE * e1;
      float e2 = as.z + ad.z; e2 = e2 > 0.f ? e2 : SLOPE * e2;
      float e3 = as.w + ad.w; e3 = e3 > 0.f ? e3 : SLOPE * e3;
      const float es = hsel == 3 ? e3 : hsel == 2 ? e2 : hsel == 1 ? e1 : e0;
      const float pa = __expf(es - mxs);
      const unsigned uu = ((const unsigned*)(hbf + (size_t)s * 128))[l];
      acc0 = fmaf(pa, bf_lo(uu), acc0);
      acc1 = fmaf(pa, bf_hi(uu), acc1);
    }
  }
  const float rsel = hsel == 3 ? r3 : hsel == 2 ? r2 : hsel == 1 ? r1 : r0;
  const int c0 = 2 * l;
  const float2 bb = *(const float2*)&b1[c0];
  float o0 = acc0 * rsel + bb.x;
  float o1 = acc1 * rsel + bb.y;
  o0 = o0 > 0.f ? o0 : expm1f(o0);
  o1 = o1 > 0.f ? o1 : expm1f(o1);
  y[(size_t)d * 64 + l] = pack2bf(o0, o1);   // y1 stored bf16
}

// ---------------- Layer-2 aggregation: 1 wave/dst, bf16 h, 64 ch --------
__global__ __launch_bounds__(256, 8) void k_agg2(const int* __restrict__ rowptr,
    const int* __restrict__ ebuf, const float* __restrict__ a_s,
    const float* __restrict__ a_d, const unsigned short* __restrict__ hbf,
    const float* __restrict__ b2, float* __restrict__ out)
{
  __shared__ uint2 pl2[4][66];
  const int w = threadIdx.x >> 6;
  const int l = threadIdx.x & 63;
  const int lh = l & 31;
  const bool hi = (l >= 32);
  const int d = blockIdx.x * 4 + w;
  const int base = rowptr[d];
  const int deg  = rowptr[d + 1] - base;
  const float ad = a_d[d];
  const unsigned lh4 = (unsigned)lh * 4u;
  float acc0 = 0.f, acc1 = 0.f;
  float rv;

  if (deg <= 64) {
    int   sreg = 0;
    float e = -1e30f;
    if (l < deg) {
      sreg = ebuf[base + l];
      e = a_s[sreg] + ad; e = e > 0.f ? e : SLOPE * e;
    }
    float mx = e;
#pragma unroll
    for (int m = 32; m >= 1; m >>= 1) mx = fmaxf(mx, __shfl_xor(mx, m));
    const float p = (l < deg) ? __expf(e - mx) : 0.f;
    float sm = p;
#pragma unroll
    for (int m = 32; m >= 1; m >>= 1) sm += __shfl_xor(sm, m);
    rv = 1.f / (sm + 1e-16f);
    if (l < deg)
      pl2[w][l] = make_uint2((unsigned)sreg << 7, __float_as_uint(p));
    const uint2* __restrict__ rp = &pl2[w][hi ? 1 : 0];
    int i = 0;
    for (; i + 8 <= deg; i += 8) {
#pragma unroll
      for (int u = 0; u < 8; u += 2) {
        const uint2 sp = rp[i + u];
        const unsigned uu =
            *(const unsigned*)((const char*)hbf + (sp.x + lh4));
        const float pp = __uint_as_float(sp.y);
        acc0 = fmaf(pp, bf_lo(uu), acc0);
        acc1 = fmaf(pp, bf_hi(uu), acc1);
      }
    }
    for (; i < deg; i += 2) {
      const bool act = (i + (hi ? 1 : 0)) < deg;
      const uint2 sp = act ? rp[i] : make_uint2(0u, 0u);
      const unsigned uu = act
          ? *(const unsigned*)((const char*)hbf + (sp.x + lh4)) : 0u;
      const float pp = __uint_as_float(sp.y);
      acc0 = fmaf(pp, bf_lo(uu), acc0);
      acc1 = fmaf(pp, bf_hi(uu), acc1);
    }
  } else {
    float mx = -1e30f;
    for (int i = l; i < deg; i += 64) {
      const int s = ebuf[base + i];
      float e = a_s[s] + ad; e = e > 0.f ? e : SLOPE * e;
      mx = fmaxf(mx, e);
    }
#pragma unroll
    for (int m = 32; m >= 1; m >>= 1) mx = fmaxf(mx, __shfl_xor(mx, m));
    float sm = 0.f;
    for (int i = l; i < deg; i += 64) {
      const int s = ebuf[base + i];
      float e = a_s[s] + ad; e = e > 0.f ? e : SLOPE * e;
      sm += __expf(e - mx);
    }
#pragma unroll
    for (int m = 32; m >= 1; m >>= 1) sm += __shfl_xor(sm, m);
    rv = 1.f / (sm + 1e-16f);
    for (int i = 0; i < deg; ++i) {
      const int s = ebuf[base + i];
      float e = a_s[s] + ad; e = e > 0.f ? e : SLOPE * e;
      const float pp = hi ? 0.f : __expf(e - mx);
      const unsigned uu = ((const unsigned*)(hbf + (size_t)s * 64))[lh];
      acc0 = fmaf(pp, bf_lo(uu), acc0);
      acc1 = fmaf(pp, bf_hi(uu), acc1);
    }
  }
  acc0 += __shfl_xor(acc0, 32);
  acc1 += __shfl_xor(acc1, 32);
  if (!hi) {
    const int c0 = 2 * lh;
    const float2 bb = *(const float2*)&b2[c0];
    *(float2*)&out[(size_t)d * 64 + c0] =
        make_float2(acc0 * rv + bb.x, acc1 * rv + bb.y);
  }
}

extern "C" void kernel_launch(void* const* d_in, const int* in_sizes, int n_in,
                              void* d_out, int out_size, void* d_ws, size_t ws_size,
                              hipStream_t stream) {
  const float* x     = (const float*)d_in[0];
  const int*   ei    = (const int*)d_in[1];
  const float* W1    = (const float*)d_in[2];
  const float* as1v  = (const float*)d_in[3];
  const float* ad1v  = (const float*)d_in[4];
  const float* b1    = (const float*)d_in[5];
  const float* W2    = (const float*)d_in[6];
  const float* as2v  = (const float*)d_in[7];
  const float* ad2v  = (const float*)d_in[8];
  const float* b2    = (const float*)d_in[9];
  float* out = (float*)d_out;

  char* ws = (char*)d_ws;
  unsigned short* h1 = (unsigned short*)(ws + OFF_H1);
  unsigned* y1       = (unsigned*)(ws + OFF_Y1);
  unsigned short* h2 = (unsigned short*)(ws + OFF_H2);
  float* a_s1 = (float*)(ws + OFF_AS1);
  float* a_d1 = (float*)(ws + OFF_AD1);
  float* a_s2 = (float*)(ws + OFF_AS2);
  float* a_d2 = (float*)(ws + OFF_AD2);
  int* rowptr = (int*)(ws + OFF_ROW);
  int* gcount = (int*)(ws + OFF_GC);
  int* goff   = (int*)(ws + OFF_GO);
  int* gcur   = (int*)(ws + OFF_GU);
  unsigned* eb1 = (unsigned*)(ws + OFF_EB1);
  int* ebuf   = (int*)(ws + OFF_EB);

  hipMemsetAsync(gcount, 0, (size_t)NB_ * 4, stream);

  k_gemm1<<<NBLKG_, 256, 0, stream>>>(x, W1, as1v, ad1v, h1, a_s1, a_d1);
  k_hist<<<NBLKA_, 256, 0, stream>>>(ei, gcount);
  k_scan<<<1, 512, 0, stream>>>(gcount, goff, gcur);
  k_scatter<<<NBLKA_, 256, 0, stream>>>(ei, gcur, eb1);
  k_bucket<<<NB_, 256, 0, stream>>>(eb1, goff, rowptr, ebuf);
  k_agg1<<<N_ / 4, 256, 0, stream>>>(rowptr, ebuf, a_s1, a_d1, h1, b1, y1);
  k_gemm2<<<NBLKG_, 256, 0, stream>>>(y1, W2, as2v, ad2v, h2, a_s2, a_d2);
  k_agg2<<<N_ / 4, 256, 0, stream>>>(rowptr, ebuf, a_s2, a_d2, h2, b2, out);
}

// Round 9
// 152.101 us; speedup vs baseline: 2.1949x; 1.0380x over previous
//
#include <hip/hip_runtime.h>
#include <math.h>

namespace {
constexpr int N_   = 50000;
constexpr int E_   = 800000;
constexpr int EP_  = E_ + N_;   // edges + self loops = 850000
constexpr float SLOPE = 0.2f;

constexpr int NB_    = (N_ + 127) / 128;          // 391 coarse buckets (dst>>7)
constexpr int CHUNK_ = 8192;                      // edges per scatter block
constexpr int NBLKA_ = (EP_ + CHUNK_ - 1) / CHUNK_; // 104
constexpr int CAPB_  = 4096;                      // LDS capacity per bucket
constexpr int NBLKG_ = (N_ + 63) / 64;            // 782 gemm blocks (64 rows)

// workspace layout (bytes)
constexpr size_t OFF_H1  = 0;                                    // [N][128] bf16
constexpr size_t OFF_Y1  = OFF_H1  + (size_t)N_ * 128 * 2;       // [N][128] bf16
constexpr size_t OFF_H2  = OFF_Y1  + (size_t)N_ * 128 * 2;       // [N][64] bf16
constexpr size_t OFF_AS1 = OFF_H2  + (size_t)N_ * 64 * 2;        // [N][4]
constexpr size_t OFF_AD1 = OFF_AS1 + (size_t)N_ * 4 * 4;         // [N][4]
constexpr size_t OFF_AS2 = OFF_AD1 + (size_t)N_ * 4 * 4;         // [N]
constexpr size_t OFF_AD2 = OFF_AS2 + (size_t)N_ * 4;             // [N]
constexpr size_t OFF_ROW = OFF_AD2 + (size_t)N_ * 4;             // [N+1] int
constexpr size_t OFF_GC  = OFF_ROW + (((size_t)(N_ + 1) * 4 + 15) & ~(size_t)15); // [NB] int
constexpr size_t OFF_GO  = OFF_GC  + (((size_t)NB_ * 4 + 15) & ~(size_t)15);      // [NB+1] int
constexpr size_t OFF_GU  = OFF_GO  + (((size_t)(NB_ + 1) * 4 + 15) & ~(size_t)15);// [NB] int
constexpr size_t OFF_EB1 = OFF_GU  + (((size_t)NB_ * 4 + 15) & ~(size_t)15);      // [EP] u32 (src<<16|dst)
constexpr size_t OFF_EB  = OFF_EB1 + (size_t)EP_ * 4;            // [EP] int (src, dst-sorted)
}

typedef __attribute__((ext_vector_type(8))) short short8;
typedef __attribute__((ext_vector_type(4))) float f32x4;

__device__ __forceinline__ unsigned short f2bf(float x) {   // RNE
  unsigned u = __float_as_uint(x);
  return (unsigned short)((u + 0x7FFFu + ((u >> 16) & 1u)) >> 16);
}
__device__ __forceinline__ unsigned pack2bf(float a, float b) {
  return (unsigned)f2bf(a) | ((unsigned)f2bf(b) << 16);
}
__device__ __forceinline__ float bf_lo(unsigned u) { return __uint_as_float(u << 16); }
__device__ __forceinline__ float bf_hi(unsigned u) { return __uint_as_float(u & 0xFFFF0000u); }

// ---------------- GEMM1 (MFMA bf16): h1 = x @ W1 ; a_s1/a_d1 -------------
__global__ __launch_bounds__(256, 3) void k_gemm1(const float* __restrict__ x,
    const float* __restrict__ W, const float* __restrict__ av_s,
    const float* __restrict__ av_d, unsigned short* __restrict__ hbf,
    float* __restrict__ a_s, float* __restrict__ a_d)
{
  __shared__ __align__(16) char smem[52224];
  unsigned short* xs = (unsigned short*)smem;          // [64][136] bf16
  unsigned*       wt = (unsigned*)(smem + 17408);      // [128][68] u32
  float*         wtf = (float*)(smem + 17408);         // [64][132] f32 (epilogue)
  const int t = threadIdx.x;
  const int rbase = blockIdx.x * 64;
#pragma unroll
  for (int it = 0; it < 8; ++it) {
    const int fidx = t + it * 256;
    const int row = fidx >> 5;
    const int c4  = fidx & 31;
    const int rg  = rbase + row;
    float4 v = (rg < N_) ? ((const float4*)x)[(size_t)rg * 32 + c4]
                         : make_float4(0.f, 0.f, 0.f, 0.f);
    *(uint2*)&xs[row * 136 + c4 * 4] =
        make_uint2(pack2bf(v.x, v.y), pack2bf(v.z, v.w));
  }
#pragma unroll
  for (int it = 0; it < 32; ++it) {
    const int idx = t + it * 256;
    const int n  = idx & 127;
    const int kk = idx >> 7;                // 0..63
    wt[n * 68 + kk] = pack2bf(W[(2 * kk) * 128 + n], W[(2 * kk + 1) * 128 + n]);
  }
  __syncthreads();
  const int wv = t >> 6;
  const int l  = t & 63;
  const int lr = l & 15;
  const int lg = l >> 4;
  f32x4 acc[8];
#pragma unroll
  for (int j = 0; j < 8; ++j) acc[j] = (f32x4){0.f, 0.f, 0.f, 0.f};
#pragma unroll
  for (int ks = 0; ks < 4; ++ks) {
    const short8 a = *(const short8*)&xs[(wv * 16 + lr) * 136 + ks * 32 + lg * 8];
#pragma unroll
    for (int j = 0; j < 8; ++j) {
      const short8 b = *(const short8*)&wt[(j * 16 + lr) * 68 + ks * 16 + lg * 4];
      acc[j] = __builtin_amdgcn_mfma_f32_16x16x32_bf16(a, b, acc[j], 0, 0, 0);
    }
  }
  __syncthreads();
#pragma unroll
  for (int j = 0; j < 8; ++j)
#pragma unroll
    for (int r = 0; r < 4; ++r)
      wtf[(wv * 16 + lg * 4 + r) * 132 + j * 16 + lr] = acc[j][r];
  __syncthreads();
  // h1 store — 4096 u32 = 64 rows x 64 u32 -> 16 iters
#pragma unroll
  for (int it = 0; it < 16; ++it) {
    const int idx = t + it * 256;
    const int row = idx >> 6;
    const int c2  = idx & 63;
    const int rg  = rbase + row;
    if (rg < N_) {
      const float2 hv = *(const float2*)&wtf[row * 132 + c2 * 2];
      ((unsigned*)hbf)[(size_t)rg * 64 + c2] = pack2bf(hv.x, hv.y);
    }
  }
  {
    const int row = t & 63;
    const int q   = t >> 6;
    const int rg  = rbase + row;
    float ss = 0.f, sd = 0.f;
#pragma unroll
    for (int i = 0; i < 8; ++i) {
      const float4 hv = *(const float4*)&wtf[row * 132 + q * 32 + 4 * i];
      const float4 s4 = *(const float4*)&av_s[q * 32 + 4 * i];
      const float4 d4 = *(const float4*)&av_d[q * 32 + 4 * i];
      ss += hv.x * s4.x + hv.y * s4.y + hv.z * s4.z + hv.w * s4.w;
      sd += hv.x * d4.x + hv.y * d4.y + hv.z * d4.z + hv.w * d4.w;
    }
    if (rg < N_) { a_s[rg * 4 + q] = ss; a_d[rg * 4 + q] = sd; }
  }
}

// ---------------- GEMM2 (MFMA bf16): h2 = y1 @ W2 ; a_s2/a_d2 ------------
__global__ __launch_bounds__(256, 4) void k_gemm2(const unsigned* __restrict__ ybf,
    const float* __restrict__ W, const float* __restrict__ av_s,
    const float* __restrict__ av_d, unsigned short* __restrict__ hbf,
    float* __restrict__ a_s, float* __restrict__ a_d)
{
  __shared__ __align__(16) char smem[36864];
  unsigned short* xs = (unsigned short*)smem;          // [64][136] bf16 (y)
  unsigned*       wt = (unsigned*)(smem + 17408);      // [64][68] u32
  float*         wtf = (float*)(smem + 17408);         // [64][68] f32 (epilogue)
  float*          ps = (float*)(smem + 34816);         // [2][4][64] partials
  const int t = threadIdx.x;
  const int rbase = blockIdx.x * 64;
#pragma unroll
  for (int it = 0; it < 16; ++it) {
    const int idx = t + it * 256;
    const int row = idx >> 6;
    const int c2  = idx & 63;
    const int rg  = rbase + row;
    const unsigned u = (rg < N_) ? ybf[(size_t)rg * 64 + c2] : 0u;
    *(unsigned*)&xs[row * 136 + c2 * 2] = u;
  }
#pragma unroll
  for (int it = 0; it < 16; ++it) {
    const int idx = t + it * 256;
    const int n  = idx & 63;
    const int kk = idx >> 6;                // 0..63
    wt[n * 68 + kk] = pack2bf(W[(2 * kk) * 64 + n], W[(2 * kk + 1) * 64 + n]);
  }
  __syncthreads();
  const int wv = t >> 6;
  const int l  = t & 63;
  const int lr = l & 15;
  const int lg = l >> 4;
  f32x4 acc[4];
#pragma unroll
  for (int j = 0; j < 4; ++j) acc[j] = (f32x4){0.f, 0.f, 0.f, 0.f};
#pragma unroll
  for (int ks = 0; ks < 4; ++ks) {
    const short8 a = *(const short8*)&xs[(wv * 16 + lr) * 136 + ks * 32 + lg * 8];
#pragma unroll
    for (int j = 0; j < 4; ++j) {
      const short8 b = *(const short8*)&wt[(j * 16 + lr) * 68 + ks * 16 + lg * 4];
      acc[j] = __builtin_amdgcn_mfma_f32_16x16x32_bf16(a, b, acc[j], 0, 0, 0);
    }
  }
  __syncthreads();
#pragma unroll
  for (int j = 0; j < 4; ++j)
#pragma unroll
    for (int r = 0; r < 4; ++r)
      wtf[(wv * 16 + lg * 4 + r) * 68 + j * 16 + lr] = acc[j][r];
  __syncthreads();
#pragma unroll
  for (int it = 0; it < 8; ++it) {
    const int idx = t + it * 256;
    const int row = idx >> 5;
    const int c2  = idx & 31;
    const int rg  = rbase + row;
    if (rg < N_) {
      const float2 hv = *(const float2*)&wtf[row * 68 + c2 * 2];
      ((unsigned*)hbf)[(size_t)rg * 32 + c2] = pack2bf(hv.x, hv.y);
    }
  }
  {
    const int row = t & 63;
    const int g   = t >> 6;
    float ss = 0.f, sd = 0.f;
#pragma unroll
    for (int i = 0; i < 4; ++i) {
      const float4 hv = *(const float4*)&wtf[row * 68 + g * 16 + 4 * i];
      const float4 s4 = *(const float4*)&av_s[g * 16 + 4 * i];
      const float4 d4 = *(const float4*)&av_d[g * 16 + 4 * i];
      ss += hv.x * s4.x + hv.y * s4.y + hv.z * s4.z + hv.w * s4.w;
      sd += hv.x * d4.x + hv.y * d4.y + hv.z * d4.z + hv.w * d4.w;
    }
    ps[g * 64 + row] = ss;
    ps[256 + g * 64 + row] = sd;
  }
  __syncthreads();
  if (t < 64) {
    const int rg = rbase + t;
    if (rg < N_) {
      a_s[rg] = ps[t] + ps[64 + t] + ps[128 + t] + ps[192 + t];
      a_d[rg] = ps[256 + t] + ps[320 + t] + ps[384 + t] + ps[448 + t];
    }
  }
}

// ---------------- CSR build: two-level counting sort ----------------
__global__ __launch_bounds__(256) void k_hist(const int* __restrict__ ei,
                                              int* __restrict__ gcount)
{
  __shared__ int nh[NB_];
  const int t = threadIdx.x;
  for (int j = t; j < NB_; j += 256) nh[j] = 0;
  __syncthreads();
  const int beg = blockIdx.x * CHUNK_;
  const int end = min(beg + CHUNK_, EP_);
  for (int i = beg + t; i < end; i += 256) {
    const int d = (i < E_) ? ei[E_ + i] : (i - E_);
    atomicAdd(&nh[d >> 7], 1);
  }
  __syncthreads();
  for (int j = t; j < NB_; j += 256)
    if (nh[j]) atomicAdd(&gcount[j], nh[j]);
}

__global__ __launch_bounds__(512) void k_scan(const int* __restrict__ gcount,
    int* __restrict__ goff, int* __restrict__ gcursor)
{
  __shared__ int sd[512];
  const int t = threadIdx.x;
  const int v = (t < NB_) ? gcount[t] : 0;
  sd[t] = v;
  __syncthreads();
  for (int off = 1; off < 512; off <<= 1) {
    const int add = (t >= off) ? sd[t - off] : 0;
    __syncthreads();
    sd[t] += add;
    __syncthreads();
  }
  if (t < NB_) { goff[t] = sd[t] - v; gcursor[t] = sd[t] - v; }
  if (t == 0) goff[NB_] = EP_;
}

__global__ __launch_bounds__(256) void k_scatter(const int* __restrict__ ei,
    int* __restrict__ gcursor, unsigned* __restrict__ eb1)
{
  __shared__ int nh[NB_];
  __shared__ int gb[NB_];
  const int t = threadIdx.x;
  for (int j = t; j < NB_; j += 256) nh[j] = 0;
  __syncthreads();
  const int beg = blockIdx.x * CHUNK_;
  const int end = min(beg + CHUNK_, EP_);
  for (int i = beg + t; i < end; i += 256) {
    const int d = (i < E_) ? ei[E_ + i] : (i - E_);
    atomicAdd(&nh[d >> 7], 1);
  }
  __syncthreads();
  for (int j = t; j < NB_; j += 256) {
    const int c = nh[j];
    gb[j] = c ? atomicAdd(&gcursor[j], c) : 0;
    nh[j] = 0;
  }
  __syncthreads();
  for (int i = beg + t; i < end; i += 256) {
    int s, d;
    if (i < E_) { s = ei[i]; d = ei[E_ + i]; } else { s = d = i - E_; }
    const int b = d >> 7;
    const int r = atomicAdd(&nh[b], 1);
    eb1[gb[b] + r] = ((unsigned)s << 16) | (unsigned)d;   // both < 65536
  }
}

__global__ __launch_bounds__(256) void k_bucket(const unsigned* __restrict__ eb1,
    const int* __restrict__ goff, int* __restrict__ rowptr,
    int* __restrict__ ebuf)
{
  __shared__ int h[128];
  __shared__ int off[129];
  __shared__ unsigned arrv[CAPB_];
  const int b = blockIdx.x;
  const int t = threadIdx.x;
  const int base = goff[b];
  const int cnt  = goff[b + 1] - base;
  if (t < 128) h[t] = 0;
  __syncthreads();
  const bool fits = (cnt <= CAPB_);
  for (int i = t; i < cnt; i += 256) {
    const unsigned v = eb1[base + i];
    if (fits) arrv[i] = v;
    atomicAdd(&h[(int)(v & 0xFFFFu) - (b << 7)], 1);
  }
  __syncthreads();
  if (t < 64) {
    const int a0 = h[2 * t], a1 = h[2 * t + 1];
    int s = a0 + a1;
#pragma unroll
    for (int m = 1; m < 64; m <<= 1) {
      const int u = __shfl_up(s, m);
      if (t >= m) s += u;
    }
    off[2 * t + 1] = s - a1;
    off[2 * t]     = s - a1 - a0;
    if (t == 63) off[128] = s;
  }
  __syncthreads();
  if (t < 128) {
    const int dst = (b << 7) + t;
    if (dst < N_) rowptr[dst] = base + off[t];
  }
  if (b == NB_ - 1 && t == 0) rowptr[N_] = EP_;
  if (t < 128) h[t] = 0;   // reuse as rank counters
  __syncthreads();
  for (int i = t; i < cnt; i += 256) {
    const unsigned v = fits ? arrv[i] : eb1[base + i];
    const int dlow = (int)(v & 0xFFFFu) - (b << 7);
    const int r = atomicAdd(&h[dlow], 1);
    ebuf[base + off[dlow] + r] = (int)(v >> 16);
  }
}

// ---------------- Layer-1 aggregation: 1 wave/dst, bf16 h, 128 ch -------
// (src_off, p) table zero-padded (p=0 edges are no-op FMAs on row 0), so the
// gather is a tail-free batch loop: 2 batches of 8 edges in flight (16 loads
// issued before the FMAs) for latency hiding.
__global__ __launch_bounds__(256, 8) void k_agg1(const int* __restrict__ rowptr,
    const int* __restrict__ ebuf, const float* __restrict__ a_s,
    const float* __restrict__ a_d, const unsigned short* __restrict__ hbf,
    const float* __restrict__ b1, unsigned* __restrict__ y)
{
  __shared__ uint2 pl[4][4 * 65];
  const int w = threadIdx.x >> 6;
  const int l = threadIdx.x & 63;
  const int d = blockIdx.x * 4 + w;
  const int base = rowptr[d];
  const int deg  = rowptr[d + 1] - base;
  const float4 ad = *(const float4*)&a_d[(size_t)d * 4];
  const int hsel = l >> 4;
  const unsigned l4 = (unsigned)l * 4u;
  float acc0 = 0.f, acc1 = 0.f;
  float r0, r1, r2, r3;

  if (deg <= 64) {
    int   sreg = 0;
    float e0 = -1e30f, e1 = -1e30f, e2 = -1e30f, e3 = -1e30f;
    if (l < deg) {
      sreg = ebuf[base + l];
      const float4 as = *(const float4*)&a_s[(size_t)sreg * 4];
      e0 = as.x + ad.x; e0 = e0 > 0.f ? e0 : SLOPE * e0;
      e1 = as.y + ad.y; e1 = e1 > 0.f ? e1 : SLOPE * e1;
      e2 = as.z + ad.z; e2 = e2 > 0.f ? e2 : SLOPE * e2;
      e3 = as.w + ad.w; e3 = e3 > 0.f ? e3 : SLOPE * e3;
    }
    float mx0 = e0, mx1 = e1, mx2 = e2, mx3 = e3;
#pragma unroll
    for (int m = 32; m >= 1; m >>= 1) {
      mx0 = fmaxf(mx0, __shfl_xor(mx0, m));
      mx1 = fmaxf(mx1, __shfl_xor(mx1, m));
      mx2 = fmaxf(mx2, __shfl_xor(mx2, m));
      mx3 = fmaxf(mx3, __shfl_xor(mx3, m));
    }
    const float p0 = (l < deg) ? __expf(e0 - mx0) : 0.f;
    const float p1 = (l < deg) ? __expf(e1 - mx1) : 0.f;
    const float p2 = (l < deg) ? __expf(e2 - mx2) : 0.f;
    const float p3 = (l < deg) ? __expf(e3 - mx3) : 0.f;
    float sm0 = p0, sm1 = p1, sm2 = p2, sm3 = p3;
#pragma unroll
    for (int m = 32; m >= 1; m >>= 1) {
      sm0 += __shfl_xor(sm0, m);
      sm1 += __shfl_xor(sm1, m);
      sm2 += __shfl_xor(sm2, m);
      sm3 += __shfl_xor(sm3, m);
    }
    r0 = 1.f / (sm0 + 1e-16f);
    r1 = 1.f / (sm1 + 1e-16f);
    r2 = 1.f / (sm2 + 1e-16f);
    r3 = 1.f / (sm3 + 1e-16f);
    // zero-padded table: lanes l>=deg have sreg=0, p*=0
    {
      const unsigned soff = (unsigned)sreg << 8;
      pl[w][0 * 65 + l] = make_uint2(soff, __float_as_uint(p0));
      pl[w][1 * 65 + l] = make_uint2(soff, __float_as_uint(p1));
      pl[w][2 * 65 + l] = make_uint2(soff, __float_as_uint(p2));
      pl[w][3 * 65 + l] = make_uint2(soff, __float_as_uint(p3));
    }
    const uint2* __restrict__ rp = &pl[w][hsel * 65];
    const int niter = (deg + 7) >> 3;
    int it = 0;
    for (; it + 2 <= niter; it += 2) {
      unsigned uA[8], uB[8];
      float pA[8], pB[8];
#pragma unroll
      for (int u = 0; u < 8; ++u) {
        const uint2 sp = rp[it * 8 + u];
        pA[u] = __uint_as_float(sp.y);
        uA[u] = *(const unsigned*)((const char*)hbf + (sp.x + l4));
      }
#pragma unroll
      for (int u = 0; u < 8; ++u) {
        const uint2 sp = rp[it * 8 + 8 + u];
        pB[u] = __uint_as_float(sp.y);
        uB[u] = *(const unsigned*)((const char*)hbf + (sp.x + l4));
      }
#pragma unroll
      for (int u = 0; u < 8; ++u) {
        acc0 = fmaf(pA[u], bf_lo(uA[u]), acc0);
        acc1 = fmaf(pA[u], bf_hi(uA[u]), acc1);
      }
#pragma unroll
      for (int u = 0; u < 8; ++u) {
        acc0 = fmaf(pB[u], bf_lo(uB[u]), acc0);
        acc1 = fmaf(pB[u], bf_hi(uB[u]), acc1);
      }
    }
    if (it < niter) {
      unsigned uA[8];
      float pA[8];
#pragma unroll
      for (int u = 0; u < 8; ++u) {
        const uint2 sp = rp[it * 8 + u];
        pA[u] = __uint_as_float(sp.y);
        uA[u] = *(const unsigned*)((const char*)hbf + (sp.x + l4));
      }
#pragma unroll
      for (int u = 0; u < 8; ++u) {
        acc0 = fmaf(pA[u], bf_lo(uA[u]), acc0);
        acc1 = fmaf(pA[u], bf_hi(uA[u]), acc1);
      }
    }
  } else {
    // ---- any-deg fallback (never taken for this graph, kept for safety) --
    float mx0 = -1e30f, mx1 = -1e30f, mx2 = -1e30f, mx3 = -1e30f;
    for (int i = l; i < deg; i += 64) {
      const int s = ebuf[base + i];
      const float4 as = *(const float4*)&a_s[(size_t)s * 4];
      float e0 = as.x + ad.x; e0 = e0 > 0.f ? e0 : SLOPE * e0;
      float e1 = as.y + ad.y; e1 = e1 > 0.f ? e1 : SLOPE * e1;
      float e2 = as.z + ad.z; e2 = e2 > 0.f ? e2 : SLOPE * e2;
      float e3 = as.w + ad.w; e3 = e3 > 0.f ? e3 : SLOPE * e3;
      mx0 = fmaxf(mx0, e0); mx1 = fmaxf(mx1, e1);
      mx2 = fmaxf(mx2, e2); mx3 = fmaxf(mx3, e3);
    }
#pragma unroll
    for (int m = 32; m >= 1; m >>= 1) {
      mx0 = fmaxf(mx0, __shfl_xor(mx0, m));
      mx1 = fmaxf(mx1, __shfl_xor(mx1, m));
      mx2 = fmaxf(mx2, __shfl_xor(mx2, m));
      mx3 = fmaxf(mx3, __shfl_xor(mx3, m));
    }
    float sm0 = 0.f, sm1 = 0.f, sm2 = 0.f, sm3 = 0.f;
    for (int i = l; i < deg; i += 64) {
      const int s = ebuf[base + i];
      const float4 as = *(const float4*)&a_s[(size_t)s * 4];
      float e0 = as.x + ad.x; e0 = e0 > 0.f ? e0 : SLOPE * e0;
      float e1 = as.y + ad.y; e1 = e1 > 0.f ? e1 : SLOPE * e1;
      float e2 = as.z + ad.z; e2 = e2 > 0.f ? e2 : SLOPE * e2;
      float e3 = as.w + ad.w; e3 = e3 > 0.f ? e3 : SLOPE * e3;
      sm0 += __expf(e0 - mx0); sm1 += __expf(e1 - mx1);
      sm2 += __expf(e2 - mx2); sm3 += __expf(e3 - mx3);
    }
#pragma unroll
    for (int m = 32; m >= 1; m >>= 1) {
      sm0 += __shfl_xor(sm0, m);
      sm1 += __shfl_xor(sm1, m);
      sm2 += __shfl_xor(sm2, m);
      sm3 += __shfl_xor(sm3, m);
    }
    r0 = 1.f / (sm0 + 1e-16f);
    r1 = 1.f / (sm1 + 1e-16f);
    r2 = 1.f / (sm2 + 1e-16f);
    r3 = 1.f / (sm3 + 1e-16f);
    const float mxs = hsel == 3 ? mx3 : hsel == 2 ? mx2 : hsel == 1 ? mx1 : mx0;
    for (int i = 0; i < deg; ++i) {
      const int s = ebuf[base + i];
      const float4 as = *(const float4*)&a_s[(size_t)s * 4];
      float e0 = as.x + ad.x; e0 = e0 > 0.f ? e0 : SLOPE * e0;
      float e1 = as.y + ad.y; e1 = e1 > 0.f ? e1 : SLOPE * e1;
      float e2 = as.z + ad.z; e2 = e2 > 0.f ? e2 : SLOPE * e2;
      float e3 = as.w + ad.w; e3 = e3 > 0.f ? e3 : SLOPE * e3;
      const float es = hsel == 3 ? e3 : hsel == 2 ? e2 : hsel == 1 ? e1 : e0;
      const float pa = __expf(es - mxs);
      const unsigned uu = ((const unsigned*)(hbf + (size_t)s * 128))[l];
      acc0 = fmaf(pa, bf_lo(uu), acc0);
      acc1 = fmaf(pa, bf_hi(uu), acc1);
    }
  }
  const float rsel = hsel == 3 ? r3 : hsel == 2 ? r2 : hsel == 1 ? r1 : r0;
  const int c0 = 2 * l;
  const float2 bb = *(const float2*)&b1[c0];
  float o0 = acc0 * rsel + bb.x;
  float o1 = acc1 * rsel + bb.y;
  o0 = o0 > 0.f ? o0 : expm1f(o0);
  o1 = o1 > 0.f ? o1 : expm1f(o1);
  y[(size_t)d * 64 + l] = pack2bf(o0, o1);   // y1 stored bf16
}

// ---------------- Layer-2 aggregation: 1 wave/dst, bf16 h, 64 ch --------
// Lanes 0-31 even edges, 32-63 odd edges; zero-padded table, batch loop
// over 8 edge-pairs (16 edges), 2 batches pipelined.
__global__ __launch_bounds__(256, 8) void k_agg2(const int* __restrict__ rowptr,
    const int* __restrict__ ebuf, const float* __restrict__ a_s,
    const float* __restrict__ a_d, const unsigned short* __restrict__ hbf,
    const float* __restrict__ b2, float* __restrict__ out)
{
  __shared__ uint2 pl2[4][66];
  const int w = threadIdx.x >> 6;
  const int l = threadIdx.x & 63;
  const int lh = l & 31;
  const bool hi = (l >= 32);
  const int d = blockIdx.x * 4 + w;
  const int base = rowptr[d];
  const int deg  = rowptr[d + 1] - base;
  const float ad = a_d[d];
  const unsigned lh4 = (unsigned)lh * 4u;
  float acc0 = 0.f, acc1 = 0.f;
  float rv;

  if (deg <= 64) {
    int   sreg = 0;
    float e = -1e30f;
    if (l < deg) {
      sreg = ebuf[base + l];
      e = a_s[sreg] + ad; e = e > 0.f ? e : SLOPE * e;
    }
    float mx = e;
#pragma unroll
    for (int m = 32; m >= 1; m >>= 1) mx = fmaxf(mx, __shfl_xor(mx, m));
    const float p = (l < deg) ? __expf(e - mx) : 0.f;
    float sm = p;
#pragma unroll
    for (int m = 32; m >= 1; m >>= 1) sm += __shfl_xor(sm, m);
    rv = 1.f / (sm + 1e-16f);
    pl2[w][l] = make_uint2((unsigned)(l < deg ? sreg : 0) << 7,
                           __float_as_uint(p));   // zero-padded
    const uint2* __restrict__ rp = &pl2[w][hi ? 1 : 0];
    const int niter = (deg + 15) >> 4;   // batches of 16 edges (8 pairs)
    int it = 0;
    for (; it + 2 <= niter; it += 2) {
      unsigned uA[8], uB[8];
      float pA[8], pB[8];
#pragma unroll
      for (int u = 0; u < 8; ++u) {
        const uint2 sp = rp[it * 16 + 2 * u];
        pA[u] = __uint_as_float(sp.y);
        uA[u] = *(const unsigned*)((const char*)hbf + (sp.x + lh4));
      }
#pragma unroll
      for (int u = 0; u < 8; ++u) {
        const uint2 sp = rp[it * 16 + 16 + 2 * u];
        pB[u] = __uint_as_float(sp.y);
        uB[u] = *(const unsigned*)((const char*)hbf + (sp.x + lh4));
      }
#pragma unroll
      for (int u = 0; u < 8; ++u) {
        acc0 = fmaf(pA[u], bf_lo(uA[u]), acc0);
        acc1 = fmaf(pA[u], bf_hi(uA[u]), acc1);
      }
#pragma unroll
      for (int u = 0; u < 8; ++u) {
        acc0 = fmaf(pB[u], bf_lo(uB[u]), acc0);
        acc1 = fmaf(pB[u], bf_hi(uB[u]), acc1);
      }
    }
    if (it < niter) {
      unsigned uA[8];
      float pA[8];
#pragma unroll
      for (int u = 0; u < 8; ++u) {
        const uint2 sp = rp[it * 16 + 2 * u];
        pA[u] = __uint_as_float(sp.y);
        uA[u] = *(const unsigned*)((const char*)hbf + (sp.x + lh4));
      }
#pragma unroll
      for (int u = 0; u < 8; ++u) {
        acc0 = fmaf(pA[u], bf_lo(uA[u]), acc0);
        acc1 = fmaf(pA[u], bf_hi(uA[u]), acc1);
      }
    }
  } else {
    float mx = -1e30f;
    for (int i = l; i < deg; i += 64) {
      const int s = ebuf[base + i];
      float e = a_s[s] + ad; e = e > 0.f ? e : SLOPE * e;
      mx = fmaxf(mx, e);
    }
#pragma unroll
    for (int m = 32; m >= 1; m >>= 1) mx = fmaxf(mx, __shfl_xor(mx, m));
    float sm = 0.f;
    for (int i = l; i < deg; i += 64) {
      const int s = ebuf[base + i];
      float e = a_s[s] + ad; e = e > 0.f ? e : SLOPE * e;
      sm += __expf(e - mx);
    }
#pragma unroll
    for (int m = 32; m >= 1; m >>= 1) sm += __shfl_xor(sm, m);
    rv = 1.f / (sm + 1e-16f);
    for (int i = 0; i < deg; ++i) {
      const int s = ebuf[base + i];
      float e = a_s[s] + ad; e = e > 0.f ? e : SLOPE * e;
      const float pp = hi ? 0.f : __expf(e - mx);
      const unsigned uu = ((const unsigned*)(hbf + (size_t)s * 64))[lh];
      acc0 = fmaf(pp, bf_lo(uu), acc0);
      acc1 = fmaf(pp, bf_hi(uu), acc1);
    }
  }
  acc0 += __shfl_xor(acc0, 32);
  acc1 += __shfl_xor(acc1, 32);
  if (!hi) {
    const int c0 = 2 * lh;
    const float2 bb = *(const float2*)&b2[c0];
    *(float2*)&out[(size_t)d * 64 + c0] =
        make_float2(acc0 * rv + bb.x, acc1 * rv + bb.y);
  }
}

extern "C" void kernel_launch(void* const* d_in, const int* in_sizes, int n_in,
                              void* d_out, int out_size, void* d_ws, size_t ws_size,
                              hipStream_t stream) {
  const float* x     = (const float*)d_in[0];
  const int*   ei    = (const int*)d_in[1];
  const float* W1    = (const float*)d_in[2];
  const float* as1v  = (const float*)d_in[3];
  const float* ad1v  = (const float*)d_in[4];
  const float* b1    = (const float*)d_in[5];
  const float* W2    = (const float*)d_in[6];
  const float* as2v  = (const float*)d_in[7];
  const float* ad2v  = (const float*)d_in[8];
  const float* b2    = (const float*)d_in[9];
  float* out = (float*)d_out;

  char* ws = (char*)d_ws;
  unsigned short* h1 = (unsigned short*)(ws + OFF_H1);
  unsigned* y1       = (unsigned*)(ws + OFF_Y1);
  unsigned short* h2 = (unsigned short*)(ws + OFF_H2);
  float* a_s1 = (float*)(ws + OFF_AS1);
  float* a_d1 = (float*)(ws + OFF_AD1);
  float* a_s2 = (float*)(ws + OFF_AS2);
  float* a_d2 = (float*)(ws + OFF_AD2);
  int* rowptr = (int*)(ws + OFF_ROW);
  int* gcount = (int*)(ws + OFF_GC);
  int* goff   = (int*)(ws + OFF_GO);
  int* gcur   = (int*)(ws + OFF_GU);
  unsigned* eb1 = (unsigned*)(ws + OFF_EB1);
  int* ebuf   = (int*)(ws + OFF_EB);

  hipMemsetAsync(gcount, 0, (size_t)NB_ * 4, stream);

  k_gemm1<<<NBLKG_, 256, 0, stream>>>(x, W1, as1v, ad1v, h1, a_s1, a_d1);
  k_hist<<<NBLKA_, 256, 0, stream>>>(ei, gcount);
  k_scan<<<1, 512, 0, stream>>>(gcount, goff, gcur);
  k_scatter<<<NBLKA_, 256, 0, stream>>>(ei, gcur, eb1);
  k_bucket<<<NB_, 256, 0, stream>>>(eb1, goff, rowptr, ebuf);
  k_agg1<<<N_ / 4, 256, 0, stream>>>(rowptr, ebuf, a_s1, a_d1, h1, b1, y1);
  k_gemm2<<<NBLKG_, 256, 0, stream>>>(y1, W2, as2v, ad2v, h2, a_s2, a_d2);
  k_agg2<<<N_ / 4, 256, 0, stream>>>(rowptr, ebuf, a_s2, a_d2, h2, b2, out);
}

// Round 10
// 149.793 us; speedup vs baseline: 2.2287x; 1.0154x over previous
//
#include <hip/hip_runtime.h>
#include <math.h>

namespace {
constexpr int N_   = 50000;
constexpr int E_   = 800000;
constexpr int EP_  = E_ + N_;   // edges + self loops = 850000
constexpr float SLOPE = 0.2f;

constexpr int NB_    = (N_ + 127) / 128;          // 391 coarse buckets (dst>>7)
constexpr int CHUNK_ = 8192;                      // edges per scatter block
constexpr int NBLKA_ = (EP_ + CHUNK_ - 1) / CHUNK_; // 104
constexpr int CAPB_  = 4096;                      // LDS capacity per bucket
constexpr int NBLKG_ = (N_ + 63) / 64;            // 782 gemm blocks (64 rows)

// workspace layout (bytes)
constexpr size_t OFF_H1  = 0;                                    // [N][128] bf16
constexpr size_t OFF_Y1  = OFF_H1  + (size_t)N_ * 128 * 2;       // [N][128] bf16
constexpr size_t OFF_H2  = OFF_Y1  + (size_t)N_ * 128 * 2;       // [N][64] bf16
constexpr size_t OFF_AS1 = OFF_H2  + (size_t)N_ * 64 * 2;        // [N][4]
constexpr size_t OFF_AD1 = OFF_AS1 + (size_t)N_ * 4 * 4;         // [N][4]
constexpr size_t OFF_AS2 = OFF_AD1 + (size_t)N_ * 4 * 4;         // [N]
constexpr size_t OFF_AD2 = OFF_AS2 + (size_t)N_ * 4;             // [N]
constexpr size_t OFF_ROW = OFF_AD2 + (size_t)N_ * 4;             // [N+1] int
constexpr size_t OFF_GC  = OFF_ROW + (((size_t)(N_ + 1) * 4 + 15) & ~(size_t)15); // [NB] int
constexpr size_t OFF_GO  = OFF_GC  + (((size_t)NB_ * 4 + 15) & ~(size_t)15);      // [NB+1] int
constexpr size_t OFF_GU  = OFF_GO  + (((size_t)(NB_ + 1) * 4 + 15) & ~(size_t)15);// [NB] int
constexpr size_t OFF_EB1 = OFF_GU  + (((size_t)NB_ * 4 + 15) & ~(size_t)15);      // [EP] u32 (src<<16|dst)
constexpr size_t OFF_EB  = OFF_EB1 + (size_t)EP_ * 4;            // [EP] int (src, dst-sorted)
}

typedef __attribute__((ext_vector_type(8))) short short8;
typedef __attribute__((ext_vector_type(4))) float f32x4;

__device__ __forceinline__ unsigned short f2bf(float x) {   // RNE
  unsigned u = __float_as_uint(x);
  return (unsigned short)((u + 0x7FFFu + ((u >> 16) & 1u)) >> 16);
}
__device__ __forceinline__ unsigned pack2bf(float a, float b) {
  return (unsigned)f2bf(a) | ((unsigned)f2bf(b) << 16);
}
__device__ __forceinline__ float bf_lo(unsigned u) { return __uint_as_float(u << 16); }
__device__ __forceinline__ float bf_hi(unsigned u) { return __uint_as_float(u & 0xFFFF0000u); }

// ---------------- GEMM1 (MFMA bf16): h1 = x @ W1 ; a_s1/a_d1 -------------
__global__ __launch_bounds__(256, 3) void k_gemm1(const float* __restrict__ x,
    const float* __restrict__ W, const float* __restrict__ av_s,
    const float* __restrict__ av_d, unsigned short* __restrict__ hbf,
    float* __restrict__ a_s, float* __restrict__ a_d)
{
  __shared__ __align__(16) char smem[52224];
  unsigned short* xs = (unsigned short*)smem;          // [64][136] bf16
  unsigned*       wt = (unsigned*)(smem + 17408);      // [128][68] u32
  float*         wtf = (float*)(smem + 17408);         // [64][132] f32 (epilogue)
  const int t = threadIdx.x;
  const int rbase = blockIdx.x * 64;
#pragma unroll
  for (int it = 0; it < 8; ++it) {
    const int fidx = t + it * 256;
    const int row = fidx >> 5;
    const int c4  = fidx & 31;
    const int rg  = rbase + row;
    float4 v = (rg < N_) ? ((const float4*)x)[(size_t)rg * 32 + c4]
                         : make_float4(0.f, 0.f, 0.f, 0.f);
    *(uint2*)&xs[row * 136 + c4 * 4] =
        make_uint2(pack2bf(v.x, v.y), pack2bf(v.z, v.w));
  }
#pragma unroll
  for (int it = 0; it < 32; ++it) {
    const int idx = t + it * 256;
    const int n  = idx & 127;
    const int kk = idx >> 7;                // 0..63
    wt[n * 68 + kk] = pack2bf(W[(2 * kk) * 128 + n], W[(2 * kk + 1) * 128 + n]);
  }
  __syncthreads();
  const int wv = t >> 6;
  const int l  = t & 63;
  const int lr = l & 15;
  const int lg = l >> 4;
  f32x4 acc[8];
#pragma unroll
  for (int j = 0; j < 8; ++j) acc[j] = (f32x4){0.f, 0.f, 0.f, 0.f};
#pragma unroll
  for (int ks = 0; ks < 4; ++ks) {
    const short8 a = *(const short8*)&xs[(wv * 16 + lr) * 136 + ks * 32 + lg * 8];
#pragma unroll
    for (int j = 0; j < 8; ++j) {
      const short8 b = *(const short8*)&wt[(j * 16 + lr) * 68 + ks * 16 + lg * 4];
      acc[j] = __builtin_amdgcn_mfma_f32_16x16x32_bf16(a, b, acc[j], 0, 0, 0);
    }
  }
  __syncthreads();
#pragma unroll
  for (int j = 0; j < 8; ++j)
#pragma unroll
    for (int r = 0; r < 4; ++r)
      wtf[(wv * 16 + lg * 4 + r) * 132 + j * 16 + lr] = acc[j][r];
  __syncthreads();
  // h1 store — 4096 u32 = 64 rows x 64 u32 -> 16 iters
#pragma unroll
  for (int it = 0; it < 16; ++it) {
    const int idx = t + it * 256;
    const int row = idx >> 6;
    const int c2  = idx & 63;
    const int rg  = rbase + row;
    if (rg < N_) {
      const float2 hv = *(const float2*)&wtf[row * 132 + c2 * 2];
      ((unsigned*)hbf)[(size_t)rg * 64 + c2] = pack2bf(hv.x, hv.y);
    }
  }
  {
    const int row = t & 63;
    const int q   = t >> 6;
    const int rg  = rbase + row;
    float ss = 0.f, sd = 0.f;
#pragma unroll
    for (int i = 0; i < 8; ++i) {
      const float4 hv = *(const float4*)&wtf[row * 132 + q * 32 + 4 * i];
      const float4 s4 = *(const float4*)&av_s[q * 32 + 4 * i];
      const float4 d4 = *(const float4*)&av_d[q * 32 + 4 * i];
      ss += hv.x * s4.x + hv.y * s4.y + hv.z * s4.z + hv.w * s4.w;
      sd += hv.x * d4.x + hv.y * d4.y + hv.z * d4.z + hv.w * d4.w;
    }
    if (rg < N_) { a_s[rg * 4 + q] = ss; a_d[rg * 4 + q] = sd; }
  }
}

// ---------------- GEMM2 (MFMA bf16): h2 = y1 @ W2 ; a_s2/a_d2 ------------
__global__ __launch_bounds__(256, 4) void k_gemm2(const unsigned* __restrict__ ybf,
    const float* __restrict__ W, const float* __restrict__ av_s,
    const float* __restrict__ av_d, unsigned short* __restrict__ hbf,
    float* __restrict__ a_s, float* __restrict__ a_d)
{
  __shared__ __align__(16) char smem[36864];
  unsigned short* xs = (unsigned short*)smem;          // [64][136] bf16 (y)
  unsigned*       wt = (unsigned*)(smem + 17408);      // [64][68] u32
  float*         wtf = (float*)(smem + 17408);         // [64][68] f32 (epilogue)
  float*          ps = (float*)(smem + 34816);         // [2][4][64] partials
  const int t = threadIdx.x;
  const int rbase = blockIdx.x * 64;
#pragma unroll
  for (int it = 0; it < 16; ++it) {
    const int idx = t + it * 256;
    const int row = idx >> 6;
    const int c2  = idx & 63;
    const int rg  = rbase + row;
    const unsigned u = (rg < N_) ? ybf[(size_t)rg * 64 + c2] : 0u;
    *(unsigned*)&xs[row * 136 + c2 * 2] = u;
  }
#pragma unroll
  for (int it = 0; it < 16; ++it) {
    const int idx = t + it * 256;
    const int n  = idx & 63;
    const int kk = idx >> 6;                // 0..63
    wt[n * 68 + kk] = pack2bf(W[(2 * kk) * 64 + n], W[(2 * kk + 1) * 64 + n]);
  }
  __syncthreads();
  const int wv = t >> 6;
  const int l  = t & 63;
  const int lr = l & 15;
  const int lg = l >> 4;
  f32x4 acc[4];
#pragma unroll
  for (int j = 0; j < 4; ++j) acc[j] = (f32x4){0.f, 0.f, 0.f, 0.f};
#pragma unroll
  for (int ks = 0; ks < 4; ++ks) {
    const short8 a = *(const short8*)&xs[(wv * 16 + lr) * 136 + ks * 32 + lg * 8];
#pragma unroll
    for (int j = 0; j < 4; ++j) {
      const short8 b = *(const short8*)&wt[(j * 16 + lr) * 68 + ks * 16 + lg * 4];
      acc[j] = __builtin_amdgcn_mfma_f32_16x16x32_bf16(a, b, acc[j], 0, 0, 0);
    }
  }
  __syncthreads();
#pragma unroll
  for (int j = 0; j < 4; ++j)
#pragma unroll
    for (int r = 0; r < 4; ++r)
      wtf[(wv * 16 + lg * 4 + r) * 68 + j * 16 + lr] = acc[j][r];
  __syncthreads();
#pragma unroll
  for (int it = 0; it < 8; ++it) {
    const int idx = t + it * 256;
    const int row = idx >> 5;
    const int c2  = idx & 31;
    const int rg  = rbase + row;
    if (rg < N_) {
      const float2 hv = *(const float2*)&wtf[row * 68 + c2 * 2];
      ((unsigned*)hbf)[(size_t)rg * 32 + c2] = pack2bf(hv.x, hv.y);
    }
  }
  {
    const int row = t & 63;
    const int g   = t >> 6;
    float ss = 0.f, sd = 0.f;
#pragma unroll
    for (int i = 0; i < 4; ++i) {
      const float4 hv = *(const float4*)&wtf[row * 68 + g * 16 + 4 * i];
      const float4 s4 = *(const float4*)&av_s[g * 16 + 4 * i];
      const float4 d4 = *(const float4*)&av_d[g * 16 + 4 * i];
      ss += hv.x * s4.x + hv.y * s4.y + hv.z * s4.z + hv.w * s4.w;
      sd += hv.x * d4.x + hv.y * d4.y + hv.z * d4.z + hv.w * d4.w;
    }
    ps[g * 64 + row] = ss;
    ps[256 + g * 64 + row] = sd;
  }
  __syncthreads();
  if (t < 64) {
    const int rg = rbase + t;
    if (rg < N_) {
      a_s[rg] = ps[t] + ps[64 + t] + ps[128 + t] + ps[192 + t];
      a_d[rg] = ps[256 + t] + ps[320 + t] + ps[384 + t] + ps[448 + t];
    }
  }
}

// ---------------- CSR build: two-level counting sort ----------------
__global__ __launch_bounds__(256) void k_hist(const int* __restrict__ ei,
                                              int* __restrict__ gcount)
{
  __shared__ int nh[NB_];
  const int t = threadIdx.x;
  for (int j = t; j < NB_; j += 256) nh[j] = 0;
  __syncthreads();
  const int beg = blockIdx.x * CHUNK_;
  const int end = min(beg + CHUNK_, EP_);
  for (int i = beg + t; i < end; i += 256) {
    const int d = (i < E_) ? ei[E_ + i] : (i - E_);
    atomicAdd(&nh[d >> 7], 1);
  }
  __syncthreads();
  for (int j = t; j < NB_; j += 256)
    if (nh[j]) atomicAdd(&gcount[j], nh[j]);
}

__global__ __launch_bounds__(512) void k_scan(const int* __restrict__ gcount,
    int* __restrict__ goff, int* __restrict__ gcursor)
{
  __shared__ int sd[512];
  const int t = threadIdx.x;
  const int v = (t < NB_) ? gcount[t] : 0;
  sd[t] = v;
  __syncthreads();
  for (int off = 1; off < 512; off <<= 1) {
    const int add = (t >= off) ? sd[t - off] : 0;
    __syncthreads();
    sd[t] += add;
    __syncthreads();
  }
  if (t < NB_) { goff[t] = sd[t] - v; gcursor[t] = sd[t] - v; }
  if (t == 0) goff[NB_] = EP_;
}

__global__ __launch_bounds__(256) void k_scatter(const int* __restrict__ ei,
    int* __restrict__ gcursor, unsigned* __restrict__ eb1)
{
  __shared__ int nh[NB_];
  __shared__ int gb[NB_];
  const int t = threadIdx.x;
  for (int j = t; j < NB_; j += 256) nh[j] = 0;
  __syncthreads();
  const int beg = blockIdx.x * CHUNK_;
  const int end = min(beg + CHUNK_, EP_);
  for (int i = beg + t; i < end; i += 256) {
    const int d = (i < E_) ? ei[E_ + i] : (i - E_);
    atomicAdd(&nh[d >> 7], 1);
  }
  __syncthreads();
  for (int j = t; j < NB_; j += 256) {
    const int c = nh[j];
    gb[j] = c ? atomicAdd(&gcursor[j], c) : 0;
    nh[j] = 0;
  }
  __syncthreads();
  for (int i = beg + t; i < end; i += 256) {
    int s, d;
    if (i < E_) { s = ei[i]; d = ei[E_ + i]; } else { s = d = i - E_; }
    const int b = d >> 7;
    const int r = atomicAdd(&nh[b], 1);
    eb1[gb[b] + r] = ((unsigned)s << 16) | (unsigned)d;   // both < 65536
  }
}

__global__ __launch_bounds__(256) void k_bucket(const unsigned* __restrict__ eb1,
    const int* __restrict__ goff, int* __restrict__ rowptr,
    int* __restrict__ ebuf)
{
  __shared__ int h[128];
  __shared__ int off[129];
  __shared__ unsigned arrv[CAPB_];
  const int b = blockIdx.x;
  const int t = threadIdx.x;
  const int base = goff[b];
  const int cnt  = goff[b + 1] - base;
  if (t < 128) h[t] = 0;
  __syncthreads();
  const bool fits = (cnt <= CAPB_);
  for (int i = t; i < cnt; i += 256) {
    const unsigned v = eb1[base + i];
    if (fits) arrv[i] = v;
    atomicAdd(&h[(int)(v & 0xFFFFu) - (b << 7)], 1);
  }
  __syncthreads();
  if (t < 64) {
    const int a0 = h[2 * t], a1 = h[2 * t + 1];
    int s = a0 + a1;
#pragma unroll
    for (int m = 1; m < 64; m <<= 1) {
      const int u = __shfl_up(s, m);
      if (t >= m) s += u;
    }
    off[2 * t + 1] = s - a1;
    off[2 * t]     = s - a1 - a0;
    if (t == 63) off[128] = s;
  }
  __syncthreads();
  if (t < 128) {
    const int dst = (b << 7) + t;
    if (dst < N_) rowptr[dst] = base + off[t];
  }
  if (b == NB_ - 1 && t == 0) rowptr[N_] = EP_;
  if (t < 128) h[t] = 0;   // reuse as rank counters
  __syncthreads();
  for (int i = t; i < cnt; i += 256) {
    const unsigned v = fits ? arrv[i] : eb1[base + i];
    const int dlow = (int)(v & 0xFFFFu) - (b << 7);
    const int r = atomicAdd(&h[dlow], 1);
    ebuf[base + off[dlow] + r] = (int)(v >> 16);
  }
}

// ---------------- Layer-1 aggregation: 1 wave/dst, bf16 h, 128 ch -------
// (src_off, p) table zero-padded; tail-free batch loop, 2 batches of 8 edges
// in flight. launch_bounds (256,4): 128-VGPR cap so batch arrays stay in
// registers — (256,8)'s 64-VGPR cap spilled them to scratch (R9: WRITE 4x).
__global__ __launch_bounds__(256, 4) void k_agg1(const int* __restrict__ rowptr,
    const int* __restrict__ ebuf, const float* __restrict__ a_s,
    const float* __restrict__ a_d, const unsigned short* __restrict__ hbf,
    const float* __restrict__ b1, unsigned* __restrict__ y)
{
  __shared__ uint2 pl[4][4 * 65];
  const int w = threadIdx.x >> 6;
  const int l = threadIdx.x & 63;
  const int d = blockIdx.x * 4 + w;
  const int base = rowptr[d];
  const int deg  = rowptr[d + 1] - base;
  const float4 ad = *(const float4*)&a_d[(size_t)d * 4];
  const int hsel = l >> 4;
  const unsigned l4 = (unsigned)l * 4u;
  float acc0 = 0.f, acc1 = 0.f;
  float r0, r1, r2, r3;

  if (deg <= 64) {
    int   sreg = 0;
    float e0 = -1e30f, e1 = -1e30f, e2 = -1e30f, e3 = -1e30f;
    if (l < deg) {
      sreg = ebuf[base + l];
      const float4 as = *(const float4*)&a_s[(size_t)sreg * 4];
      e0 = as.x + ad.x; e0 = e0 > 0.f ? e0 : SLOPE * e0;
      e1 = as.y + ad.y; e1 = e1 > 0.f ? e1 : SLOPE * e1;
      e2 = as.z + ad.z; e2 = e2 > 0.f ? e2 : SLOPE * e2;
      e3 = as.w + ad.w; e3 = e3 > 0.f ? e3 : SLOPE * e3;
    }
    float mx0 = e0, mx1 = e1, mx2 = e2, mx3 = e3;
#pragma unroll
    for (int m = 32; m >= 1; m >>= 1) {
      mx0 = fmaxf(mx0, __shfl_xor(mx0, m));
      mx1 = fmaxf(mx1, __shfl_xor(mx1, m));
      mx2 = fmaxf(mx2, __shfl_xor(mx2, m));
      mx3 = fmaxf(mx3, __shfl_xor(mx3, m));
    }
    const float p0 = (l < deg) ? __expf(e0 - mx0) : 0.f;
    const float p1 = (l < deg) ? __expf(e1 - mx1) : 0.f;
    const float p2 = (l < deg) ? __expf(e2 - mx2) : 0.f;
    const float p3 = (l < deg) ? __expf(e3 - mx3) : 0.f;
    float sm0 = p0, sm1 = p1, sm2 = p2, sm3 = p3;
#pragma unroll
    for (int m = 32; m >= 1; m >>= 1) {
      sm0 += __shfl_xor(sm0, m);
      sm1 += __shfl_xor(sm1, m);
      sm2 += __shfl_xor(sm2, m);
      sm3 += __shfl_xor(sm3, m);
    }
    r0 = 1.f / (sm0 + 1e-16f);
    r1 = 1.f / (sm1 + 1e-16f);
    r2 = 1.f / (sm2 + 1e-16f);
    r3 = 1.f / (sm3 + 1e-16f);
    // zero-padded table: lanes l>=deg have sreg=0, p*=0
    {
      const unsigned soff = (unsigned)sreg << 8;
      pl[w][0 * 65 + l] = make_uint2(soff, __float_as_uint(p0));
      pl[w][1 * 65 + l] = make_uint2(soff, __float_as_uint(p1));
      pl[w][2 * 65 + l] = make_uint2(soff, __float_as_uint(p2));
      pl[w][3 * 65 + l] = make_uint2(soff, __float_as_uint(p3));
    }
    const uint2* __restrict__ rp = &pl[w][hsel * 65];
    const int niter = (deg + 7) >> 3;
    int it = 0;
    for (; it + 2 <= niter; it += 2) {
      unsigned uA[8], uB[8];
      float pA[8], pB[8];
#pragma unroll
      for (int u = 0; u < 8; ++u) {
        const uint2 sp = rp[it * 8 + u];
        pA[u] = __uint_as_float(sp.y);
        uA[u] = *(const unsigned*)((const char*)hbf + (sp.x + l4));
      }
#pragma unroll
      for (int u = 0; u < 8; ++u) {
        const uint2 sp = rp[it * 8 + 8 + u];
        pB[u] = __uint_as_float(sp.y);
        uB[u] = *(const unsigned*)((const char*)hbf + (sp.x + l4));
      }
#pragma unroll
      for (int u = 0; u < 8; ++u) {
        acc0 = fmaf(pA[u], bf_lo(uA[u]), acc0);
        acc1 = fmaf(pA[u], bf_hi(uA[u]), acc1);
      }
#pragma unroll
      for (int u = 0; u < 8; ++u) {
        acc0 = fmaf(pB[u], bf_lo(uB[u]), acc0);
        acc1 = fmaf(pB[u], bf_hi(uB[u]), acc1);
      }
    }
    if (it < niter) {
      unsigned uA[8];
      float pA[8];
#pragma unroll
      for (int u = 0; u < 8; ++u) {
        const uint2 sp = rp[it * 8 + u];
        pA[u] = __uint_as_float(sp.y);
        uA[u] = *(const unsigned*)((const char*)hbf + (sp.x + l4));
      }
#pragma unroll
      for (int u = 0; u < 8; ++u) {
        acc0 = fmaf(pA[u], bf_lo(uA[u]), acc0);
        acc1 = fmaf(pA[u], bf_hi(uA[u]), acc1);
      }
    }
  } else {
    // ---- any-deg fallback (never taken for this graph, kept for safety) --
    float mx0 = -1e30f, mx1 = -1e30f, mx2 = -1e30f, mx3 = -1e30f;
    for (int i = l; i < deg; i += 64) {
      const int s = ebuf[base + i];
      const float4 as = *(const float4*)&a_s[(size_t)s * 4];
      float e0 = as.x + ad.x; e0 = e0 > 0.f ? e0 : SLOPE * e0;
      float e1 = as.y + ad.y; e1 = e1 > 0.f ? e1 : SLOPE * e1;
      float e2 = as.z + ad.z; e2 = e2 > 0.f ? e2 : SLOPE * e2;
      float e3 = as.w + ad.w; e3 = e3 > 0.f ? e3 : SLOPE * e3;
      mx0 = fmaxf(mx0, e0); mx1 = fmaxf(mx1, e1);
      mx2 = fmaxf(mx2, e2); mx3 = fmaxf(mx3, e3);
    }
#pragma unroll
    for (int m = 32; m >= 1; m >>= 1) {
      mx0 = fmaxf(mx0, __shfl_xor(mx0, m));
      mx1 = fmaxf(mx1, __shfl_xor(mx1, m));
      mx2 = fmaxf(mx2, __shfl_xor(mx2, m));
      mx3 = fmaxf(mx3, __shfl_xor(mx3, m));
    }
    float sm0 = 0.f, sm1 = 0.f, sm2 = 0.f, sm3 = 0.f;
    for (int i = l; i < deg; i += 64) {
      const int s = ebuf[base + i];
      const float4 as = *(const float4*)&a_s[(size_t)s * 4];
      float e0 = as.x + ad.x; e0 = e0 > 0.f ? e0 : SLOPE * e0;
      float e1 = as.y + ad.y; e1 = e1 > 0.f ? e1 : SLOPE * e1;
      float e2 = as.z + ad.z; e2 = e2 > 0.f ? e2 : SLOPE * e2;
      float e3 = as.w + ad.w; e3 = e3 > 0.f ? e3 : SLOPE * e3;
      sm0 += __expf(e0 - mx0); sm1 += __expf(e1 - mx1);
      sm2 += __expf(e2 - mx2); sm3 += __expf(e3 - mx3);
    }
#pragma unroll
    for (int m = 32; m >= 1; m >>= 1) {
      sm0 += __shfl_xor(sm0, m);
      sm1 += __shfl_xor(sm1, m);
      sm2 += __shfl_xor(sm2, m);
      sm3 += __shfl_xor(sm3, m);
    }
    r0 = 1.f / (sm0 + 1e-16f);
    r1 = 1.f / (sm1 + 1e-16f);
    r2 = 1.f / (sm2 + 1e-16f);
    r3 = 1.f / (sm3 + 1e-16f);
    const float mxs = hsel == 3 ? mx3 : hsel == 2 ? mx2 : hsel == 1 ? mx1 : mx0;
    for (int i = 0; i < deg; ++i) {
      const int s = ebuf[base + i];
      const float4 as = *(const float4*)&a_s[(size_t)s * 4];
      float e0 = as.x + ad.x; e0 = e0 > 0.f ? e0 : SLOPE * e0;
      float e1 = as.y + ad.y; e1 = e1 > 0.f ? e1 : SLOPE * e1;
      float e2 = as.z + ad.z; e2 = e2 > 0.f ? e2 : SLOPE * e2;
      float e3 = as.w + ad.w; e3 = e3 > 0.f ? e3 : SLOPE * e3;
      const float es = hsel == 3 ? e3 : hsel == 2 ? e2 : hsel == 1 ? e1 : e0;
      const float pa = __expf(es - mxs);
      const unsigned uu = ((const unsigned*)(hbf + (size_t)s * 128))[l];
      acc0 = fmaf(pa, bf_lo(uu), acc0);
      acc1 = fmaf(pa, bf_hi(uu), acc1);
    }
  }
  const float rsel = hsel == 3 ? r3 : hsel == 2 ? r2 : hsel == 1 ? r1 : r0;
  const int c0 = 2 * l;
  const float2 bb = *(const float2*)&b1[c0];
  float o0 = acc0 * rsel + bb.x;
  float o1 = acc1 * rsel + bb.y;
  o0 = o0 > 0.f ? o0 : expm1f(o0);
  o1 = o1 > 0.f ? o1 : expm1f(o1);
  y[(size_t)d * 64 + l] = pack2bf(o0, o1);   // y1 stored bf16
}

// ---------------- Layer-2 aggregation: 1 wave/dst, bf16 h, 64 ch --------
__global__ __launch_bounds__(256, 4) void k_agg2(const int* __restrict__ rowptr,
    const int* __restrict__ ebuf, const float* __restrict__ a_s,
    const float* __restrict__ a_d, const unsigned short* __restrict__ hbf,
    const float* __restrict__ b2, float* __restrict__ out)
{
  __shared__ uint2 pl2[4][66];
  const int w = threadIdx.x >> 6;
  const int l = threadIdx.x & 63;
  const int lh = l & 31;
  const bool hi = (l >= 32);
  const int d = blockIdx.x * 4 + w;
  const int base = rowptr[d];
  const int deg  = rowptr[d + 1] - base;
  const float ad = a_d[d];
  const unsigned lh4 = (unsigned)lh * 4u;
  float acc0 = 0.f, acc1 = 0.f;
  float rv;

  if (deg <= 64) {
    int   sreg = 0;
    float e = -1e30f;
    if (l < deg) {
      sreg = ebuf[base + l];
      e = a_s[sreg] + ad; e = e > 0.f ? e : SLOPE * e;
    }
    float mx = e;
#pragma unroll
    for (int m = 32; m >= 1; m >>= 1) mx = fmaxf(mx, __shfl_xor(mx, m));
    const float p = (l < deg) ? __expf(e - mx) : 0.f;
    float sm = p;
#pragma unroll
    for (int m = 32; m >= 1; m >>= 1) sm += __shfl_xor(sm, m);
    rv = 1.f / (sm + 1e-16f);
    pl2[w][l] = make_uint2((unsigned)(l < deg ? sreg : 0) << 7,
                           __float_as_uint(p));   // zero-padded
    const uint2* __restrict__ rp = &pl2[w][hi ? 1 : 0];
    const int niter = (deg + 15) >> 4;   // batches of 16 edges (8 pairs)
    int it = 0;
    for (; it + 2 <= niter; it += 2) {
      unsigned uA[8], uB[8];
      float pA[8], pB[8];
#pragma unroll
      for (int u = 0; u < 8; ++u) {
        const uint2 sp = rp[it * 16 + 2 * u];
        pA[u] = __uint_as_float(sp.y);
        uA[u] = *(const unsigned*)((const char*)hbf + (sp.x + lh4));
      }
#pragma unroll
      for (int u = 0; u < 8; ++u) {
        const uint2 sp = rp[it * 16 + 16 + 2 * u];
        pB[u] = __uint_as_float(sp.y);
        uB[u] = *(const unsigned*)((const char*)hbf + (sp.x + lh4));
      }
#pragma unroll
      for (int u = 0; u < 8; ++u) {
        acc0 = fmaf(pA[u], bf_lo(uA[u]), acc0);
        acc1 = fmaf(pA[u], bf_hi(uA[u]), acc1);
      }
#pragma unroll
      for (int u = 0; u < 8; ++u) {
        acc0 = fmaf(pB[u], bf_lo(uB[u]), acc0);
        acc1 = fmaf(pB[u], bf_hi(uB[u]), acc1);
      }
    }
    if (it < niter) {
      unsigned uA[8];
      float pA[8];
#pragma unroll
      for (int u = 0; u < 8; ++u) {
        const uint2 sp = rp[it * 16 + 2 * u];
        pA[u] = __uint_as_float(sp.y);
        uA[u] = *(const unsigned*)((const char*)hbf + (sp.x + lh4));
      }
#pragma unroll
      for (int u = 0; u < 8; ++u) {
        acc0 = fmaf(pA[u], bf_lo(uA[u]), acc0);
        acc1 = fmaf(pA[u], bf_hi(uA[u]), acc1);
      }
    }
  } else {
    float mx = -1e30f;
    for (int i = l; i < deg; i += 64) {
      const int s = ebuf[base + i];
      float e = a_s[s] + ad; e = e > 0.f ? e : SLOPE * e;
      mx = fmaxf(mx, e);
    }
#pragma unroll
    for (int m = 32; m >= 1; m >>= 1) mx = fmaxf(mx, __shfl_xor(mx, m));
    float sm = 0.f;
    for (int i = l; i < deg; i += 64) {
      const int s = ebuf[base + i];
      float e = a_s[s] + ad; e = e > 0.f ? e : SLOPE * e;
      sm += __expf(e - mx);
    }
#pragma unroll
    for (int m = 32; m >= 1; m >>= 1) sm += __shfl_xor(sm, m);
    rv = 1.f / (sm + 1e-16f);
    for (int i = 0; i < deg; ++i) {
      const int s = ebuf[base + i];
      float e = a_s[s] + ad; e = e > 0.f ? e : SLOPE * e;
      const float pp = hi ? 0.f : __expf(e - mx);
      const unsigned uu = ((const unsigned*)(hbf + (size_t)s * 64))[lh];
      acc0 = fmaf(pp, bf_lo(uu), acc0);
      acc1 = fmaf(pp, bf_hi(uu), acc1);
    }
  }
  acc0 += __shfl_xor(acc0, 32);
  acc1 += __shfl_xor(acc1, 32);
  if (!hi) {
    const int c0 = 2 * lh;
    const float2 bb = *(const float2*)&b2[c0];
    *(float2*)&out[(size_t)d * 64 + c0] =
        make_float2(acc0 * rv + bb.x, acc1 * rv + bb.y);
  }
}

extern "C" void kernel_launch(void* const* d_in, const int* in_sizes, int n_in,
                              void* d_out, int out_size, void* d_ws, size_t ws_size,
                              hipStream_t stream) {
  const float* x     = (const float*)d_in[0];
  const int*   ei    = (const int*)d_in[1];
  const float* W1    = (const float*)d_in[2];
  const float* as1v  = (const float*)d_in[3];
  const float* ad1v  = (const float*)d_in[4];
  const float* b1    = (const float*)d_in[5];
  const float* W2    = (const float*)d_in[6];
  const float* as2v  = (const float*)d_in[7];
  const float* ad2v  = (const float*)d_in[8];
  const float* b2    = (const float*)d_in[9];
  float* out = (float*)d_out;

  char* ws = (char*)d_ws;
  unsigned short* h1 = (unsigned short*)(ws + OFF_H1);
  unsigned* y1       = (unsigned*)(ws + OFF_Y1);
  unsigned short* h2 = (unsigned short*)(ws + OFF_H2);
  float* a_s1 = (float*)(ws + OFF_AS1);
  float* a_d1 = (float*)(ws + OFF_AD1);
  float* a_s2 = (float*)(ws + OFF_AS2);
  float* a_d2 = (float*)(ws + OFF_AD2);
  int* rowptr = (int*)(ws + OFF_ROW);
  int* gcount = (int*)(ws + OFF_GC);
  int* goff   = (int*)(ws + OFF_GO);
  int* gcur   = (int*)(ws + OFF_GU);
  unsigned* eb1 = (unsigned*)(ws + OFF_EB1);
  int* ebuf   = (int*)(ws + OFF_EB);

  hipMemsetAsync(gcount, 0, (size_t)NB_ * 4, stream);

  k_gemm1<<<NBLKG_, 256, 0, stream>>>(x, W1, as1v, ad1v, h1, a_s1, a_d1);
  k_hist<<<NBLKA_, 256, 0, stream>>>(ei, gcount);
  k_scan<<<1, 512, 0, stream>>>(gcount, goff, gcur);
  k_scatter<<<NBLKA_, 256, 0, stream>>>(ei, gcur, eb1);
  k_bucket<<<NB_, 256, 0, stream>>>(eb1, goff, rowptr, ebuf);
  k_agg1<<<N_ / 4, 256, 0, stream>>>(rowptr, ebuf, a_s1, a_d1, h1, b1, y1);
  k_gemm2<<<NBLKG_, 256, 0, stream>>>(y1, W2, as2v, ad2v, h2, a_s2, a_d2);
  k_agg2<<<N_ / 4, 256, 0, stream>>>(rowptr, ebuf, a_s2, a_d2, h2, b2, out);
}